// Round 9
// baseline (1122.396 us; speedup 1.0000x reference)
//
#include <hip/hip_runtime.h>
#include <math.h>

// ---------------- constants ----------------
#define T99   99
#define CC    256
#define NHH   8
#define FEAT  400
#define NS_   32
#define LSTEP 33

typedef __attribute__((ext_vector_type(8))) short s8v;   // 8 x bf16 (as raw u16)
typedef __attribute__((ext_vector_type(4))) float f4v;   // MFMA accumulator

__device__ __forceinline__ void mfma_bf16(f4v& d, s8v a, s8v b) {
  asm("v_mfma_f32_16x16x32_bf16 %0, %1, %2, %0" : "+v"(d) : "v"(a), "v"(b));
}

__device__ __forceinline__ unsigned short f2bf(float f) {
  union { float f; unsigned u; } x; x.f = f;
  unsigned r = x.u + 0x7FFFu + ((x.u >> 16) & 1u);
  return (unsigned short)(r >> 16);
}
__device__ __forceinline__ float bf2f(unsigned short h) {
  union { unsigned u; float f; } x; x.u = ((unsigned)h) << 16;
  return x.f;
}
__device__ __forceinline__ float blo(unsigned u) { union { unsigned x; float f; } c; c.x = u << 16; return c.f; }
__device__ __forceinline__ float bhi(unsigned u) { union { unsigned x; float f; } c; c.x = u & 0xffff0000u; return c.f; }

__device__ __forceinline__ float pe_val(int pos, int c) {
  int i = c >> 1;
  float freq = expf((float)(2 * i) * (-0.03597789207803197f)); // -ln(10000)/256
  float ang = (float)pos * freq;
  return (c & 1) ? cosf(ang) : sinf(ang);
}

// ---------------- software grid barrier (device-scope, replay-safe) ----------------
__device__ __forceinline__ void gbar(unsigned* cnt, unsigned* gen, int nblk) {
  __syncthreads();
  if (threadIdx.x == 0) {
    __threadfence();
    unsigned g = atomicAdd(gen, 0u);          // read generation BEFORE arriving
    unsigned t = atomicAdd(cnt, 1u);
    if (t == (unsigned)(nblk - 1)) {
      atomicExch(cnt, 0u);                    // re-arm for next barrier / next replay
      __threadfence();
      atomicAdd(gen, 1u);                     // release
    } else {
      while (atomicAdd(gen, 0u) == g) __builtin_amdgcn_s_sleep(8);
    }
    __threadfence();
  }
  __syncthreads();
}

__global__ void k_zero(unsigned* p) { p[threadIdx.x] = 0u; }

// ---------------- conv stem ----------------
__global__ __launch_bounds__(128) void k_convbase(const float* __restrict__ x,
                                                  const float* __restrict__ w,
                                                  const float* __restrict__ bias,
                                                  float* __restrict__ base) {
  int b = blockIdx.x >> 8, co = blockIdx.x & 255, t = threadIdx.x;
  if (t >= T99) return;
  int g = co >> 6;
  float acc = bias[co];
  const float* xp = x + (size_t)(b * FEAT + g * 100) * T99;
  const float* wp = w + (size_t)co * 300;
  for (int ic = 0; ic < 100; ++ic) {
    float x0 = (t > 0)  ? xp[ic * T99 + t - 1] : 0.f;
    float x1 = xp[ic * T99 + t];
    float x2 = (t < 98) ? xp[ic * T99 + t + 1] : 0.f;
    acc += wp[ic * 3] * x0 + wp[ic * 3 + 1] * x1 + wp[ic * 3 + 2] * x2;
  }
  base[(size_t)(b * CC + co) * T99 + t] = fmaxf(acc, 0.f);
}

// ---------------- weight conversion: pack {qkv,o,l1,l2} per layer into bf16 row-major blob ----------------
__global__ __launch_bounds__(256) void k_convW(const float* __restrict__ qkv, const float* __restrict__ o,
                                               const float* __restrict__ l1, const float* __restrict__ l2,
                                               int L, unsigned short* __restrict__ dst) {
  int total = L * 786432;
  for (int idx = blockIdx.x * 256 + threadIdx.x; idx < total; idx += gridDim.x * 256) {
    int l = idx / 786432, r = idx % 786432;
    float v;
    if (r < 196608)      v = qkv[(size_t)l * 196608 + r];
    else if (r < 262144) v = o[(size_t)l * 65536 + (r - 196608)];
    else if (r < 524288) v = l1[(size_t)l * 262144 + (r - 262144)];
    else                 v = l2[(size_t)l * 262144 + (r - 524288)];
    dst[idx] = f2bf(v);
  }
}

// ---------------- build encoder inputs ----------------
__global__ __launch_bounds__(256) void k_build_xg(const float* __restrict__ base, float* __restrict__ xg,
                                                  unsigned short* __restrict__ xgb) {
  int idx = blockIdx.x * 256 + threadIdx.x;
  int t = idx >> 10, r = idx & 1023, b4 = r >> 8, c = r & 255;
  float v = (b4 < 2) ? base[(size_t)(b4 * CC + c) * T99 + t]
                     : base[(size_t)((b4 - 2) * CC + c) * T99 + (98 - t)];
  v += pe_val(t, c);
  xg[idx] = v; xgb[idx] = f2bf(v);
}

__global__ __launch_bounds__(256) void k_build_xl(const float* __restrict__ base, float* __restrict__ xl,
                                                  unsigned short* __restrict__ xlb) {
  int idx = blockIdx.x * 256 + threadIdx.x;
  int ls = idx / 1536, r = idx % 1536, j = r >> 8, c = r & 255;
  int g = j >> 1, b = j & 1, t = ls * 3 + g;
  float v = base[(size_t)(b * CC + c) * T99 + t] + pe_val(ls, c);
  xl[idx] = v; xlb[idx] = f2bf(v);
}

// ================= GEMM body (R6-proven: dual LDS staging, 64x64 tile) =================
// flags: 1=relu, 2=residual R, 4=write bf16 Yb, 8=skip fp32 Yf
__device__ void gemm_body(const unsigned short* __restrict__ A,
                          const unsigned short* __restrict__ W,
                          const float* __restrict__ bias,
                          const float* __restrict__ R,
                          float* __restrict__ Y,
                          unsigned short* __restrict__ Yb,
                          int M, int N, int K, int flags,
                          int m0, int n0) {
  __shared__ __align__(16) unsigned short Al[64][40];
  __shared__ __align__(16) unsigned short Bl[64][40];
  int tid = threadIdx.x;
  int lane = tid & 63, w = tid >> 6, wm = w >> 1, wn = w & 1;
  int sp = tid >> 2, kc = (tid & 3) << 3;
  f4v acc[2][2];
#pragma unroll
  for (int mt = 0; mt < 2; ++mt)
#pragma unroll
    for (int nt = 0; nt < 2; ++nt) acc[mt][nt] = (f4v){0.f, 0.f, 0.f, 0.f};

  for (int k0 = 0; k0 < K; k0 += 32) {
    s8v av = {0, 0, 0, 0, 0, 0, 0, 0};
    int row = m0 + sp;
    if (row < M) av = *(const s8v*)&A[(size_t)row * K + k0 + kc];
    *(s8v*)&Al[sp][kc] = av;
    *(s8v*)&Bl[sp][kc] = *(const s8v*)&W[(size_t)(n0 + sp) * K + k0 + kc];
    __syncthreads();
    s8v af[2], bf[2];
#pragma unroll
    for (int mt = 0; mt < 2; ++mt)
      af[mt] = *(const s8v*)&Al[wm * 32 + mt * 16 + (lane & 15)][(lane >> 4) * 8];
#pragma unroll
    for (int nt = 0; nt < 2; ++nt)
      bf[nt] = *(const s8v*)&Bl[wn * 32 + nt * 16 + (lane & 15)][(lane >> 4) * 8];
#pragma unroll
    for (int mt = 0; mt < 2; ++mt)
#pragma unroll
      for (int nt = 0; nt < 2; ++nt) mfma_bf16(acc[mt][nt], af[mt], bf[nt]);
    __syncthreads();
  }
  asm volatile("s_nop 7\n\ts_nop 7\n\ts_nop 4");
#pragma unroll
  for (int mt = 0; mt < 2; ++mt) {
#pragma unroll
    for (int nt = 0; nt < 2; ++nt) {
      int col = n0 + wn * 32 + nt * 16 + (lane & 15);
      float bv = bias[col];
#pragma unroll
      for (int r = 0; r < 4; ++r) {
        int row = m0 + wm * 32 + mt * 16 + (lane >> 4) * 4 + r;
        if (row < M) {
          float v = acc[mt][nt][r] + bv;
          if (flags & 2) v += R[(size_t)row * N + col];
          if (flags & 1) v = fmaxf(v, 0.f);
          if (!(flags & 8)) Y[(size_t)row * N + col] = v;
          if (flags & 4) Yb[(size_t)row * N + col] = f2bf(v);
        }
      }
    }
  }
}

// ---------------- megakernel parameter block ----------------
struct EncP {
  const unsigned short *wL, *wG;
  const float *qbL, *obL, *l1bL, *l2bL, *n1gL, *n1bL, *n2gL, *n2bL, *nfgL, *nfbL;
  const float *qbG, *obG, *l1bG, *l2bG, *n1gG, *n1bG, *n2gG, *n2bG, *nfgG, *nfbG;
  float *xL, *yL; unsigned short *xbL, *qkL, *atL, *hbL;
  float *xG, *yG; unsigned short *xbG, *qkG, *atG, *hbG;
  float *encl, *encg;
  unsigned *cnt, *gen;
};

// attention unit on a 32-lane group (no LDS, shuffle reductions)
__device__ void attn_g32(const unsigned short* __restrict__ qkv,
                         unsigned short* __restrict__ attb,
                         int T_, int B_, int unit) {
  int lane = threadIdx.x & 31;
  int q = unit % T_, h = (unit / T_) % NHH, b = unit / (T_ * NHH);
  float qd = bf2f(qkv[(size_t)(q * B_ + b) * 768 + h * 32 + lane]);
  int nk = (T_ + 31) >> 5;
  float sc[4], mx = -1e30f;
#pragma unroll
  for (int j = 0; j < 4; ++j) {
    float s = -1e30f;
    int k = j * 32 + lane;
    if (j < nk && k < T_) {
      const unsigned short* kp = qkv + (size_t)(k * B_ + b) * 768 + 256 + h * 32;
      float d = 0.f;
#pragma unroll
      for (int i = 0; i < 32; ++i) d += __shfl(qd, i, 32) * bf2f(kp[i]);
      s = d * 0.176776695296636881f;
    }
    sc[j] = s;
    mx = fmaxf(mx, s);
  }
#pragma unroll
  for (int m = 16; m >= 1; m >>= 1) mx = fmaxf(mx, __shfl_xor(mx, m, 32));
  float pj[4], sum = 0.f;
#pragma unroll
  for (int j = 0; j < 4; ++j) {
    float p = (sc[j] > -1e29f) ? expf(sc[j] - mx) : 0.f;
    pj[j] = p; sum += p;
  }
#pragma unroll
  for (int m = 16; m >= 1; m >>= 1) sum += __shfl_xor(sum, m, 32);
  float inv = 1.f / sum;
  const unsigned short* vp = qkv + (size_t)b * 768 + 512 + h * 32 + lane;
  float o = 0.f;
  for (int k = 0; k < T_; ++k) {
    float pk = __shfl(pj[k >> 5], k & 31, 32);
    o += pk * bf2f(vp[(size_t)k * B_ * 768]);
  }
  attb[(size_t)(q * B_ + b) * 256 + h * 32 + lane] = f2bf(o * inv);
}

__device__ void ln_one(const float* __restrict__ X, const float* __restrict__ g,
                       const float* __restrict__ bb, float* __restrict__ Y,
                       unsigned short* __restrict__ Yb, int tok) {
  __shared__ float rs[256], rq[256];
  int c = threadIdx.x;
  float v = X[(size_t)tok * 256 + c];
  rs[c] = v; rq[c] = v * v; __syncthreads();
  for (int o = 128; o > 0; o >>= 1) { if (c < o) { rs[c] += rs[c + o]; rq[c] += rq[c + o]; } __syncthreads(); }
  float mu = rs[0] * (1.f / 256.f);
  float var = rq[0] * (1.f / 256.f) - mu * mu;
  float r = (v - mu) * rsqrtf(var + 1e-5f) * g[c] + bb[c];
  Y[(size_t)tok * 256 + c] = r;
  if (Yb) Yb[(size_t)tok * 256 + c] = f2bf(r);
  __syncthreads();
}

// gemm stage: type 0=qkv, 1=proj, 2=ffn1, 3=ffn2
__device__ void gemm_stage(const EncP& P, int l, int type, int bid) {
  const int mgL = 4, mgG = 7;
  int nyt = (type == 0) ? 12 : (type == 2) ? 16 : 4;
  int ntL = (l < 3) ? mgL * nyt : 0;
  int ntG = mgG * nyt;
  if (bid >= ntL + ntG) return;
  bool isL = bid < ntL;
  int t = isL ? bid : bid - ntL;
  int mg = isL ? mgL : mgG;
  int mx = t % mg, ny = t / mg;
  int M = isL ? 198 : 396;
  const unsigned short* blob = (isL ? P.wL : P.wG) + (size_t)l * 786432;
  const unsigned short* A; const unsigned short* W; const float* bias;
  const float* R = nullptr; float* Yf = nullptr; unsigned short* Yb = nullptr;
  int N, K, flags;
  if (type == 0) {
    A = isL ? P.xbL : P.xbG; W = blob;
    bias = (isL ? P.qbL : P.qbG) + (size_t)l * 768;
    Yb = isL ? P.qkL : P.qkG; N = 768; K = 256; flags = 4 | 8;
  } else if (type == 1) {
    A = isL ? P.atL : P.atG; W = blob + 196608;
    bias = (isL ? P.obL : P.obG) + (size_t)l * 256;
    R = isL ? P.xL : P.xG; Yf = isL ? P.yL : P.yG; N = 256; K = 256; flags = 2;
  } else if (type == 2) {
    A = isL ? P.xbL : P.xbG; W = blob + 262144;
    bias = (isL ? P.l1bL : P.l1bG) + (size_t)l * 1024;
    Yb = isL ? P.hbL : P.hbG; N = 1024; K = 256; flags = 1 | 4 | 8;
  } else {
    A = isL ? P.hbL : P.hbG; W = blob + 524288;
    bias = (isL ? P.l2bL : P.l2bG) + (size_t)l * 256;
    R = isL ? P.xL : P.xG; Yf = isL ? P.yL : P.yG; N = 256; K = 1024; flags = 2;
  }
  gemm_body(A, W, bias, R, Yf, Yb, M, N, K, flags, mx * 64, ny * 64);
}

__device__ void attn_stage(const EncP& P, int l, int bid, int nblk) {
  int NL = (l < 3) ? 6 * NHH * LSTEP : 0;
  int NG = 4 * NHH * T99;
  int ntot = NL + NG;
  int gid = threadIdx.x >> 5;
  for (int u = bid * 8 + gid; u < ntot; u += nblk * 8) {
    if (u < NL) attn_g32(P.qkL, P.atL, LSTEP, 6, u);
    else        attn_g32(P.qkG, P.atG, T99, 4, u - NL);
  }
}

__device__ void ln_stage(const EncP& P, int l, int which, int bid, int nblk) {
  int NLt = (l < 3) ? 198 : 0;
  int ntot = NLt + 396;
  for (int tok = bid; tok < ntot; tok += nblk) {
    if (tok < NLt) {
      const float* g = (which == 1 ? P.n1gL : P.n2gL) + (size_t)l * 256;
      const float* b = (which == 1 ? P.n1bL : P.n2bL) + (size_t)l * 256;
      ln_one(P.yL, g, b, P.xL, P.xbL, tok);
    } else {
      int tg = tok - NLt;
      const float* g = (which == 1 ? P.n1gG : P.n2gG) + (size_t)l * 256;
      const float* b = (which == 1 ? P.n1bG : P.n2bG) + (size_t)l * 256;
      ln_one(P.yG, g, b, P.xG, P.xbG, tg);
    }
  }
}

__global__ __launch_bounds__(256) void k_enc(EncP P) {
  int bid = blockIdx.x, nblk = gridDim.x;
  for (int l = 0; l < 6; ++l) {
    gemm_stage(P, l, 0, bid);        gbar(P.cnt, P.gen, nblk);
    attn_stage(P, l, bid, nblk);     gbar(P.cnt, P.gen, nblk);
    gemm_stage(P, l, 1, bid);        gbar(P.cnt, P.gen, nblk);
    ln_stage(P, l, 1, bid, nblk);    gbar(P.cnt, P.gen, nblk);
    gemm_stage(P, l, 2, bid);        gbar(P.cnt, P.gen, nblk);
    gemm_stage(P, l, 3, bid);        gbar(P.cnt, P.gen, nblk);
    ln_stage(P, l, 2, bid, nblk);    gbar(P.cnt, P.gen, nblk);
  }
  for (int tok = bid; tok < 594; tok += nblk) {
    if (tok < 198) ln_one(P.xL, P.nfgL, P.nfbL, P.encl, nullptr, tok);
    else           ln_one(P.xG, P.nfgG, P.nfbG, P.encg, nullptr, tok - 198);
  }
}

// ---------------- combine ----------------
__global__ __launch_bounds__(256) void k_combine(const float* __restrict__ encl, const float* __restrict__ encg,
                                                 float* __restrict__ base2) {
  int idx = blockIdx.x * 256 + threadIdx.x;
  int t = idx % T99, c = (idx / T99) & 255, b = idx / (CC * T99);
  int ls = t / 3, g = t % 3;
  float v = encl[(size_t)(ls * 6 + g * 2 + b) * 256 + c]
          + encg[(size_t)(t * 4 + b) * 256 + c]
          + encg[(size_t)((98 - t) * 4 + 2 + b) * 256 + c];
  base2[idx] = v;
}

// ---------------- fused s-branch ----------------
__global__ __launch_bounds__(256) void k_sfuse(const float* __restrict__ base2, const float* __restrict__ s1w,
                                               const float* __restrict__ s1b, const float* __restrict__ s2w,
                                               const float* __restrict__ s2b, float* __restrict__ out) {
  __shared__ float rs[256];
  int b = blockIdx.x / T99, t = blockIdx.x % T99, co = threadIdx.x;
  int g = co >> 6;
  float acc = s1b[co];
  const float* xp = base2 + (size_t)(b * CC + g * 64) * T99;
  const float* wp = s1w + (size_t)co * 192;
  for (int ic = 0; ic < 64; ++ic) {
    float x0 = (t > 0)  ? xp[ic * T99 + t - 1] : 0.f;
    float x1 = xp[ic * T99 + t];
    float x2 = (t < 98) ? xp[ic * T99 + t + 1] : 0.f;
    acc += wp[ic * 3] * x0 + wp[ic * 3 + 1] * x1 + wp[ic * 3 + 2] * x2;
  }
  rs[co] = fmaxf(acc, 0.f) * s2w[co];
  __syncthreads();
  for (int o = 128; o > 0; o >>= 1) { if (co < o) rs[co] += rs[co + o]; __syncthreads(); }
  if (co == 0) out[blockIdx.x] = 1.f / (1.f + expf(-(rs[0] + s2b[0])));
}

// ---------------- w3 transpose ----------------
__global__ __launch_bounds__(256) void k_w3t(const float* __restrict__ c3w, float* __restrict__ w3t) {
  int idx = blockIdx.x * 256 + threadIdx.x;
  int co = idx & 255, ci = (idx >> 8) & 255, n = idx >> 16;
  w3t[idx] = c3w[((size_t)(co << 8) + ci) * 32 + n];
}

// ---------------- Gb[n][t][co][b] bf16 + pad row ----------------
__global__ __launch_bounds__(256) void k_G(const float* __restrict__ w3t, const float* __restrict__ base2,
                                           unsigned short* __restrict__ Gb) {
  int tc = blockIdx.x, n = blockIdx.y, b = blockIdx.z;
  int co = threadIdx.x;
  int t0 = tc * 25;
  float acc[25];
#pragma unroll
  for (int q = 0; q < 25; ++q) acc[q] = 0.f;
  const float* w = w3t + (size_t)n * 65536 + co;
  const float* bs = base2 + (size_t)b * CC * T99 + t0;
  for (int ci = 0; ci < 256; ++ci) {
    float wv = w[(size_t)ci * 256];
#pragma unroll
    for (int q = 0; q < 25; ++q) acc[q] += wv * bs[ci * T99 + q];
  }
#pragma unroll
  for (int q = 0; q < 25; ++q) {
    int t = t0 + q;
    if (t < T99) Gb[((size_t)(n * T99 + t) * 256 + co) * 2 + b] = f2bf(acc[q]);
  }
  if (tc == 0 && n == 0 && b == 0)
    ((unsigned int*)(Gb + (size_t)NS_ * T99 * 512))[co] = 0u;
}

// ---------------- p_pre: split-k 256-thread ----------------
__global__ __launch_bounds__(256) void k_ppre(const unsigned short* __restrict__ Gb,
                                              const float* __restrict__ c3b,
                                              unsigned int* __restrict__ pinb32) {
  __shared__ float w0s[96], w1s[96];
  __shared__ int   ofs[96];
  __shared__ float part[128][4];
  int e = blockIdx.x % T99, s = blockIdx.x / T99;
  int tid = threadIdx.x;
  if (s >= e) {
    if (tid < 128) {
      float z0 = fmaxf(c3b[2 * tid], 0.f), z1 = fmaxf(c3b[2 * tid + 1], 0.f);
      unsigned int zz = ((unsigned)f2bf(z1) << 16) | (unsigned)f2bf(z0);
      pinb32[((size_t)s * T99 + e) * 128 + tid] = zz;
      pinb32[((size_t)(T99 + s) * T99 + e) * 128 + tid] = zz;
    }
    return;
  }
  if (tid < 96) {
    double center = (double)(e - s + 1);
    double S = ((double)s - 0.5 * center) + ((2.0 * center - 1.0) / 95.0) * (double)tid;
    double dn = trunc(S);
    double dec = S - dn;
    int di = (int)dn;
    double uc = ceil(S);
    int ui = (int)uc;
    int n = tid / 3;
    float w0 = 0.f, w1 = 0.f;
    int r0 = 0;
    if (dn >= 0.0 && dn <= 98.0) {
      r0 = di;
      w0 = (float)((1.0 - dec) / 3.0);
      if (uc >= 0.0 && uc <= 98.0) {
        if (ui == di) w0 += (float)(dec / 3.0);
        else          w1  = (float)(dec / 3.0);
      }
    }
    w0s[tid] = w0; w1s[tid] = w1;
    ofs[tid] = (n * T99 + r0) * 1024;
  }
  __syncthreads();
  int ch = tid & 127, half = tid >> 7;
  float a00 = 0.f, a01 = 0.f, a10 = 0.f, a11 = 0.f;
  const char* basep = (const char*)Gb + ch * 8;
  int k0 = half * 48;
#pragma unroll 8
  for (int k = k0; k < k0 + 48; ++k) {
    float w0 = w0s[k], w1 = w1s[k];
    const uint2* p = (const uint2*)(basep + ofs[k]);
    uint2 u0 = p[0];
    uint2 u1 = p[128];
    a00 += w0 * blo(u0.x) + w1 * blo(u1.x);
    a01 += w0 * bhi(u0.x) + w1 * bhi(u1.x);
    a10 += w0 * blo(u0.y) + w1 * blo(u1.y);
    a11 += w0 * bhi(u0.y) + w1 * bhi(u1.y);
  }
  if (half) { part[ch][0] = a00; part[ch][1] = a01; part[ch][2] = a10; part[ch][3] = a11; }
  __syncthreads();
  if (tid < 128) {
    a00 += part[ch][0]; a01 += part[ch][1]; a10 += part[ch][2]; a11 += part[ch][3];
    float b0 = c3b[2 * tid], b1 = c3b[2 * tid + 1];
    unsigned int zb0 = ((unsigned)f2bf(fmaxf(a10 + b1, 0.f)) << 16) | (unsigned)f2bf(fmaxf(a00 + b0, 0.f));
    unsigned int zb1 = ((unsigned)f2bf(fmaxf(a11 + b1, 0.f)) << 16) | (unsigned)f2bf(fmaxf(a01 + b0, 0.f));
    pinb32[((size_t)s * T99 + e) * 128 + tid] = zb0;
    pinb32[((size_t)(T99 + s) * T99 + e) * 128 + tid] = zb1;
  }
}

// ---------------- weight pack for conv3x3 ----------------
__global__ __launch_bounds__(256) void k_wb2(const float* __restrict__ pw, unsigned short* __restrict__ wbf) {
  int idx = blockIdx.x * 256 + threadIdx.x;
  if (idx >= 73728) return;
  int lane = idx & 63;
  int cog  = (idx >> 6) & 15;
  int kst  = (idx >> 10) & 7;
  int tap  = idx >> 13;
  int co = cog * 16 + (lane & 15);
  int k  = kst * 32 + (lane >> 4) * 8;
  s8v v;
#pragma unroll
  for (int j = 0; j < 8; ++j)
    v[j] = (short)f2bf(pw[((size_t)co * 256 + k + j) * 9 + tap]);
  *(s8v*)&wbf[(size_t)idx * 8] = v;
}

// ---------------- const-vector for conv const-region ----------------
__global__ __launch_bounds__(256) void k_cvec(const float* __restrict__ pw, const float* __restrict__ cin,
                                              const float* __restrict__ bias, int reluCin,
                                              float* __restrict__ coutF, unsigned short* __restrict__ coutB) {
  __shared__ float rs[256];
  int co = blockIdx.x, ci = threadIdx.x;
  float c = cin[ci];
  if (reluCin) c = fmaxf(c, 0.f);
  const float* wp = pw + ((size_t)co * 256 + ci) * 9;
  float wsum = 0.f;
#pragma unroll
  for (int t = 0; t < 9; ++t) wsum += wp[t];
  rs[ci] = wsum * c;
  __syncthreads();
  for (int o = 128; o > 0; o >>= 1) { if (ci < o) rs[ci] += rs[ci + o]; __syncthreads(); }
  if (ci == 0) {
    float r = fmaxf(bias[co] + rs[0], 0.f);
    coutF[co] = r;
    coutB[co] = f2bf(r);
  }
}

// ---------------- 3x3 conv: halo-LDS, sw-pipelined MFMA, const-region skip ----------------
__device__ __forceinline__ int aoff(int s) {
  int tap = s >> 3, kst = s & 7;
  return ((tap / 3) * 10 + (tap % 3)) * 264 + kst * 32;
}
__device__ __forceinline__ void ldb4(const unsigned short* __restrict__ B0, int s, s8v* dst) {
#pragma unroll
  for (int nt = 0; nt < 4; ++nt) dst[nt] = *(const s8v*)(B0 + (size_t)s * 8192 + nt * 512);
}

__global__ __launch_bounds__(256) void k_conv3x3(const unsigned short* __restrict__ in,
                                                 const unsigned short* __restrict__ wbf,
                                                 const float* __restrict__ bias,
                                                 const unsigned short* __restrict__ cvecB,
                                                 int D, int lo, int hi,
                                                 unsigned short* __restrict__ out) {
  __shared__ __align__(16) unsigned short Ah[100 * 264];
  int b = blockIdx.z;
  int co0 = blockIdx.y * 128;
  int ti = blockIdx.x / 13, tj = blockIdx.x % 13;
  int i0 = ti * 8, j0 = tj * 8;
  int tid = threadIdx.x;

  if (i0 - 1 >= lo && i0 + 8 <= hi && j0 - 1 >= lo && j0 + 8 <= hi && i0 - 1 >= j0 + 8 + D) {
    const unsigned int* cv = (const unsigned int*)(cvecB + co0);
    unsigned int* ob = (unsigned int*)out;
#pragma unroll
    for (int r = 0; r < 16; ++r) {
      int idx = r * 256 + tid;
      int sp = idx >> 6, cp = idx & 63;
      int gi = i0 + (sp >> 3), gj = j0 + (sp & 7);
      ob[((size_t)(b * T99 + gi) * T99 + gj) * 128 + (co0 >> 1) + cp] = cv[cp];
    }
    return;
  }

#pragma unroll
  for (int it = 0; it < 13; ++it) {
    int chunk = it * 256 + tid;
    if (chunk < 3200) {
      int row = chunk >> 5;
      int cc = (chunk & 31) * 8;
      int gi = i0 + row / 10 - 1, gj = j0 + row % 10 - 1;
      s8v val = {0, 0, 0, 0, 0, 0, 0, 0};
      if (gi >= 0 && gi < T99 && gj >= 0 && gj < T99)
        val = *(const s8v*)&in[((size_t)(b * T99 + gi) * T99 + gj) * 256 + cc];
      *(s8v*)&Ah[row * 264 + cc] = val;
    }
  }
  __syncthreads();

  int lane = tid & 63, w = tid >> 6, wm = w >> 1, wn = w & 1;
  int l15 = lane & 15, lk = lane >> 4;
  int spL0 = wm * 32 + l15, spL1 = spL0 + 16;
  int hr0 = (spL0 >> 3) * 10 + (spL0 & 7);
  int hr1 = (spL1 >> 3) * 10 + (spL1 & 7);
  const unsigned short* A0 = &Ah[hr0 * 264 + lk * 8];
  const unsigned short* A1 = &Ah[hr1 * 264 + lk * 8];
  int cogbase = blockIdx.y * 8 + wn * 4;
  const unsigned short* B0 = wbf + (size_t)cogbase * 512 + (size_t)lane * 8;

  f4v acc[2][4];
#pragma unroll
  for (int mt = 0; mt < 2; ++mt)
#pragma unroll
    for (int nt = 0; nt < 4; ++nt) acc[mt][nt] = (f4v){0.f, 0.f, 0.f, 0.f};

  s8v a0c, a1c, a0n, a1n;
  s8v bq[3][4];
  a0c = *(const s8v*)(A0 + aoff(0));
  a1c = *(const s8v*)(A1 + aoff(0));
  a0n = a0c; a1n = a1c;
  ldb4(B0, 0, bq[0]);
  ldb4(B0, 1, bq[1]);
#pragma unroll
  for (int s = 0; s < 72; ++s) {
    if (s + 2 < 72) ldb4(B0, s + 2, bq[(s + 2) % 3]);
    if (s + 1 < 72) {
      a0n = *(const s8v*)(A0 + aoff(s + 1));
      a1n = *(const s8v*)(A1 + aoff(s + 1));
    }
#pragma unroll
    for (int nt = 0; nt < 4; ++nt) {
      mfma_bf16(acc[0][nt], a0c, bq[s % 3][nt]);
      mfma_bf16(acc[1][nt], a1c, bq[s % 3][nt]);
    }
    a0c = a0n; a1c = a1n;
  }

  asm volatile("s_nop 7\n\ts_nop 7\n\ts_nop 4");
#pragma unroll
  for (int mt = 0; mt < 2; ++mt) {
#pragma unroll
    for (int nt = 0; nt < 4; ++nt) {
      int co = co0 + wn * 64 + nt * 16 + l15;
      float bv = bias[co];
#pragma unroll
      for (int r = 0; r < 4; ++r) {
        int sp = wm * 32 + mt * 16 + lk * 4 + r;
        int gi = i0 + (sp >> 3), gj = j0 + (sp & 7);
        if (gi < T99 && gj < T99) {
          float v = fmaxf(acc[mt][nt][r] + bv, 0.f);
          out[((size_t)(b * T99 + gi) * T99 + gj) * 256 + co] = f2bf(v);
        }
      }
    }
  }
}

// ---------------- p3: both channels per row ----------------
__global__ __launch_bounds__(256) void k_p3(const unsigned short* __restrict__ p2o,
                                            const float* __restrict__ w, const float* __restrict__ bias,
                                            float* __restrict__ cm) {
  int idx = blockIdx.x * 256 + threadIdx.x;
  if (idx >= 2 * T99 * T99) return;
  int j = idx % T99, i = (idx / T99) % T99, b = idx / (T99 * T99);
  float a0 = bias[0], a1 = bias[1];
  const unsigned short* row = p2o + ((size_t)(b * T99 + i) * T99 + j) * 256;
  for (int c8 = 0; c8 < 256; c8 += 8) {
    s8v v = *(const s8v*)&row[c8];
#pragma unroll
    for (int q = 0; q < 8; ++q) {
      float x = bf2f((unsigned short)v[q]);
      a0 += w[c8 + q] * x;
      a1 += w[256 + c8 + q] * x;
    }
  }
  size_t base = (size_t)b * 2 * T99 * T99 + (size_t)i * T99 + j;
  cm[base] = 1.f / (1.f + expf(-a0));
  cm[base + T99 * T99] = 1.f / (1.f + expf(-a1));
}

// ---------------- host ----------------
extern "C" void kernel_launch(void* const* d_in, const int* in_sizes, int n_in,
                              void* d_out, int out_size, void* d_ws, size_t ws_size,
                              hipStream_t stream) {
  (void)in_sizes; (void)n_in; (void)out_size; (void)ws_size;
  const float* x    = (const float*)d_in[0];
  const float* cbw  = (const float*)d_in[1];
  const float* cbb  = (const float*)d_in[2];
  const float* tg_qkvw = (const float*)d_in[3];
  const float* tg_qkvb = (const float*)d_in[4];
  const float* tg_ow   = (const float*)d_in[5];
  const float* tg_ob   = (const float*)d_in[6];
  const float* tg_l1w  = (const float*)d_in[7];
  const float* tg_l1b  = (const float*)d_in[8];
  const float* tg_l2w  = (const float*)d_in[9];
  const float* tg_l2b  = (const float*)d_in[10];
  const float* tg_n1g  = (const float*)d_in[11];
  const float* tg_n1b  = (const float*)d_in[12];
  const float* tg_n2g  = (const float*)d_in[13];
  const float* tg_n2b  = (const float*)d_in[14];
  const float* tg_nfg  = (const float*)d_in[15];
  const float* tg_nfb  = (const float*)d_in[16];
  const float* tl_qkvw = (const float*)d_in[17];
  const float* tl_qkvb = (const float*)d_in[18];
  const float* tl_ow   = (const float*)d_in[19];
  const float* tl_ob   = (const float*)d_in[20];
  const float* tl_l1w  = (const float*)d_in[21];
  const float* tl_l1b  = (const float*)d_in[22];
  const float* tl_l2w  = (const float*)d_in[23];
  const float* tl_l2b  = (const float*)d_in[24];
  const float* tl_n1g  = (const float*)d_in[25];
  const float* tl_n1b  = (const float*)d_in[26];
  const float* tl_n2g  = (const float*)d_in[27];
  const float* tl_n2b  = (const float*)d_in[28];
  const float* tl_nfg  = (const float*)d_in[29];
  const float* tl_nfb  = (const float*)d_in[30];
  const float* s1w = (const float*)d_in[31];
  const float* s1b = (const float*)d_in[32];
  const float* s2w = (const float*)d_in[33];
  const float* s2b = (const float*)d_in[34];
  const float* c3w = (const float*)d_in[35];
  const float* c3b = (const float*)d_in[36];
  const float* p1w = (const float*)d_in[37];
  const float* p1b = (const float*)d_in[38];
  const float* p2w = (const float*)d_in[39];
  const float* p2b = (const float*)d_in[40];
  const float* p3w = (const float*)d_in[41];
  const float* p3b = (const float*)d_in[42];

  float* outp = (float*)d_out; // [cm 39204][start1 198]

  char* wp = (char*)d_ws;
  auto alloc = [&](size_t bytes) -> void* {
    void* p = (void*)wp;
    wp += (bytes + 255) & ~(size_t)255;
    return p;
  };
  float* base  = (float*)alloc(sizeof(float) * 2 * CC * T99);
  const int ML = 198, MG = 396;
  EncP P = {};
  P.xG   = (float*)alloc(sizeof(float) * MG * 256);
  P.xL   = (float*)alloc(sizeof(float) * ML * 256);
  P.xbG  = (unsigned short*)alloc(sizeof(short) * MG * 256);
  P.xbL  = (unsigned short*)alloc(sizeof(short) * ML * 256);
  P.yG   = (float*)alloc(sizeof(float) * MG * 256);
  P.yL   = (float*)alloc(sizeof(float) * ML * 256);
  P.qkG  = (unsigned short*)alloc(sizeof(short) * MG * 768);
  P.qkL  = (unsigned short*)alloc(sizeof(short) * ML * 768);
  P.atG  = (unsigned short*)alloc(sizeof(short) * MG * 256);
  P.atL  = (unsigned short*)alloc(sizeof(short) * ML * 256);
  P.hbG  = (unsigned short*)alloc(sizeof(short) * MG * 1024);
  P.hbL  = (unsigned short*)alloc(sizeof(short) * ML * 1024);
  float* encg  = (float*)alloc(sizeof(float) * MG * 256);
  float* encl  = (float*)alloc(sizeof(float) * ML * 256);
  float* base2 = (float*)alloc(sizeof(float) * 2 * CC * T99);
  float* w3t   = (float*)alloc(sizeof(float) * 32 * 256 * 256);
  unsigned short* Gb = (unsigned short*)alloc(sizeof(short) * (2 * NS_ * T99 * 256 + 512));
  unsigned short* pinb = (unsigned short*)alloc(sizeof(short) * 2 * T99 * T99 * 256);
  unsigned short* p1o  = (unsigned short*)alloc(sizeof(short) * 2 * T99 * T99 * 256);
  unsigned short* p2o  = (unsigned short*)alloc(sizeof(short) * 2 * T99 * T99 * 256);
  unsigned short* wb2a = (unsigned short*)alloc(sizeof(short) * 9 * 256 * 256);
  unsigned short* wb2b = (unsigned short*)alloc(sizeof(short) * 9 * 256 * 256);
  unsigned short* wpg  = (unsigned short*)alloc(sizeof(short) * 6 * 786432);
  unsigned short* wpl  = (unsigned short*)alloc(sizeof(short) * 3 * 786432);
  float* c1F = (float*)alloc(sizeof(float) * 256);
  unsigned short* c1B = (unsigned short*)alloc(sizeof(short) * 256);
  float* c2F = (float*)alloc(sizeof(float) * 256);
  unsigned short* c2B = (unsigned short*)alloc(sizeof(short) * 256);
  unsigned* barbuf = (unsigned*)alloc(sizeof(unsigned) * 64);

  P.wL = wpl; P.wG = wpg;
  P.qbL = tl_qkvb; P.obL = tl_ob; P.l1bL = tl_l1b; P.l2bL = tl_l2b;
  P.n1gL = tl_n1g; P.n1bL = tl_n1b; P.n2gL = tl_n2g; P.n2bL = tl_n2b;
  P.nfgL = tl_nfg; P.nfbL = tl_nfb;
  P.qbG = tg_qkvb; P.obG = tg_ob; P.l1bG = tg_l1b; P.l2bG = tg_l2b;
  P.n1gG = tg_n1g; P.n1bG = tg_n1b; P.n2gG = tg_n2g; P.n2bG = tg_n2b;
  P.nfgG = tg_nfg; P.nfbG = tg_nfb;
  P.encl = encl; P.encg = encg;
  P.cnt = barbuf; P.gen = barbuf + 32;

  // 0. preamble
  k_zero<<<dim3(1), dim3(64), 0, stream>>>(barbuf);
  k_convW<<<dim3(4096), dim3(256), 0, stream>>>(tg_qkvw, tg_ow, tg_l1w, tg_l2w, 6, wpg);
  k_convW<<<dim3(2048), dim3(256), 0, stream>>>(tl_qkvw, tl_ow, tl_l1w, tl_l2w, 3, wpl);
  k_w3t<<<dim3(8192), dim3(256), 0, stream>>>(c3w, w3t);
  k_wb2<<<dim3(288), dim3(256), 0, stream>>>(p1w, wb2a);
  k_wb2<<<dim3(288), dim3(256), 0, stream>>>(p2w, wb2b);
  k_cvec<<<dim3(256), dim3(256), 0, stream>>>(p1w, c3b, p1b, 1, c1F, c1B);
  k_cvec<<<dim3(256), dim3(256), 0, stream>>>(p2w, c1F, p2b, 0, c2F, c2B);
  // 1. conv stem + encoder inputs
  k_convbase<<<dim3(512), dim3(128), 0, stream>>>(x, cbw, cbb, base);
  k_build_xl<<<dim3(198), dim3(256), 0, stream>>>(base, P.xL, P.xbL);
  k_build_xg<<<dim3(396), dim3(256), 0, stream>>>(base, P.xG, P.xbG);
  // 2. persistent dual-encoder megakernel
  k_enc<<<dim3(176), dim3(256), 0, stream>>>(P);
  // 3. combine + s-branch
  k_combine<<<dim3(198), dim3(256), 0, stream>>>(encl, encg, base2);
  k_sfuse<<<dim3(198), dim3(256), 0, stream>>>(base2, s1w, s1b, s2w, s2b, outp + 2 * 2 * T99 * T99);
  // 4. bm + conv3d
  k_G<<<dim3(4, 32, 2), dim3(256), 0, stream>>>(w3t, base2, Gb);
  k_ppre<<<dim3(T99 * T99), dim3(256), 0, stream>>>(Gb, c3b, (unsigned int*)pinb);
  // 5. p-branch
  k_conv3x3<<<dim3(169, 2, 2), dim3(256), 0, stream>>>(pinb, wb2a, p1b, c1B, 0, 0, 98, p1o);
  k_conv3x3<<<dim3(169, 2, 2), dim3(256), 0, stream>>>(p1o, wb2b, p2b, c2B, 2, 1, 97, p2o);
  k_p3<<<dim3(77), dim3(256), 0, stream>>>(p2o, p3w, p3b, outp);
}

// Round 10
// 688.137 us; speedup vs baseline: 1.6311x; 1.6311x over previous
//
#include <hip/hip_runtime.h>
#include <math.h>

// ---------------- constants ----------------
#define T99   99
#define CC    256
#define NHH   8
#define FEAT  400
#define NS_   32
#define LSTEP 33

typedef __attribute__((ext_vector_type(8))) short s8v;   // 8 x bf16 (as raw u16)
typedef __attribute__((ext_vector_type(4))) float f4v;   // MFMA accumulator

// non-volatile asm: data deps preserve correctness, scheduler may interleave loads
__device__ __forceinline__ void mfma_bf16(f4v& d, s8v a, s8v b) {
  asm("v_mfma_f32_16x16x32_bf16 %0, %1, %2, %0" : "+v"(d) : "v"(a), "v"(b));
}

__device__ __forceinline__ unsigned short f2bf(float f) {
  union { float f; unsigned u; } x; x.f = f;
  unsigned r = x.u + 0x7FFFu + ((x.u >> 16) & 1u);
  return (unsigned short)(r >> 16);
}
__device__ __forceinline__ float bf2f(unsigned short h) {
  union { unsigned u; float f; } x; x.u = ((unsigned)h) << 16;
  return x.f;
}
__device__ __forceinline__ float blo(unsigned u) { union { unsigned x; float f; } c; c.x = u << 16; return c.f; }
__device__ __forceinline__ float bhi(unsigned u) { union { unsigned x; float f; } c; c.x = u & 0xffff0000u; return c.f; }

__device__ __forceinline__ float pe_val(int pos, int c) {
  int i = c >> 1;
  float freq = expf((float)(2 * i) * (-0.03597789207803197f)); // -ln(10000)/256
  float ang = (float)pos * freq;
  return (c & 1) ? cosf(ang) : sinf(ang);
}

// ---------------- conv stem ----------------
__global__ __launch_bounds__(128) void k_convbase(const float* __restrict__ x,
                                                  const float* __restrict__ w,
                                                  const float* __restrict__ bias,
                                                  float* __restrict__ base) {
  int b = blockIdx.x >> 8, co = blockIdx.x & 255, t = threadIdx.x;
  if (t >= T99) return;
  int g = co >> 6;
  float acc = bias[co];
  const float* xp = x + (size_t)(b * FEAT + g * 100) * T99;
  const float* wp = w + (size_t)co * 300;
  for (int ic = 0; ic < 100; ++ic) {
    float x0 = (t > 0)  ? xp[ic * T99 + t - 1] : 0.f;
    float x1 = xp[ic * T99 + t];
    float x2 = (t < 98) ? xp[ic * T99 + t + 1] : 0.f;
    acc += wp[ic * 3] * x0 + wp[ic * 3 + 1] * x1 + wp[ic * 3 + 2] * x2;
  }
  base[(size_t)(b * CC + co) * T99 + t] = fmaxf(acc, 0.f);
}

// ---------------- weight conversion: pack {qkv,o,l1,l2} per layer into bf16 row-major blob ----------------
__global__ __launch_bounds__(256) void k_convW(const float* __restrict__ qkv, const float* __restrict__ o,
                                               const float* __restrict__ l1, const float* __restrict__ l2,
                                               int L, unsigned short* __restrict__ dst) {
  int total = L * 786432;
  for (int idx = blockIdx.x * 256 + threadIdx.x; idx < total; idx += gridDim.x * 256) {
    int l = idx / 786432, r = idx % 786432;
    float v;
    if (r < 196608)      v = qkv[(size_t)l * 196608 + r];
    else if (r < 262144) v = o[(size_t)l * 65536 + (r - 196608)];
    else if (r < 524288) v = l1[(size_t)l * 262144 + (r - 262144)];
    else                 v = l2[(size_t)l * 262144 + (r - 524288)];
    dst[idx] = f2bf(v);
  }
}

// ---------------- build encoder inputs ----------------
__global__ __launch_bounds__(256) void k_build_xg(const float* __restrict__ base, float* __restrict__ xg,
                                                  unsigned short* __restrict__ xgb) {
  int idx = blockIdx.x * 256 + threadIdx.x;
  int t = idx >> 10, r = idx & 1023, b4 = r >> 8, c = r & 255;
  float v = (b4 < 2) ? base[(size_t)(b4 * CC + c) * T99 + t]
                     : base[(size_t)((b4 - 2) * CC + c) * T99 + (98 - t)];
  v += pe_val(t, c);
  xg[idx] = v; xgb[idx] = f2bf(v);
}

__global__ __launch_bounds__(256) void k_build_xl(const float* __restrict__ base, float* __restrict__ xl,
                                                  unsigned short* __restrict__ xlb) {
  int idx = blockIdx.x * 256 + threadIdx.x;
  int ls = idx / 1536, r = idx % 1536, j = r >> 8, c = r & 255;
  int g = j >> 1, b = j & 1, t = ls * 3 + g;
  float v = base[(size_t)(b * CC + c) * T99 + t] + pe_val(ls, c);
  xl[idx] = v; xlb[idx] = f2bf(v);
}

// ================= GEMM: one-shot 64x256 LDS chunk staging, barrier-free kstep loop =================
// flags: 1=relu, 2=residual R, 4=write bf16 Yb, 8=skip fp32 Yf
struct GJ {
  const unsigned short* Ab;   // bf16 row-major [M][K]
  const unsigned short* W;    // bf16 row-major [N][K]
  const float* bias;
  const float* R;
  float* Yf;
  unsigned short* Yb;
  int M, N, K, flags;
};

__device__ void g_body(const GJ& j, int m0, int n0) {
  __shared__ __align__(16) unsigned short Al[64][264];
  __shared__ __align__(16) unsigned short Bl[64][264];
  int tid = threadIdx.x, lane = tid & 63, w = tid >> 6, wm = w >> 1, wn = w & 1;
  f4v acc[2][2];
#pragma unroll
  for (int mt = 0; mt < 2; ++mt)
#pragma unroll
    for (int nt = 0; nt < 2; ++nt) acc[mt][nt] = (f4v){0.f, 0.f, 0.f, 0.f};

  for (int kc0 = 0; kc0 < j.K; kc0 += 256) {
    // stage A 64x256 + B 64x256 with ONE barrier
#pragma unroll
    for (int it = 0; it < 8; ++it) {
      int idx = it * 256 + tid, row = idx >> 5, seg = (idx & 31) << 3;
      s8v av = {0, 0, 0, 0, 0, 0, 0, 0};
      if (m0 + row < j.M) av = *(const s8v*)&j.Ab[(size_t)(m0 + row) * j.K + kc0 + seg];
      *(s8v*)&Al[row][seg] = av;
      *(s8v*)&Bl[row][seg] = *(const s8v*)&j.W[(size_t)(n0 + row) * j.K + kc0 + seg];
    }
    __syncthreads();
#pragma unroll
    for (int kst = 0; kst < 8; ++kst) {
      int kcol = kst * 32 + (lane >> 4) * 8;
      s8v af[2], bf[2];
#pragma unroll
      for (int mt = 0; mt < 2; ++mt)
        af[mt] = *(const s8v*)&Al[wm * 32 + mt * 16 + (lane & 15)][kcol];
#pragma unroll
      for (int nt = 0; nt < 2; ++nt)
        bf[nt] = *(const s8v*)&Bl[wn * 32 + nt * 16 + (lane & 15)][kcol];
#pragma unroll
      for (int mt = 0; mt < 2; ++mt)
#pragma unroll
        for (int nt = 0; nt < 2; ++nt) mfma_bf16(acc[mt][nt], af[mt], bf[nt]);
    }
    __syncthreads();
  }
  asm volatile("s_nop 7\n\ts_nop 7\n\ts_nop 4");
#pragma unroll
  for (int mt = 0; mt < 2; ++mt) {
#pragma unroll
    for (int nt = 0; nt < 2; ++nt) {
      int col = n0 + wn * 32 + nt * 16 + (lane & 15);
      float bv = j.bias[col];
#pragma unroll
      for (int r = 0; r < 4; ++r) {
        int row = m0 + wm * 32 + mt * 16 + (lane >> 4) * 4 + r;
        if (row < j.M) {
          float v = acc[mt][nt][r] + bv;
          if (j.flags & 2) v += j.R[(size_t)row * j.N + col];
          if (j.flags & 1) v = fmaxf(v, 0.f);
          if (!(j.flags & 8)) j.Yf[(size_t)row * j.N + col] = v;
          if (j.flags & 4) j.Yb[(size_t)row * j.N + col] = f2bf(v);
        }
      }
    }
  }
}

__global__ __launch_bounds__(256) void k_g(GJ j) {
  if ((int)blockIdx.x * 64 >= j.M) return;
  g_body(j, blockIdx.x * 64, blockIdx.y * 64);
}

__global__ __launch_bounds__(256) void k_g2(GJ j0, GJ j1) {
  if (blockIdx.z == 0) {
    if ((int)blockIdx.x * 64 >= j0.M) return;
    g_body(j0, blockIdx.x * 64, blockIdx.y * 64);
  } else {
    if ((int)blockIdx.x * 64 >= j1.M) return;
    g_body(j1, blockIdx.x * 64, blockIdx.y * 64);
  }
}

// ---------------- attention (PV 4-way split) ----------------
__device__ __forceinline__ void attn_body(const unsigned short* __restrict__ qkv,
                                          unsigned short* __restrict__ attb,
                                          int T_, int B_, int bid) {
  __shared__ float qv[32];
  __shared__ float red[128];
  __shared__ float pv[128];
  int tid = threadIdx.x;
  int q = bid % T_;
  int h = (bid / T_) % NHH;
  int b = bid / (T_ * NHH);
  if (tid < 32) qv[tid] = bf2f(qkv[(size_t)(q * B_ + b) * 768 + h * 32 + tid]);
  __syncthreads();
  float s = -1e30f;
  if (tid < T_) {
    const unsigned short* kp = qkv + (size_t)(tid * B_ + b) * 768 + 256 + h * 32;
    float d = 0;
#pragma unroll
    for (int i = 0; i < 32; ++i) d += qv[i] * bf2f(kp[i]);
    s = d * 0.176776695296636881f; // 1/sqrt(32)
  }
  red[tid] = s; __syncthreads();
  for (int o = 64; o > 0; o >>= 1) { if (tid < o) red[tid] = fmaxf(red[tid], red[tid + o]); __syncthreads(); }
  float mx = red[0]; __syncthreads();
  float p = (tid < T_) ? expf(s - mx) : 0.f;
  pv[tid] = p; red[tid] = p; __syncthreads();
  for (int o = 64; o > 0; o >>= 1) { if (tid < o) red[tid] += red[tid + o]; __syncthreads(); }
  float denom = red[0];
  __syncthreads();
  int d = tid & 31, part = tid >> 5;
  float o = 0.f;
  for (int k = part; k < T_; k += 4)
    o += pv[k] * bf2f(qkv[(size_t)(k * B_ + b) * 768 + 512 + h * 32 + d]);
  red[tid] = o; __syncthreads();
  if (tid < 32) {
    float t = red[tid] + red[tid + 32] + red[tid + 64] + red[tid + 96];
    attb[(size_t)(q * B_ + b) * 256 + h * 32 + tid] = f2bf(t / denom);
  }
}

__global__ __launch_bounds__(128) void k_attn(const unsigned short* __restrict__ qkv,
                                              unsigned short* __restrict__ attb, int T_, int B_) {
  attn_body(qkv, attb, T_, B_, blockIdx.x);
}

__global__ __launch_bounds__(128) void k_attn2(const unsigned short* __restrict__ qkv0,
                                               unsigned short* __restrict__ attb0, int T0, int B0,
                                               const unsigned short* __restrict__ qkv1,
                                               unsigned short* __restrict__ attb1, int T1, int B1) {
  int bid = blockIdx.x;
  if (blockIdx.z == 0) {
    if (bid >= B0 * NHH * T0) return;
    attn_body(qkv0, attb0, T0, B0, bid);
  } else {
    if (bid >= B1 * NHH * T1) return;
    attn_body(qkv1, attb1, T1, B1, bid);
  }
}

// ---------------- layer norm (fp32 out + optional bf16 mirror) ----------------
__device__ __forceinline__ void ln_body(const float* __restrict__ X, const float* __restrict__ g,
                                        const float* __restrict__ bb, float* __restrict__ Y,
                                        unsigned short* __restrict__ Yb, int tok) {
  __shared__ float rs[256], rq[256];
  int c = threadIdx.x;
  float v = X[(size_t)tok * 256 + c];
  rs[c] = v; rq[c] = v * v; __syncthreads();
  for (int o = 128; o > 0; o >>= 1) { if (c < o) { rs[c] += rs[c + o]; rq[c] += rq[c + o]; } __syncthreads(); }
  float mu = rs[0] * (1.f / 256.f);
  float var = rq[0] * (1.f / 256.f) - mu * mu;
  float r = (v - mu) * rsqrtf(var + 1e-5f) * g[c] + bb[c];
  Y[(size_t)tok * 256 + c] = r;
  if (Yb) Yb[(size_t)tok * 256 + c] = f2bf(r);
}

__global__ __launch_bounds__(256) void k_ln(const float* __restrict__ X, const float* __restrict__ g,
                                            const float* __restrict__ bb, float* __restrict__ Y,
                                            unsigned short* __restrict__ Yb) {
  ln_body(X, g, bb, Y, Yb, blockIdx.x);
}

__global__ __launch_bounds__(256) void k_ln2(const float* __restrict__ X0, const float* __restrict__ g0,
                                             const float* __restrict__ bb0, float* __restrict__ Y0,
                                             unsigned short* __restrict__ Yb0, int n0,
                                             const float* __restrict__ X1, const float* __restrict__ g1,
                                             const float* __restrict__ bb1, float* __restrict__ Y1,
                                             unsigned short* __restrict__ Yb1, int n1) {
  int tok = blockIdx.x;
  if (blockIdx.z == 0) { if (tok < n0) ln_body(X0, g0, bb0, Y0, Yb0, tok); }
  else                 { if (tok < n1) ln_body(X1, g1, bb1, Y1, Yb1, tok); }
}

// ---------------- combine ----------------
__global__ __launch_bounds__(256) void k_combine(const float* __restrict__ encl, const float* __restrict__ encg,
                                                 float* __restrict__ base2) {
  int idx = blockIdx.x * 256 + threadIdx.x;
  int t = idx % T99, c = (idx / T99) & 255, b = idx / (CC * T99);
  int ls = t / 3, g = t % 3;
  float v = encl[(size_t)(ls * 6 + g * 2 + b) * 256 + c]
          + encg[(size_t)(t * 4 + b) * 256 + c]
          + encg[(size_t)((98 - t) * 4 + 2 + b) * 256 + c];
  base2[idx] = v;
}

// ---------------- fused s-branch ----------------
__global__ __launch_bounds__(256) void k_sfuse(const float* __restrict__ base2, const float* __restrict__ s1w,
                                               const float* __restrict__ s1b, const float* __restrict__ s2w,
                                               const float* __restrict__ s2b, float* __restrict__ out) {
  __shared__ float rs[256];
  int b = blockIdx.x / T99, t = blockIdx.x % T99, co = threadIdx.x;
  int g = co >> 6;
  float acc = s1b[co];
  const float* xp = base2 + (size_t)(b * CC + g * 64) * T99;
  const float* wp = s1w + (size_t)co * 192;
  for (int ic = 0; ic < 64; ++ic) {
    float x0 = (t > 0)  ? xp[ic * T99 + t - 1] : 0.f;
    float x1 = xp[ic * T99 + t];
    float x2 = (t < 98) ? xp[ic * T99 + t + 1] : 0.f;
    acc += wp[ic * 3] * x0 + wp[ic * 3 + 1] * x1 + wp[ic * 3 + 2] * x2;
  }
  rs[co] = fmaxf(acc, 0.f) * s2w[co];
  __syncthreads();
  for (int o = 128; o > 0; o >>= 1) { if (co < o) rs[co] += rs[co + o]; __syncthreads(); }
  if (co == 0) out[blockIdx.x] = 1.f / (1.f + expf(-(rs[0] + s2b[0])));
}

// ---------------- w3 transpose ----------------
__global__ __launch_bounds__(256) void k_w3t(const float* __restrict__ c3w, float* __restrict__ w3t) {
  int idx = blockIdx.x * 256 + threadIdx.x;
  int co = idx & 255, ci = (idx >> 8) & 255, n = idx >> 16;
  w3t[idx] = c3w[((size_t)(co << 8) + ci) * 32 + n];
}

// ---------------- Gb[n][t][co][b] bf16 + pad row ----------------
__global__ __launch_bounds__(256) void k_G(const float* __restrict__ w3t, const float* __restrict__ base2,
                                           unsigned short* __restrict__ Gb) {
  int tc = blockIdx.x, n = blockIdx.y, b = blockIdx.z;
  int co = threadIdx.x;
  int t0 = tc * 25;
  float acc[25];
#pragma unroll
  for (int q = 0; q < 25; ++q) acc[q] = 0.f;
  const float* w = w3t + (size_t)n * 65536 + co;
  const float* bs = base2 + (size_t)b * CC * T99 + t0;
  for (int ci = 0; ci < 256; ++ci) {
    float wv = w[(size_t)ci * 256];
#pragma unroll
    for (int q = 0; q < 25; ++q) acc[q] += wv * bs[ci * T99 + q];
  }
#pragma unroll
  for (int q = 0; q < 25; ++q) {
    int t = t0 + q;
    if (t < T99) Gb[((size_t)(n * T99 + t) * 256 + co) * 2 + b] = f2bf(acc[q]);
  }
  if (tc == 0 && n == 0 && b == 0)
    ((unsigned int*)(Gb + (size_t)NS_ * T99 * 512))[co] = 0u;
}

// ---------------- p_pre: split-k 256-thread ----------------
__global__ __launch_bounds__(256) void k_ppre(const unsigned short* __restrict__ Gb,
                                              const float* __restrict__ c3b,
                                              unsigned int* __restrict__ pinb32) {
  __shared__ float w0s[96], w1s[96];
  __shared__ int   ofs[96];
  __shared__ float part[128][4];
  int e = blockIdx.x % T99, s = blockIdx.x / T99;
  int tid = threadIdx.x;
  if (s >= e) {
    if (tid < 128) {
      float z0 = fmaxf(c3b[2 * tid], 0.f), z1 = fmaxf(c3b[2 * tid + 1], 0.f);
      unsigned int zz = ((unsigned)f2bf(z1) << 16) | (unsigned)f2bf(z0);
      pinb32[((size_t)s * T99 + e) * 128 + tid] = zz;
      pinb32[((size_t)(T99 + s) * T99 + e) * 128 + tid] = zz;
    }
    return;
  }
  if (tid < 96) {
    double center = (double)(e - s + 1);
    double S = ((double)s - 0.5 * center) + ((2.0 * center - 1.0) / 95.0) * (double)tid;
    double dn = trunc(S);
    double dec = S - dn;
    int di = (int)dn;
    double uc = ceil(S);
    int ui = (int)uc;
    int n = tid / 3;
    float w0 = 0.f, w1 = 0.f;
    int r0 = 0;
    if (dn >= 0.0 && dn <= 98.0) {
      r0 = di;
      w0 = (float)((1.0 - dec) / 3.0);
      if (uc >= 0.0 && uc <= 98.0) {
        if (ui == di) w0 += (float)(dec / 3.0);
        else          w1  = (float)(dec / 3.0);
      }
    }
    w0s[tid] = w0; w1s[tid] = w1;
    ofs[tid] = (n * T99 + r0) * 1024;
  }
  __syncthreads();
  int ch = tid & 127, half = tid >> 7;
  float a00 = 0.f, a01 = 0.f, a10 = 0.f, a11 = 0.f;
  const char* basep = (const char*)Gb + ch * 8;
  int k0 = half * 48;
#pragma unroll 8
  for (int k = k0; k < k0 + 48; ++k) {
    float w0 = w0s[k], w1 = w1s[k];
    const uint2* p = (const uint2*)(basep + ofs[k]);
    uint2 u0 = p[0];
    uint2 u1 = p[128];
    a00 += w0 * blo(u0.x) + w1 * blo(u1.x);
    a01 += w0 * bhi(u0.x) + w1 * bhi(u1.x);
    a10 += w0 * blo(u0.y) + w1 * blo(u1.y);
    a11 += w0 * bhi(u0.y) + w1 * bhi(u1.y);
  }
  if (half) { part[ch][0] = a00; part[ch][1] = a01; part[ch][2] = a10; part[ch][3] = a11; }
  __syncthreads();
  if (tid < 128) {
    a00 += part[ch][0]; a01 += part[ch][1]; a10 += part[ch][2]; a11 += part[ch][3];
    float b0 = c3b[2 * tid], b1 = c3b[2 * tid + 1];
    unsigned int zb0 = ((unsigned)f2bf(fmaxf(a10 + b1, 0.f)) << 16) | (unsigned)f2bf(fmaxf(a00 + b0, 0.f));
    unsigned int zb1 = ((unsigned)f2bf(fmaxf(a11 + b1, 0.f)) << 16) | (unsigned)f2bf(fmaxf(a01 + b0, 0.f));
    pinb32[((size_t)s * T99 + e) * 128 + tid] = zb0;
    pinb32[((size_t)(T99 + s) * T99 + e) * 128 + tid] = zb1;
  }
}

// ---------------- weight pack for conv3x3 ----------------
__global__ __launch_bounds__(256) void k_wb2(const float* __restrict__ pw, unsigned short* __restrict__ wbf) {
  int idx = blockIdx.x * 256 + threadIdx.x;
  if (idx >= 73728) return;
  int lane = idx & 63;
  int cog  = (idx >> 6) & 15;
  int kst  = (idx >> 10) & 7;
  int tap  = idx >> 13;
  int co = cog * 16 + (lane & 15);
  int k  = kst * 32 + (lane >> 4) * 8;
  s8v v;
#pragma unroll
  for (int j = 0; j < 8; ++j)
    v[j] = (short)f2bf(pw[((size_t)co * 256 + k + j) * 9 + tap]);
  *(s8v*)&wbf[(size_t)idx * 8] = v;
}

// ---------------- const-vector for conv const-region ----------------
__global__ __launch_bounds__(256) void k_cvec(const float* __restrict__ pw, const float* __restrict__ cin,
                                              const float* __restrict__ bias, int reluCin,
                                              float* __restrict__ coutF, unsigned short* __restrict__ coutB) {
  __shared__ float rs[256];
  int co = blockIdx.x, ci = threadIdx.x;
  float c = cin[ci];
  if (reluCin) c = fmaxf(c, 0.f);
  const float* wp = pw + ((size_t)co * 256 + ci) * 9;
  float wsum = 0.f;
#pragma unroll
  for (int t = 0; t < 9; ++t) wsum += wp[t];
  rs[ci] = wsum * c;
  __syncthreads();
  for (int o = 128; o > 0; o >>= 1) { if (ci < o) rs[ci] += rs[ci + o]; __syncthreads(); }
  if (ci == 0) {
    float r = fmaxf(bias[co] + rs[0], 0.f);
    coutF[co] = r;
    coutB[co] = f2bf(r);
  }
}

// ---------------- 3x3 conv: halo-LDS, sw-pipelined MFMA, const-region skip ----------------
__device__ __forceinline__ int aoff(int s) {
  int tap = s >> 3, kst = s & 7;
  return ((tap / 3) * 10 + (tap % 3)) * 264 + kst * 32;
}
__device__ __forceinline__ void ldb4(const unsigned short* __restrict__ B0, int s, s8v* dst) {
#pragma unroll
  for (int nt = 0; nt < 4; ++nt) dst[nt] = *(const s8v*)(B0 + (size_t)s * 8192 + nt * 512);
}

__global__ __launch_bounds__(256) void k_conv3x3(const unsigned short* __restrict__ in,
                                                 const unsigned short* __restrict__ wbf,
                                                 const float* __restrict__ bias,
                                                 const unsigned short* __restrict__ cvecB,
                                                 int D, int lo, int hi,
                                                 unsigned short* __restrict__ out) {
  __shared__ __align__(16) unsigned short Ah[100 * 264];
  int b = blockIdx.z;
  int co0 = blockIdx.y * 128;
  int ti = blockIdx.x / 13, tj = blockIdx.x % 13;
  int i0 = ti * 8, j0 = tj * 8;
  int tid = threadIdx.x;

  if (i0 - 1 >= lo && i0 + 8 <= hi && j0 - 1 >= lo && j0 + 8 <= hi && i0 - 1 >= j0 + 8 + D) {
    const unsigned int* cv = (const unsigned int*)(cvecB + co0);
    unsigned int* ob = (unsigned int*)out;
#pragma unroll
    for (int r = 0; r < 16; ++r) {
      int idx = r * 256 + tid;
      int sp = idx >> 6, cp = idx & 63;
      int gi = i0 + (sp >> 3), gj = j0 + (sp & 7);
      ob[((size_t)(b * T99 + gi) * T99 + gj) * 128 + (co0 >> 1) + cp] = cv[cp];
    }
    return;
  }

#pragma unroll
  for (int it = 0; it < 13; ++it) {
    int chunk = it * 256 + tid;
    if (chunk < 3200) {
      int row = chunk >> 5;
      int cc = (chunk & 31) * 8;
      int gi = i0 + row / 10 - 1, gj = j0 + row % 10 - 1;
      s8v val = {0, 0, 0, 0, 0, 0, 0, 0};
      if (gi >= 0 && gi < T99 && gj >= 0 && gj < T99)
        val = *(const s8v*)&in[((size_t)(b * T99 + gi) * T99 + gj) * 256 + cc];
      *(s8v*)&Ah[row * 264 + cc] = val;
    }
  }
  __syncthreads();

  int lane = tid & 63, w = tid >> 6, wm = w >> 1, wn = w & 1;
  int l15 = lane & 15, lk = lane >> 4;
  int spL0 = wm * 32 + l15, spL1 = spL0 + 16;
  int hr0 = (spL0 >> 3) * 10 + (spL0 & 7);
  int hr1 = (spL1 >> 3) * 10 + (spL1 & 7);
  const unsigned short* A0 = &Ah[hr0 * 264 + lk * 8];
  const unsigned short* A1 = &Ah[hr1 * 264 + lk * 8];
  int cogbase = blockIdx.y * 8 + wn * 4;
  const unsigned short* B0 = wbf + (size_t)cogbase * 512 + (size_t)lane * 8;

  f4v acc[2][4];
#pragma unroll
  for (int mt = 0; mt < 2; ++mt)
#pragma unroll
    for (int nt = 0; nt < 4; ++nt) acc[mt][nt] = (f4v){0.f, 0.f, 0.f, 0.f};

  s8v a0c, a1c, a0n, a1n;
  s8v bq[3][4];
  a0c = *(const s8v*)(A0 + aoff(0));
  a1c = *(const s8v*)(A1 + aoff(0));
  a0n = a0c; a1n = a1c;
  ldb4(B0, 0, bq[0]);
  ldb4(B0, 1, bq[1]);
#pragma unroll
  for (int s = 0; s < 72; ++s) {
    if (s + 2 < 72) ldb4(B0, s + 2, bq[(s + 2) % 3]);
    if (s + 1 < 72) {
      a0n = *(const s8v*)(A0 + aoff(s + 1));
      a1n = *(const s8v*)(A1 + aoff(s + 1));
    }
#pragma unroll
    for (int nt = 0; nt < 4; ++nt) {
      mfma_bf16(acc[0][nt], a0c, bq[s % 3][nt]);
      mfma_bf16(acc[1][nt], a1c, bq[s % 3][nt]);
    }
    a0c = a0n; a1c = a1n;
  }

  asm volatile("s_nop 7\n\ts_nop 7\n\ts_nop 4");
#pragma unroll
  for (int mt = 0; mt < 2; ++mt) {
#pragma unroll
    for (int nt = 0; nt < 4; ++nt) {
      int co = co0 + wn * 64 + nt * 16 + l15;
      float bv = bias[co];
#pragma unroll
      for (int r = 0; r < 4; ++r) {
        int sp = wm * 32 + mt * 16 + lk * 4 + r;
        int gi = i0 + (sp >> 3), gj = j0 + (sp & 7);
        if (gi < T99 && gj < T99) {
          float v = fmaxf(acc[mt][nt][r] + bv, 0.f);
          out[((size_t)(b * T99 + gi) * T99 + gj) * 256 + co] = f2bf(v);
        }
      }
    }
  }
}

// ---------------- p3: both channels per row ----------------
__global__ __launch_bounds__(256) void k_p3(const unsigned short* __restrict__ p2o,
                                            const float* __restrict__ w, const float* __restrict__ bias,
                                            float* __restrict__ cm) {
  int idx = blockIdx.x * 256 + threadIdx.x;
  if (idx >= 2 * T99 * T99) return;
  int j = idx % T99, i = (idx / T99) % T99, b = idx / (T99 * T99);
  float a0 = bias[0], a1 = bias[1];
  const unsigned short* row = p2o + ((size_t)(b * T99 + i) * T99 + j) * 256;
  for (int c8 = 0; c8 < 256; c8 += 8) {
    s8v v = *(const s8v*)&row[c8];
#pragma unroll
    for (int q = 0; q < 8; ++q) {
      float x = bf2f((unsigned short)v[q]);
      a0 += w[c8 + q] * x;
      a1 += w[256 + c8 + q] * x;
    }
  }
  size_t base = (size_t)b * 2 * T99 * T99 + (size_t)i * T99 + j;
  cm[base] = 1.f / (1.f + expf(-a0));
  cm[base + T99 * T99] = 1.f / (1.f + expf(-a1));
}

// ---------------- host ----------------
struct EncW {
  const float *qkvw, *qkvb, *ow, *ob, *l1w, *l1b, *l2w, *l2b, *n1g, *n1b, *n2g, *n2b, *nfg, *nfb;
};
struct EncBufs {
  float* x; unsigned short* xb;
  float* yb;
  unsigned short *qkvb, *attb, *hb;
  int M;
};

static GJ jqkv(const EncW& W, const unsigned short* Wb, int l, const EncBufs& B) {
  GJ j = {}; j.Ab = B.xb; j.W = Wb + (size_t)l * 786432;
  j.bias = W.qkvb + (size_t)l * 768; j.Yb = B.qkvb; j.flags = 4 | 8;
  j.M = B.M; j.N = 768; j.K = 256; return j;
}
static GJ jproj(const EncW& W, const unsigned short* Wb, int l, const EncBufs& B) {
  GJ j = {}; j.Ab = B.attb; j.W = Wb + (size_t)l * 786432 + 196608;
  j.bias = W.ob + (size_t)l * 256; j.R = B.x; j.Yf = B.yb; j.flags = 2;
  j.M = B.M; j.N = 256; j.K = 256; return j;
}
static GJ jffn1(const EncW& W, const unsigned short* Wb, int l, const EncBufs& B) {
  GJ j = {}; j.Ab = B.xb; j.W = Wb + (size_t)l * 786432 + 262144;
  j.bias = W.l1b + (size_t)l * 1024; j.Yb = B.hb; j.flags = 1 | 4 | 8;
  j.M = B.M; j.N = 1024; j.K = 256; return j;
}
static GJ jffn2(const EncW& W, const unsigned short* Wb, int l, const EncBufs& B) {
  GJ j = {}; j.Ab = B.hb; j.W = Wb + (size_t)l * 786432 + 524288;
  j.bias = W.l2b + (size_t)l * 256; j.R = B.x; j.Yf = B.yb; j.flags = 2;
  j.M = B.M; j.N = 256; j.K = 1024; return j;
}

extern "C" void kernel_launch(void* const* d_in, const int* in_sizes, int n_in,
                              void* d_out, int out_size, void* d_ws, size_t ws_size,
                              hipStream_t stream) {
  (void)in_sizes; (void)n_in; (void)out_size; (void)ws_size;
  const float* x    = (const float*)d_in[0];
  const float* cbw  = (const float*)d_in[1];
  const float* cbb  = (const float*)d_in[2];
  EncW tg = {(const float*)d_in[3],  (const float*)d_in[4],  (const float*)d_in[5],  (const float*)d_in[6],
             (const float*)d_in[7],  (const float*)d_in[8],  (const float*)d_in[9],  (const float*)d_in[10],
             (const float*)d_in[11], (const float*)d_in[12], (const float*)d_in[13], (const float*)d_in[14],
             (const float*)d_in[15], (const float*)d_in[16]};
  EncW tl = {(const float*)d_in[17], (const float*)d_in[18], (const float*)d_in[19], (const float*)d_in[20],
             (const float*)d_in[21], (const float*)d_in[22], (const float*)d_in[23], (const float*)d_in[24],
             (const float*)d_in[25], (const float*)d_in[26], (const float*)d_in[27], (const float*)d_in[28],
             (const float*)d_in[29], (const float*)d_in[30]};
  const float* s1w = (const float*)d_in[31];
  const float* s1b = (const float*)d_in[32];
  const float* s2w = (const float*)d_in[33];
  const float* s2b = (const float*)d_in[34];
  const float* c3w = (const float*)d_in[35];
  const float* c3b = (const float*)d_in[36];
  const float* p1w = (const float*)d_in[37];
  const float* p1b = (const float*)d_in[38];
  const float* p2w = (const float*)d_in[39];
  const float* p2b = (const float*)d_in[40];
  const float* p3w = (const float*)d_in[41];
  const float* p3b = (const float*)d_in[42];

  float* outp = (float*)d_out; // [cm 39204][start1 198]

  char* wp = (char*)d_ws;
  auto alloc = [&](size_t bytes) -> void* {
    void* p = (void*)wp;
    wp += (bytes + 255) & ~(size_t)255;
    return p;
  };
  float* base  = (float*)alloc(sizeof(float) * 2 * CC * T99);
  const int ML = 198, MG = 396;
  EncBufs BG, BL;
  BG.M = MG; BL.M = ML;
  BG.x  = (float*)alloc(sizeof(float) * MG * 256);
  BL.x  = (float*)alloc(sizeof(float) * ML * 256);
  BG.xb = (unsigned short*)alloc(sizeof(short) * MG * 256);
  BL.xb = (unsigned short*)alloc(sizeof(short) * ML * 256);
  BG.yb = (float*)alloc(sizeof(float) * MG * 256);
  BL.yb = (float*)alloc(sizeof(float) * ML * 256);
  BG.qkvb = (unsigned short*)alloc(sizeof(short) * MG * 768);
  BL.qkvb = (unsigned short*)alloc(sizeof(short) * ML * 768);
  BG.attb = (unsigned short*)alloc(sizeof(short) * MG * 256);
  BL.attb = (unsigned short*)alloc(sizeof(short) * ML * 256);
  BG.hb = (unsigned short*)alloc(sizeof(short) * MG * 1024);
  BL.hb = (unsigned short*)alloc(sizeof(short) * ML * 1024);
  float* encg  = (float*)alloc(sizeof(float) * MG * 256);
  float* encl  = (float*)alloc(sizeof(float) * ML * 256);
  float* base2 = (float*)alloc(sizeof(float) * 2 * CC * T99);
  float* w3t   = (float*)alloc(sizeof(float) * 32 * 256 * 256);
  unsigned short* Gb = (unsigned short*)alloc(sizeof(short) * (2 * NS_ * T99 * 256 + 512));
  unsigned short* pinb = (unsigned short*)alloc(sizeof(short) * 2 * T99 * T99 * 256);
  unsigned short* p1o  = (unsigned short*)alloc(sizeof(short) * 2 * T99 * T99 * 256);
  unsigned short* p2o  = (unsigned short*)alloc(sizeof(short) * 2 * T99 * T99 * 256);
  unsigned short* wb2a = (unsigned short*)alloc(sizeof(short) * 9 * 256 * 256);
  unsigned short* wb2b = (unsigned short*)alloc(sizeof(short) * 9 * 256 * 256);
  unsigned short* wtgb = (unsigned short*)alloc(sizeof(short) * 6 * 786432);
  unsigned short* wtlb = (unsigned short*)alloc(sizeof(short) * 3 * 786432);
  float* c1F = (float*)alloc(sizeof(float) * 256);
  unsigned short* c1B = (unsigned short*)alloc(sizeof(short) * 256);
  float* c2F = (float*)alloc(sizeof(float) * 256);
  unsigned short* c2B = (unsigned short*)alloc(sizeof(short) * 256);

  // 0. preamble
  k_convW<<<dim3(4096), dim3(256), 0, stream>>>(tg.qkvw, tg.ow, tg.l1w, tg.l2w, 6, wtgb);
  k_convW<<<dim3(2048), dim3(256), 0, stream>>>(tl.qkvw, tl.ow, tl.l1w, tl.l2w, 3, wtlb);
  k_w3t<<<dim3(8192), dim3(256), 0, stream>>>(c3w, w3t);
  k_wb2<<<dim3(288), dim3(256), 0, stream>>>(p1w, wb2a);
  k_wb2<<<dim3(288), dim3(256), 0, stream>>>(p2w, wb2b);
  k_cvec<<<dim3(256), dim3(256), 0, stream>>>(p1w, c3b, p1b, 1, c1F, c1B);
  k_cvec<<<dim3(256), dim3(256), 0, stream>>>(p2w, c1F, p2b, 0, c2F, c2B);
  // 1. conv stem + encoder inputs
  k_convbase<<<dim3(512), dim3(128), 0, stream>>>(x, cbw, cbb, base);
  k_build_xl<<<dim3(198), dim3(256), 0, stream>>>(base, BL.x, BL.xb);
  k_build_xg<<<dim3(396), dim3(256), 0, stream>>>(base, BG.x, BG.xb);

  // 2. layers 0..2 merged (local || global)
  const int mgG = 7;
  for (int l = 0; l < 3; ++l) {
    k_g2<<<dim3(mgG, 12, 2), dim3(256), 0, stream>>>(jqkv(tl, wtlb, l, BL), jqkv(tg, wtgb, l, BG));
    k_attn2<<<dim3(4 * NHH * T99, 1, 2), dim3(128), 0, stream>>>(BL.qkvb, BL.attb, LSTEP, 6,
                                                                 BG.qkvb, BG.attb, T99, 4);
    k_g2<<<dim3(mgG, 4, 2), dim3(256), 0, stream>>>(jproj(tl, wtlb, l, BL), jproj(tg, wtgb, l, BG));
    k_ln2<<<dim3(MG, 1, 2), dim3(256), 0, stream>>>(BL.yb, tl.n1g + l * 256, tl.n1b + l * 256, BL.x, BL.xb, ML,
                                                    BG.yb, tg.n1g + l * 256, tg.n1b + l * 256, BG.x, BG.xb, MG);
    k_g2<<<dim3(mgG, 16, 2), dim3(256), 0, stream>>>(jffn1(tl, wtlb, l, BL), jffn1(tg, wtgb, l, BG));
    k_g2<<<dim3(mgG, 4, 2), dim3(256), 0, stream>>>(jffn2(tl, wtlb, l, BL), jffn2(tg, wtgb, l, BG));
    k_ln2<<<dim3(MG, 1, 2), dim3(256), 0, stream>>>(BL.yb, tl.n2g + l * 256, tl.n2b + l * 256, BL.x, BL.xb, ML,
                                                    BG.yb, tg.n2g + l * 256, tg.n2b + l * 256, BG.x, BG.xb, MG);
  }
  // 3. global layers 3..5
  for (int l = 3; l < 6; ++l) {
    k_g<<<dim3(mgG, 12), dim3(256), 0, stream>>>(jqkv(tg, wtgb, l, BG));
    k_attn<<<dim3(4 * NHH * T99), dim3(128), 0, stream>>>(BG.qkvb, BG.attb, T99, 4);
    k_g<<<dim3(mgG, 4), dim3(256), 0, stream>>>(jproj(tg, wtgb, l, BG));
    k_ln<<<dim3(MG), dim3(256), 0, stream>>>(BG.yb, tg.n1g + l * 256, tg.n1b + l * 256, BG.x, BG.xb);
    k_g<<<dim3(mgG, 16), dim3(256), 0, stream>>>(jffn1(tg, wtgb, l, BG));
    k_g<<<dim3(mgG, 4), dim3(256), 0, stream>>>(jffn2(tg, wtgb, l, BG));
    k_ln<<<dim3(MG), dim3(256), 0, stream>>>(BG.yb, tg.n2g + l * 256, tg.n2b + l * 256, BG.x, BG.xb);
  }
  // 4. final LNs
  k_ln2<<<dim3(MG, 1, 2), dim3(256), 0, stream>>>(BL.x, tl.nfg, tl.nfb, encl, nullptr, ML,
                                                  BG.x, tg.nfg, tg.nfb, encg, nullptr, MG);
  // 5. combine + s-branch
  k_combine<<<dim3(198), dim3(256), 0, stream>>>(encl, encg, base2);
  k_sfuse<<<dim3(198), dim3(256), 0, stream>>>(base2, s1w, s1b, s2w, s2b, outp + 2 * 2 * T99 * T99);
  // 6. bm + conv3d
  k_G<<<dim3(4, 32, 2), dim3(256), 0, stream>>>(w3t, base2, Gb);
  k_ppre<<<dim3(T99 * T99), dim3(256), 0, stream>>>(Gb, c3b, (unsigned int*)pinb);
  // 7. p-branch
  k_conv3x3<<<dim3(169, 2, 2), dim3(256), 0, stream>>>(pinb, wb2a, p1b, c1B, 0, 0, 98, p1o);
  k_conv3x3<<<dim3(169, 2, 2), dim3(256), 0, stream>>>(p1o, wb2b, p2b, c2B, 2, 1, 97, p2o);
  k_p3<<<dim3(77), dim3(256), 0, stream>>>(p2o, p3w, p3b, outp);
}

// Round 11
// 635.401 us; speedup vs baseline: 1.7664x; 1.0830x over previous
//
#include <hip/hip_runtime.h>
#include <math.h>

// ---------------- constants ----------------
#define T99   99
#define CC    256
#define NHH   8
#define FEAT  400
#define NS_   32
#define LSTEP 33

typedef __attribute__((ext_vector_type(8))) short s8v;   // 8 x bf16 (as raw u16)
typedef __attribute__((ext_vector_type(4))) float f4v;   // MFMA accumulator

// non-volatile asm: data deps preserve correctness, scheduler may interleave loads
__device__ __forceinline__ void mfma_bf16(f4v& d, s8v a, s8v b) {
  asm("v_mfma_f32_16x16x32_bf16 %0, %1, %2, %0" : "+v"(d) : "v"(a), "v"(b));
}

__device__ __forceinline__ unsigned short f2bf(float f) {
  union { float f; unsigned u; } x; x.f = f;
  unsigned r = x.u + 0x7FFFu + ((x.u >> 16) & 1u);
  return (unsigned short)(r >> 16);
}
__device__ __forceinline__ float bf2f(unsigned short h) {
  union { unsigned u; float f; } x; x.u = ((unsigned)h) << 16;
  return x.f;
}
__device__ __forceinline__ float blo(unsigned u) { union { unsigned x; float f; } c; c.x = u << 16; return c.f; }
__device__ __forceinline__ float bhi(unsigned u) { union { unsigned x; float f; } c; c.x = u & 0xffff0000u; return c.f; }

__device__ __forceinline__ float pe_val(int pos, int c) {
  int i = c >> 1;
  float freq = expf((float)(2 * i) * (-0.03597789207803197f)); // -ln(10000)/256
  float ang = (float)pos * freq;
  return (c & 1) ? cosf(ang) : sinf(ang);
}

// ---------------- conv stem ----------------
__global__ __launch_bounds__(128) void k_convbase(const float* __restrict__ x,
                                                  const float* __restrict__ w,
                                                  const float* __restrict__ bias,
                                                  float* __restrict__ base) {
  int b = blockIdx.x >> 8, co = blockIdx.x & 255, t = threadIdx.x;
  if (t >= T99) return;
  int g = co >> 6;
  float acc = bias[co];
  const float* xp = x + (size_t)(b * FEAT + g * 100) * T99;
  const float* wp = w + (size_t)co * 300;
  for (int ic = 0; ic < 100; ++ic) {
    float x0 = (t > 0)  ? xp[ic * T99 + t - 1] : 0.f;
    float x1 = xp[ic * T99 + t];
    float x2 = (t < 98) ? xp[ic * T99 + t + 1] : 0.f;
    acc += wp[ic * 3] * x0 + wp[ic * 3 + 1] * x1 + wp[ic * 3 + 2] * x2;
  }
  base[(size_t)(b * CC + co) * T99 + t] = fmaxf(acc, 0.f);
}

// ---------------- weight conversion: pack {qkv,o,l1,l2} per layer into bf16 row-major blob ----------------
__global__ __launch_bounds__(256) void k_convW(const float* __restrict__ qkv, const float* __restrict__ o,
                                               const float* __restrict__ l1, const float* __restrict__ l2,
                                               int L, unsigned short* __restrict__ dst) {
  int total = L * 786432;
  for (int idx = blockIdx.x * 256 + threadIdx.x; idx < total; idx += gridDim.x * 256) {
    int l = idx / 786432, r = idx % 786432;
    float v;
    if (r < 196608)      v = qkv[(size_t)l * 196608 + r];
    else if (r < 262144) v = o[(size_t)l * 65536 + (r - 196608)];
    else if (r < 524288) v = l1[(size_t)l * 262144 + (r - 262144)];
    else                 v = l2[(size_t)l * 262144 + (r - 524288)];
    dst[idx] = f2bf(v);
  }
}

// ---------------- build encoder inputs ----------------
__global__ __launch_bounds__(256) void k_build_xg(const float* __restrict__ base, float* __restrict__ xg,
                                                  unsigned short* __restrict__ xgb) {
  int idx = blockIdx.x * 256 + threadIdx.x;
  int t = idx >> 10, r = idx & 1023, b4 = r >> 8, c = r & 255;
  float v = (b4 < 2) ? base[(size_t)(b4 * CC + c) * T99 + t]
                     : base[(size_t)((b4 - 2) * CC + c) * T99 + (98 - t)];
  v += pe_val(t, c);
  xg[idx] = v; xgb[idx] = f2bf(v);
}

__global__ __launch_bounds__(256) void k_build_xl(const float* __restrict__ base, float* __restrict__ xl,
                                                  unsigned short* __restrict__ xlb) {
  int idx = blockIdx.x * 256 + threadIdx.x;
  int ls = idx / 1536, r = idx % 1536, j = r >> 8, c = r & 255;
  int g = j >> 1, b = j & 1, t = ls * 3 + g;
  float v = base[(size_t)(b * CC + c) * T99 + t] + pe_val(ls, c);
  xl[idx] = v; xlb[idx] = f2bf(v);
}

// ================= GEMM (R6-proven: 32-wide ksteps, dual LDS staging) =================
// flags: 1=relu, 2=residual R, 4=write bf16 Yb, 8=skip fp32 Yf
struct GJ {
  const unsigned short* Ab;   // bf16 row-major [M][K]
  const unsigned short* W;    // bf16 row-major [N][K]
  const float* bias;
  const float* R;
  float* Yf;
  unsigned short* Yb;
  int M, N, K, flags;
};

__device__ void g_body(const GJ& j, int m0, int n0) {
  __shared__ __align__(16) unsigned short Al[64][40];
  __shared__ __align__(16) unsigned short Bl[64][40];
  int tid = threadIdx.x;
  int lane = tid & 63, w = tid >> 6, wm = w >> 1, wn = w & 1;
  int sp = tid >> 2, kc = (tid & 3) << 3;
  f4v acc[2][2];
#pragma unroll
  for (int mt = 0; mt < 2; ++mt)
#pragma unroll
    for (int nt = 0; nt < 2; ++nt) acc[mt][nt] = (f4v){0.f, 0.f, 0.f, 0.f};

  for (int k0 = 0; k0 < j.K; k0 += 32) {
    s8v av = {0, 0, 0, 0, 0, 0, 0, 0};
    int row = m0 + sp;
    if (row < j.M) av = *(const s8v*)&j.Ab[(size_t)row * j.K + k0 + kc];
    *(s8v*)&Al[sp][kc] = av;
    *(s8v*)&Bl[sp][kc] = *(const s8v*)&j.W[(size_t)(n0 + sp) * j.K + k0 + kc];
    __syncthreads();
    s8v af[2], bf[2];
#pragma unroll
    for (int mt = 0; mt < 2; ++mt)
      af[mt] = *(const s8v*)&Al[wm * 32 + mt * 16 + (lane & 15)][(lane >> 4) * 8];
#pragma unroll
    for (int nt = 0; nt < 2; ++nt)
      bf[nt] = *(const s8v*)&Bl[wn * 32 + nt * 16 + (lane & 15)][(lane >> 4) * 8];
#pragma unroll
    for (int mt = 0; mt < 2; ++mt)
#pragma unroll
      for (int nt = 0; nt < 2; ++nt) mfma_bf16(acc[mt][nt], af[mt], bf[nt]);
    __syncthreads();
  }
  asm volatile("s_nop 7\n\ts_nop 7\n\ts_nop 4");
#pragma unroll
  for (int mt = 0; mt < 2; ++mt) {
#pragma unroll
    for (int nt = 0; nt < 2; ++nt) {
      int col = n0 + wn * 32 + nt * 16 + (lane & 15);
      float bv = j.bias[col];
#pragma unroll
      for (int r = 0; r < 4; ++r) {
        int row = m0 + wm * 32 + mt * 16 + (lane >> 4) * 4 + r;
        if (row < j.M) {
          float v = acc[mt][nt][r] + bv;
          if (j.flags & 2) v += j.R[(size_t)row * j.N + col];
          if (j.flags & 1) v = fmaxf(v, 0.f);
          if (!(j.flags & 8)) j.Yf[(size_t)row * j.N + col] = v;
          if (j.flags & 4) j.Yb[(size_t)row * j.N + col] = f2bf(v);
        }
      }
    }
  }
}

__global__ __launch_bounds__(256) void k_g(GJ j) {
  if ((int)blockIdx.x * 64 >= j.M) return;
  g_body(j, blockIdx.x * 64, blockIdx.y * 64);
}

__global__ __launch_bounds__(256) void k_g2(GJ j0, GJ j1) {
  if (blockIdx.z == 0) {
    if ((int)blockIdx.x * 64 >= j0.M) return;
    g_body(j0, blockIdx.x * 64, blockIdx.y * 64);
  } else {
    if ((int)blockIdx.x * 64 >= j1.M) return;
    g_body(j1, blockIdx.x * 64, blockIdx.y * 64);
  }
}

// ---------------- attention (PV 4-way split) ----------------
__device__ __forceinline__ void attn_body(const unsigned short* __restrict__ qkv,
                                          unsigned short* __restrict__ attb,
                                          int T_, int B_, int bid) {
  __shared__ float qv[32];
  __shared__ float red[128];
  __shared__ float pv[128];
  int tid = threadIdx.x;
  int q = bid % T_;
  int h = (bid / T_) % NHH;
  int b = bid / (T_ * NHH);
  if (tid < 32) qv[tid] = bf2f(qkv[(size_t)(q * B_ + b) * 768 + h * 32 + tid]);
  __syncthreads();
  float s = -1e30f;
  if (tid < T_) {
    const unsigned short* kp = qkv + (size_t)(tid * B_ + b) * 768 + 256 + h * 32;
    float d = 0;
#pragma unroll
    for (int i = 0; i < 32; ++i) d += qv[i] * bf2f(kp[i]);
    s = d * 0.176776695296636881f; // 1/sqrt(32)
  }
  red[tid] = s; __syncthreads();
  for (int o = 64; o > 0; o >>= 1) { if (tid < o) red[tid] = fmaxf(red[tid], red[tid + o]); __syncthreads(); }
  float mx = red[0]; __syncthreads();
  float p = (tid < T_) ? expf(s - mx) : 0.f;
  pv[tid] = p; red[tid] = p; __syncthreads();
  for (int o = 64; o > 0; o >>= 1) { if (tid < o) red[tid] += red[tid + o]; __syncthreads(); }
  float denom = red[0];
  __syncthreads();
  int d = tid & 31, part = tid >> 5;
  float o = 0.f;
  for (int k = part; k < T_; k += 4)
    o += pv[k] * bf2f(qkv[(size_t)(k * B_ + b) * 768 + 512 + h * 32 + d]);
  red[tid] = o; __syncthreads();
  if (tid < 32) {
    float t = red[tid] + red[tid + 32] + red[tid + 64] + red[tid + 96];
    attb[(size_t)(q * B_ + b) * 256 + h * 32 + tid] = f2bf(t / denom);
  }
}

__global__ __launch_bounds__(128) void k_attn(const unsigned short* __restrict__ qkv,
                                              unsigned short* __restrict__ attb, int T_, int B_) {
  attn_body(qkv, attb, T_, B_, blockIdx.x);
}

__global__ __launch_bounds__(128) void k_attn2(const unsigned short* __restrict__ qkv0,
                                               unsigned short* __restrict__ attb0, int T0, int B0,
                                               const unsigned short* __restrict__ qkv1,
                                               unsigned short* __restrict__ attb1, int T1, int B1) {
  int bid = blockIdx.x;
  if (blockIdx.z == 0) {
    if (bid >= B0 * NHH * T0) return;
    attn_body(qkv0, attb0, T0, B0, bid);
  } else {
    if (bid >= B1 * NHH * T1) return;
    attn_body(qkv1, attb1, T1, B1, bid);
  }
}

// ---------------- layer norm (fp32 out + optional bf16 mirror) ----------------
__device__ __forceinline__ void ln_body(const float* __restrict__ X, const float* __restrict__ g,
                                        const float* __restrict__ bb, float* __restrict__ Y,
                                        unsigned short* __restrict__ Yb, int tok) {
  __shared__ float rs[256], rq[256];
  int c = threadIdx.x;
  float v = X[(size_t)tok * 256 + c];
  rs[c] = v; rq[c] = v * v; __syncthreads();
  for (int o = 128; o > 0; o >>= 1) { if (c < o) { rs[c] += rs[c + o]; rq[c] += rq[c + o]; } __syncthreads(); }
  float mu = rs[0] * (1.f / 256.f);
  float var = rq[0] * (1.f / 256.f) - mu * mu;
  float r = (v - mu) * rsqrtf(var + 1e-5f) * g[c] + bb[c];
  Y[(size_t)tok * 256 + c] = r;
  if (Yb) Yb[(size_t)tok * 256 + c] = f2bf(r);
}

__global__ __launch_bounds__(256) void k_ln(const float* __restrict__ X, const float* __restrict__ g,
                                            const float* __restrict__ bb, float* __restrict__ Y,
                                            unsigned short* __restrict__ Yb) {
  ln_body(X, g, bb, Y, Yb, blockIdx.x);
}

__global__ __launch_bounds__(256) void k_ln2(const float* __restrict__ X0, const float* __restrict__ g0,
                                             const float* __restrict__ bb0, float* __restrict__ Y0,
                                             unsigned short* __restrict__ Yb0, int n0,
                                             const float* __restrict__ X1, const float* __restrict__ g1,
                                             const float* __restrict__ bb1, float* __restrict__ Y1,
                                             unsigned short* __restrict__ Yb1, int n1) {
  int tok = blockIdx.x;
  if (blockIdx.z == 0) { if (tok < n0) ln_body(X0, g0, bb0, Y0, Yb0, tok); }
  else                 { if (tok < n1) ln_body(X1, g1, bb1, Y1, Yb1, tok); }
}

// ---------------- combine: base2 fp32 [b][c][t] + b2t bf16 [b][t][c] ----------------
__global__ __launch_bounds__(256) void k_combine(const float* __restrict__ encl, const float* __restrict__ encg,
                                                 float* __restrict__ base2, unsigned short* __restrict__ b2t) {
  int idx = blockIdx.x * 256 + threadIdx.x;
  int t = idx % T99, c = (idx / T99) & 255, b = idx / (CC * T99);
  int ls = t / 3, g = t % 3;
  float v = encl[(size_t)(ls * 6 + g * 2 + b) * 256 + c]
          + encg[(size_t)(t * 4 + b) * 256 + c]
          + encg[(size_t)((98 - t) * 4 + 2 + b) * 256 + c];
  base2[idx] = v;
  b2t[((size_t)(b * T99) + t) * 256 + c] = f2bf(v);
}

// ---------------- fused s-branch ----------------
__global__ __launch_bounds__(256) void k_sfuse(const float* __restrict__ base2, const float* __restrict__ s1w,
                                               const float* __restrict__ s1b, const float* __restrict__ s2w,
                                               const float* __restrict__ s2b, float* __restrict__ out) {
  __shared__ float rs[256];
  int b = blockIdx.x / T99, t = blockIdx.x % T99, co = threadIdx.x;
  int g = co >> 6;
  float acc = s1b[co];
  const float* xp = base2 + (size_t)(b * CC + g * 64) * T99;
  const float* wp = s1w + (size_t)co * 192;
  for (int ic = 0; ic < 64; ++ic) {
    float x0 = (t > 0)  ? xp[ic * T99 + t - 1] : 0.f;
    float x1 = xp[ic * T99 + t];
    float x2 = (t < 98) ? xp[ic * T99 + t + 1] : 0.f;
    acc += wp[ic * 3] * x0 + wp[ic * 3 + 1] * x1 + wp[ic * 3 + 2] * x2;
  }
  rs[co] = fmaxf(acc, 0.f) * s2w[co];
  __syncthreads();
  for (int o = 128; o > 0; o >>= 1) { if (co < o) rs[co] += rs[co + o]; __syncthreads(); }
  if (co == 0) out[blockIdx.x] = 1.f / (1.f + expf(-(rs[0] + s2b[0])));
}

// ---------------- w3 pack: w3tb[n][co][ci] bf16 = c3w[co][ci][n] ----------------
__global__ __launch_bounds__(256) void k_w3tb(const float* __restrict__ c3w, unsigned short* __restrict__ w3tb) {
  int idx = blockIdx.x * 256 + threadIdx.x;
  int ci = idx & 255, co = (idx >> 8) & 255, n = idx >> 16;
  w3tb[idx] = f2bf(c3w[((size_t)(co << 8) + ci) * 32 + n]);
}

// ---------------- Gb via MFMA: 64 batched GEMMs (99t x 64co x 256ci) ----------------
// A = b2t[b][t][ci] bf16; B = w3tb[n][co][ci]; out Gb[((n*99+t)*256+co)*2+b] bf16
__global__ __launch_bounds__(256) void k_Gm(const unsigned short* __restrict__ b2t,
                                            const unsigned short* __restrict__ w3tb,
                                            unsigned short* __restrict__ Gb) {
  __shared__ __align__(16) unsigned short Al[64][40];
  __shared__ __align__(16) unsigned short Bl[64][40];
  int nb = blockIdx.z, n = nb >> 1, b = nb & 1;
  int m0 = blockIdx.x * 64, n0 = blockIdx.y * 64;
  int tid = threadIdx.x;
  // zero the pad row once (read by k_ppre with weight 0; keep deterministic)
  if (blockIdx.x == 0 && blockIdx.y == 0 && nb == 0)
    ((unsigned int*)(Gb + (size_t)NS_ * T99 * 512))[tid] = 0u;
  const unsigned short* A = b2t + (size_t)b * T99 * 256;
  const unsigned short* W = w3tb + (size_t)n * 65536;
  int lane = tid & 63, w = tid >> 6, wm = w >> 1, wn = w & 1;
  int sp = tid >> 2, kc = (tid & 3) << 3;
  f4v acc[2][2];
#pragma unroll
  for (int mt = 0; mt < 2; ++mt)
#pragma unroll
    for (int nt = 0; nt < 2; ++nt) acc[mt][nt] = (f4v){0.f, 0.f, 0.f, 0.f};
#pragma unroll
  for (int k0 = 0; k0 < 256; k0 += 32) {
    s8v av = {0, 0, 0, 0, 0, 0, 0, 0};
    int row = m0 + sp;
    if (row < T99) av = *(const s8v*)&A[(size_t)row * 256 + k0 + kc];
    *(s8v*)&Al[sp][kc] = av;
    *(s8v*)&Bl[sp][kc] = *(const s8v*)&W[(size_t)(n0 + sp) * 256 + k0 + kc];
    __syncthreads();
    s8v af[2], bf[2];
#pragma unroll
    for (int mt = 0; mt < 2; ++mt)
      af[mt] = *(const s8v*)&Al[wm * 32 + mt * 16 + (lane & 15)][(lane >> 4) * 8];
#pragma unroll
    for (int nt = 0; nt < 2; ++nt)
      bf[nt] = *(const s8v*)&Bl[wn * 32 + nt * 16 + (lane & 15)][(lane >> 4) * 8];
#pragma unroll
    for (int mt = 0; mt < 2; ++mt)
#pragma unroll
      for (int nt = 0; nt < 2; ++nt) mfma_bf16(acc[mt][nt], af[mt], bf[nt]);
    __syncthreads();
  }
  asm volatile("s_nop 7\n\ts_nop 7\n\ts_nop 4");
#pragma unroll
  for (int mt = 0; mt < 2; ++mt) {
#pragma unroll
    for (int nt = 0; nt < 2; ++nt) {
      int co = n0 + wn * 32 + nt * 16 + (lane & 15);
#pragma unroll
      for (int r = 0; r < 4; ++r) {
        int t = m0 + wm * 32 + mt * 16 + (lane >> 4) * 4 + r;
        if (t < T99)
          Gb[((size_t)(n * T99 + t) * 256 + co) * 2 + b] = f2bf(acc[mt][nt][r]);
      }
    }
  }
}

// ---------------- p_pre: split-k 256-thread ----------------
__global__ __launch_bounds__(256) void k_ppre(const unsigned short* __restrict__ Gb,
                                              const float* __restrict__ c3b,
                                              unsigned int* __restrict__ pinb32) {
  __shared__ float w0s[96], w1s[96];
  __shared__ int   ofs[96];
  __shared__ float part[128][4];
  int e = blockIdx.x % T99, s = blockIdx.x / T99;
  int tid = threadIdx.x;
  if (s >= e) {
    if (tid < 128) {
      float z0 = fmaxf(c3b[2 * tid], 0.f), z1 = fmaxf(c3b[2 * tid + 1], 0.f);
      unsigned int zz = ((unsigned)f2bf(z1) << 16) | (unsigned)f2bf(z0);
      pinb32[((size_t)s * T99 + e) * 128 + tid] = zz;
      pinb32[((size_t)(T99 + s) * T99 + e) * 128 + tid] = zz;
    }
    return;
  }
  if (tid < 96) {
    double center = (double)(e - s + 1);
    double S = ((double)s - 0.5 * center) + ((2.0 * center - 1.0) / 95.0) * (double)tid;
    double dn = trunc(S);
    double dec = S - dn;
    int di = (int)dn;
    double uc = ceil(S);
    int ui = (int)uc;
    int n = tid / 3;
    float w0 = 0.f, w1 = 0.f;
    int r0 = 0;
    if (dn >= 0.0 && dn <= 98.0) {
      r0 = di;
      w0 = (float)((1.0 - dec) / 3.0);
      if (uc >= 0.0 && uc <= 98.0) {
        if (ui == di) w0 += (float)(dec / 3.0);
        else          w1  = (float)(dec / 3.0);
      }
    }
    w0s[tid] = w0; w1s[tid] = w1;
    ofs[tid] = (n * T99 + r0) * 1024;
  }
  __syncthreads();
  int ch = tid & 127, half = tid >> 7;
  float a00 = 0.f, a01 = 0.f, a10 = 0.f, a11 = 0.f;
  const char* basep = (const char*)Gb + ch * 8;
  int k0 = half * 48;
#pragma unroll 8
  for (int k = k0; k < k0 + 48; ++k) {
    float w0 = w0s[k], w1 = w1s[k];
    const uint2* p = (const uint2*)(basep + ofs[k]);
    uint2 u0 = p[0];
    uint2 u1 = p[128];
    a00 += w0 * blo(u0.x) + w1 * blo(u1.x);
    a01 += w0 * bhi(u0.x) + w1 * bhi(u1.x);
    a10 += w0 * blo(u0.y) + w1 * blo(u1.y);
    a11 += w0 * bhi(u0.y) + w1 * bhi(u1.y);
  }
  if (half) { part[ch][0] = a00; part[ch][1] = a01; part[ch][2] = a10; part[ch][3] = a11; }
  __syncthreads();
  if (tid < 128) {
    a00 += part[ch][0]; a01 += part[ch][1]; a10 += part[ch][2]; a11 += part[ch][3];
    float b0 = c3b[2 * tid], b1 = c3b[2 * tid + 1];
    unsigned int zb0 = ((unsigned)f2bf(fmaxf(a10 + b1, 0.f)) << 16) | (unsigned)f2bf(fmaxf(a00 + b0, 0.f));
    unsigned int zb1 = ((unsigned)f2bf(fmaxf(a11 + b1, 0.f)) << 16) | (unsigned)f2bf(fmaxf(a01 + b0, 0.f));
    pinb32[((size_t)s * T99 + e) * 128 + tid] = zb0;
    pinb32[((size_t)(T99 + s) * T99 + e) * 128 + tid] = zb1;
  }
}

// ---------------- weight pack for conv3x3 ----------------
__global__ __launch_bounds__(256) void k_wb2(const float* __restrict__ pw, unsigned short* __restrict__ wbf) {
  int idx = blockIdx.x * 256 + threadIdx.x;
  if (idx >= 73728) return;
  int lane = idx & 63;
  int cog  = (idx >> 6) & 15;
  int kst  = (idx >> 10) & 7;
  int tap  = idx >> 13;
  int co = cog * 16 + (lane & 15);
  int k  = kst * 32 + (lane >> 4) * 8;
  s8v v;
#pragma unroll
  for (int j = 0; j < 8; ++j)
    v[j] = (short)f2bf(pw[((size_t)co * 256 + k + j) * 9 + tap]);
  *(s8v*)&wbf[(size_t)idx * 8] = v;
}

// ---------------- const-vector for conv const-region ----------------
__global__ __launch_bounds__(256) void k_cvec(const float* __restrict__ pw, const float* __restrict__ cin,
                                              const float* __restrict__ bias, int reluCin,
                                              float* __restrict__ coutF, unsigned short* __restrict__ coutB) {
  __shared__ float rs[256];
  int co = blockIdx.x, ci = threadIdx.x;
  float c = cin[ci];
  if (reluCin) c = fmaxf(c, 0.f);
  const float* wp = pw + ((size_t)co * 256 + ci) * 9;
  float wsum = 0.f;
#pragma unroll
  for (int t = 0; t < 9; ++t) wsum += wp[t];
  rs[ci] = wsum * c;
  __syncthreads();
  for (int o = 128; o > 0; o >>= 1) { if (ci < o) rs[ci] += rs[ci + o]; __syncthreads(); }
  if (ci == 0) {
    float r = fmaxf(bias[co] + rs[0], 0.f);
    coutF[co] = r;
    coutB[co] = f2bf(r);
  }
}

// ---------------- 3x3 conv: halo-LDS, sw-pipelined MFMA, const-region skip ----------------
__device__ __forceinline__ int aoff(int s) {
  int tap = s >> 3, kst = s & 7;
  return ((tap / 3) * 10 + (tap % 3)) * 264 + kst * 32;
}
__device__ __forceinline__ void ldb4(const unsigned short* __restrict__ B0, int s, s8v* dst) {
#pragma unroll
  for (int nt = 0; nt < 4; ++nt) dst[nt] = *(const s8v*)(B0 + (size_t)s * 8192 + nt * 512);
}

__global__ __launch_bounds__(256) void k_conv3x3(const unsigned short* __restrict__ in,
                                                 const unsigned short* __restrict__ wbf,
                                                 const float* __restrict__ bias,
                                                 const unsigned short* __restrict__ cvecB,
                                                 int D, int lo, int hi,
                                                 unsigned short* __restrict__ out) {
  __shared__ __align__(16) unsigned short Ah[100 * 264];
  int b = blockIdx.z;
  int co0 = blockIdx.y * 128;
  int ti = blockIdx.x / 13, tj = blockIdx.x % 13;
  int i0 = ti * 8, j0 = tj * 8;
  int tid = threadIdx.x;

  if (i0 - 1 >= lo && i0 + 8 <= hi && j0 - 1 >= lo && j0 + 8 <= hi && i0 - 1 >= j0 + 8 + D) {
    const unsigned int* cv = (const unsigned int*)(cvecB + co0);
    unsigned int* ob = (unsigned int*)out;
#pragma unroll
    for (int r = 0; r < 16; ++r) {
      int idx = r * 256 + tid;
      int sp = idx >> 6, cp = idx & 63;
      int gi = i0 + (sp >> 3), gj = j0 + (sp & 7);
      ob[((size_t)(b * T99 + gi) * T99 + gj) * 128 + (co0 >> 1) + cp] = cv[cp];
    }
    return;
  }

#pragma unroll
  for (int it = 0; it < 13; ++it) {
    int chunk = it * 256 + tid;
    if (chunk < 3200) {
      int row = chunk >> 5;
      int cc = (chunk & 31) * 8;
      int gi = i0 + row / 10 - 1, gj = j0 + row % 10 - 1;
      s8v val = {0, 0, 0, 0, 0, 0, 0, 0};
      if (gi >= 0 && gi < T99 && gj >= 0 && gj < T99)
        val = *(const s8v*)&in[((size_t)(b * T99 + gi) * T99 + gj) * 256 + cc];
      *(s8v*)&Ah[row * 264 + cc] = val;
    }
  }
  __syncthreads();

  int lane = tid & 63, w = tid >> 6, wm = w >> 1, wn = w & 1;
  int l15 = lane & 15, lk = lane >> 4;
  int spL0 = wm * 32 + l15, spL1 = spL0 + 16;
  int hr0 = (spL0 >> 3) * 10 + (spL0 & 7);
  int hr1 = (spL1 >> 3) * 10 + (spL1 & 7);
  const unsigned short* A0 = &Ah[hr0 * 264 + lk * 8];
  const unsigned short* A1 = &Ah[hr1 * 264 + lk * 8];
  int cogbase = blockIdx.y * 8 + wn * 4;
  const unsigned short* B0 = wbf + (size_t)cogbase * 512 + (size_t)lane * 8;

  f4v acc[2][4];
#pragma unroll
  for (int mt = 0; mt < 2; ++mt)
#pragma unroll
    for (int nt = 0; nt < 4; ++nt) acc[mt][nt] = (f4v){0.f, 0.f, 0.f, 0.f};

  s8v a0c, a1c, a0n, a1n;
  s8v bq[3][4];
  a0c = *(const s8v*)(A0 + aoff(0));
  a1c = *(const s8v*)(A1 + aoff(0));
  a0n = a0c; a1n = a1c;
  ldb4(B0, 0, bq[0]);
  ldb4(B0, 1, bq[1]);
#pragma unroll
  for (int s = 0; s < 72; ++s) {
    if (s + 2 < 72) ldb4(B0, s + 2, bq[(s + 2) % 3]);
    if (s + 1 < 72) {
      a0n = *(const s8v*)(A0 + aoff(s + 1));
      a1n = *(const s8v*)(A1 + aoff(s + 1));
    }
#pragma unroll
    for (int nt = 0; nt < 4; ++nt) {
      mfma_bf16(acc[0][nt], a0c, bq[s % 3][nt]);
      mfma_bf16(acc[1][nt], a1c, bq[s % 3][nt]);
    }
    a0c = a0n; a1c = a1n;
  }

  asm volatile("s_nop 7\n\ts_nop 7\n\ts_nop 4");
#pragma unroll
  for (int mt = 0; mt < 2; ++mt) {
#pragma unroll
    for (int nt = 0; nt < 4; ++nt) {
      int co = co0 + wn * 64 + nt * 16 + l15;
      float bv = bias[co];
#pragma unroll
      for (int r = 0; r < 4; ++r) {
        int sp = wm * 32 + mt * 16 + lk * 4 + r;
        int gi = i0 + (sp >> 3), gj = j0 + (sp & 7);
        if (gi < T99 && gj < T99) {
          float v = fmaxf(acc[mt][nt][r] + bv, 0.f);
          out[((size_t)(b * T99 + gi) * T99 + gj) * 256 + co] = f2bf(v);
        }
      }
    }
  }
}

// ---------------- p3: both channels per row ----------------
__global__ __launch_bounds__(256) void k_p3(const unsigned short* __restrict__ p2o,
                                            const float* __restrict__ w, const float* __restrict__ bias,
                                            float* __restrict__ cm) {
  int idx = blockIdx.x * 256 + threadIdx.x;
  if (idx >= 2 * T99 * T99) return;
  int j = idx % T99, i = (idx / T99) % T99, b = idx / (T99 * T99);
  float a0 = bias[0], a1 = bias[1];
  const unsigned short* row = p2o + ((size_t)(b * T99 + i) * T99 + j) * 256;
  for (int c8 = 0; c8 < 256; c8 += 8) {
    s8v v = *(const s8v*)&row[c8];
#pragma unroll
    for (int q = 0; q < 8; ++q) {
      float x = bf2f((unsigned short)v[q]);
      a0 += w[c8 + q] * x;
      a1 += w[256 + c8 + q] * x;
    }
  }
  size_t base = (size_t)b * 2 * T99 * T99 + (size_t)i * T99 + j;
  cm[base] = 1.f / (1.f + expf(-a0));
  cm[base + T99 * T99] = 1.f / (1.f + expf(-a1));
}

// ---------------- host ----------------
struct EncW {
  const float *qkvw, *qkvb, *ow, *ob, *l1w, *l1b, *l2w, *l2b, *n1g, *n1b, *n2g, *n2b, *nfg, *nfb;
};
struct EncBufs {
  float* x; unsigned short* xb;
  float* yb;
  unsigned short *qkvb, *attb, *hb;
  int M;
};

static GJ jqkv(const EncW& W, const unsigned short* Wb, int l, const EncBufs& B) {
  GJ j = {}; j.Ab = B.xb; j.W = Wb + (size_t)l * 786432;
  j.bias = W.qkvb + (size_t)l * 768; j.Yb = B.qkvb; j.flags = 4 | 8;
  j.M = B.M; j.N = 768; j.K = 256; return j;
}
static GJ jproj(const EncW& W, const unsigned short* Wb, int l, const EncBufs& B) {
  GJ j = {}; j.Ab = B.attb; j.W = Wb + (size_t)l * 786432 + 196608;
  j.bias = W.ob + (size_t)l * 256; j.R = B.x; j.Yf = B.yb; j.flags = 2;
  j.M = B.M; j.N = 256; j.K = 256; return j;
}
static GJ jffn1(const EncW& W, const unsigned short* Wb, int l, const EncBufs& B) {
  GJ j = {}; j.Ab = B.xb; j.W = Wb + (size_t)l * 786432 + 262144;
  j.bias = W.l1b + (size_t)l * 1024; j.Yb = B.hb; j.flags = 1 | 4 | 8;
  j.M = B.M; j.N = 1024; j.K = 256; return j;
}
static GJ jffn2(const EncW& W, const unsigned short* Wb, int l, const EncBufs& B) {
  GJ j = {}; j.Ab = B.hb; j.W = Wb + (size_t)l * 786432 + 524288;
  j.bias = W.l2b + (size_t)l * 256; j.R = B.x; j.Yf = B.yb; j.flags = 2;
  j.M = B.M; j.N = 256; j.K = 1024; return j;
}

extern "C" void kernel_launch(void* const* d_in, const int* in_sizes, int n_in,
                              void* d_out, int out_size, void* d_ws, size_t ws_size,
                              hipStream_t stream) {
  (void)in_sizes; (void)n_in; (void)out_size; (void)ws_size;
  const float* x    = (const float*)d_in[0];
  const float* cbw  = (const float*)d_in[1];
  const float* cbb  = (const float*)d_in[2];
  EncW tg = {(const float*)d_in[3],  (const float*)d_in[4],  (const float*)d_in[5],  (const float*)d_in[6],
             (const float*)d_in[7],  (const float*)d_in[8],  (const float*)d_in[9],  (const float*)d_in[10],
             (const float*)d_in[11], (const float*)d_in[12], (const float*)d_in[13], (const float*)d_in[14],
             (const float*)d_in[15], (const float*)d_in[16]};
  EncW tl = {(const float*)d_in[17], (const float*)d_in[18], (const float*)d_in[19], (const float*)d_in[20],
             (const float*)d_in[21], (const float*)d_in[22], (const float*)d_in[23], (const float*)d_in[24],
             (const float*)d_in[25], (const float*)d_in[26], (const float*)d_in[27], (const float*)d_in[28],
             (const float*)d_in[29], (const float*)d_in[30]};
  const float* s1w = (const float*)d_in[31];
  const float* s1b = (const float*)d_in[32];
  const float* s2w = (const float*)d_in[33];
  const float* s2b = (const float*)d_in[34];
  const float* c3w = (const float*)d_in[35];
  const float* c3b = (const float*)d_in[36];
  const float* p1w = (const float*)d_in[37];
  const float* p1b = (const float*)d_in[38];
  const float* p2w = (const float*)d_in[39];
  const float* p2b = (const float*)d_in[40];
  const float* p3w = (const float*)d_in[41];
  const float* p3b = (const float*)d_in[42];

  float* outp = (float*)d_out; // [cm 39204][start1 198]

  char* wp = (char*)d_ws;
  auto alloc = [&](size_t bytes) -> void* {
    void* p = (void*)wp;
    wp += (bytes + 255) & ~(size_t)255;
    return p;
  };
  float* base  = (float*)alloc(sizeof(float) * 2 * CC * T99);
  const int ML = 198, MG = 396;
  EncBufs BG, BL;
  BG.M = MG; BL.M = ML;
  BG.x  = (float*)alloc(sizeof(float) * MG * 256);
  BL.x  = (float*)alloc(sizeof(float) * ML * 256);
  BG.xb = (unsigned short*)alloc(sizeof(short) * MG * 256);
  BL.xb = (unsigned short*)alloc(sizeof(short) * ML * 256);
  BG.yb = (float*)alloc(sizeof(float) * MG * 256);
  BL.yb = (float*)alloc(sizeof(float) * ML * 256);
  BG.qkvb = (unsigned short*)alloc(sizeof(short) * MG * 768);
  BL.qkvb = (unsigned short*)alloc(sizeof(short) * ML * 768);
  BG.attb = (unsigned short*)alloc(sizeof(short) * MG * 256);
  BL.attb = (unsigned short*)alloc(sizeof(short) * ML * 256);
  BG.hb = (unsigned short*)alloc(sizeof(short) * MG * 1024);
  BL.hb = (unsigned short*)alloc(sizeof(short) * ML * 1024);
  float* encg  = (float*)alloc(sizeof(float) * MG * 256);
  float* encl  = (float*)alloc(sizeof(float) * ML * 256);
  float* base2 = (float*)alloc(sizeof(float) * 2 * CC * T99);
  unsigned short* b2t = (unsigned short*)alloc(sizeof(short) * 2 * T99 * 256);
  unsigned short* w3tb = (unsigned short*)alloc(sizeof(short) * 32 * 256 * 256);
  unsigned short* Gb = (unsigned short*)alloc(sizeof(short) * (2 * NS_ * T99 * 256 + 512));
  unsigned short* pinb = (unsigned short*)alloc(sizeof(short) * 2 * T99 * T99 * 256);
  unsigned short* p1o  = (unsigned short*)alloc(sizeof(short) * 2 * T99 * T99 * 256);
  unsigned short* p2o  = (unsigned short*)alloc(sizeof(short) * 2 * T99 * T99 * 256);
  unsigned short* wb2a = (unsigned short*)alloc(sizeof(short) * 9 * 256 * 256);
  unsigned short* wb2b = (unsigned short*)alloc(sizeof(short) * 9 * 256 * 256);
  unsigned short* wtgb = (unsigned short*)alloc(sizeof(short) * 6 * 786432);
  unsigned short* wtlb = (unsigned short*)alloc(sizeof(short) * 3 * 786432);
  float* c1F = (float*)alloc(sizeof(float) * 256);
  unsigned short* c1B = (unsigned short*)alloc(sizeof(short) * 256);
  float* c2F = (float*)alloc(sizeof(float) * 256);
  unsigned short* c2B = (unsigned short*)alloc(sizeof(short) * 256);

  // 0. preamble
  k_convW<<<dim3(4096), dim3(256), 0, stream>>>(tg.qkvw, tg.ow, tg.l1w, tg.l2w, 6, wtgb);
  k_convW<<<dim3(2048), dim3(256), 0, stream>>>(tl.qkvw, tl.ow, tl.l1w, tl.l2w, 3, wtlb);
  k_w3tb<<<dim3(8192), dim3(256), 0, stream>>>(c3w, w3tb);
  k_wb2<<<dim3(288), dim3(256), 0, stream>>>(p1w, wb2a);
  k_wb2<<<dim3(288), dim3(256), 0, stream>>>(p2w, wb2b);
  k_cvec<<<dim3(256), dim3(256), 0, stream>>>(p1w, c3b, p1b, 1, c1F, c1B);
  k_cvec<<<dim3(256), dim3(256), 0, stream>>>(p2w, c1F, p2b, 0, c2F, c2B);
  // 1. conv stem + encoder inputs
  k_convbase<<<dim3(512), dim3(128), 0, stream>>>(x, cbw, cbb, base);
  k_build_xl<<<dim3(198), dim3(256), 0, stream>>>(base, BL.x, BL.xb);
  k_build_xg<<<dim3(396), dim3(256), 0, stream>>>(base, BG.x, BG.xb);

  // 2. layers 0..2 merged (local || global)
  const int mgG = 7;
  for (int l = 0; l < 3; ++l) {
    k_g2<<<dim3(mgG, 12, 2), dim3(256), 0, stream>>>(jqkv(tl, wtlb, l, BL), jqkv(tg, wtgb, l, BG));
    k_attn2<<<dim3(4 * NHH * T99, 1, 2), dim3(128), 0, stream>>>(BL.qkvb, BL.attb, LSTEP, 6,
                                                                 BG.qkvb, BG.attb, T99, 4);
    k_g2<<<dim3(mgG, 4, 2), dim3(256), 0, stream>>>(jproj(tl, wtlb, l, BL), jproj(tg, wtgb, l, BG));
    k_ln2<<<dim3(MG, 1, 2), dim3(256), 0, stream>>>(BL.yb, tl.n1g + l * 256, tl.n1b + l * 256, BL.x, BL.xb, ML,
                                                    BG.yb, tg.n1g + l * 256, tg.n1b + l * 256, BG.x, BG.xb, MG);
    k_g2<<<dim3(mgG, 16, 2), dim3(256), 0, stream>>>(jffn1(tl, wtlb, l, BL), jffn1(tg, wtgb, l, BG));
    k_g2<<<dim3(mgG, 4, 2), dim3(256), 0, stream>>>(jffn2(tl, wtlb, l, BL), jffn2(tg, wtgb, l, BG));
    k_ln2<<<dim3(MG, 1, 2), dim3(256), 0, stream>>>(BL.yb, tl.n2g + l * 256, tl.n2b + l * 256, BL.x, BL.xb, ML,
                                                    BG.yb, tg.n2g + l * 256, tg.n2b + l * 256, BG.x, BG.xb, MG);
  }
  // 3. global layers 3..5
  for (int l = 3; l < 6; ++l) {
    k_g<<<dim3(mgG, 12), dim3(256), 0, stream>>>(jqkv(tg, wtgb, l, BG));
    k_attn<<<dim3(4 * NHH * T99), dim3(128), 0, stream>>>(BG.qkvb, BG.attb, T99, 4);
    k_g<<<dim3(mgG, 4), dim3(256), 0, stream>>>(jproj(tg, wtgb, l, BG));
    k_ln<<<dim3(MG), dim3(256), 0, stream>>>(BG.yb, tg.n1g + l * 256, tg.n1b + l * 256, BG.x, BG.xb);
    k_g<<<dim3(mgG, 16), dim3(256), 0, stream>>>(jffn1(tg, wtgb, l, BG));
    k_g<<<dim3(mgG, 4), dim3(256), 0, stream>>>(jffn2(tg, wtgb, l, BG));
    k_ln<<<dim3(MG), dim3(256), 0, stream>>>(BG.yb, tg.n2g + l * 256, tg.n2b + l * 256, BG.x, BG.xb);
  }
  // 4. final LNs
  k_ln2<<<dim3(MG, 1, 2), dim3(256), 0, stream>>>(BL.x, tl.nfg, tl.nfb, encl, nullptr, ML,
                                                  BG.x, tg.nfg, tg.nfb, encg, nullptr, MG);
  // 5. combine + s-branch
  k_combine<<<dim3(198), dim3(256), 0, stream>>>(encl, encg, base2, b2t);
  k_sfuse<<<dim3(198), dim3(256), 0, stream>>>(base2, s1w, s1b, s2w, s2b, outp + 2 * 2 * T99 * T99);
  // 6. bm + conv3d
  k_Gm<<<dim3(2, 4, 64), dim3(256), 0, stream>>>(b2t, w3tb, Gb);
  k_ppre<<<dim3(T99 * T99), dim3(256), 0, stream>>>(Gb, c3b, (unsigned int*)pinb);
  // 7. p-branch
  k_conv3x3<<<dim3(169, 2, 2), dim3(256), 0, stream>>>(pinb, wb2a, p1b, c1B, 0, 0, 98, p1o);
  k_conv3x3<<<dim3(169, 2, 2), dim3(256), 0, stream>>>(p1o, wb2b, p2b, c2B, 2, 1, 97, p2o);
  k_p3<<<dim3(77), dim3(256), 0, stream>>>(p2o, p3w, p3b, outp);
}

// Round 12
// 626.311 us; speedup vs baseline: 1.7921x; 1.0145x over previous
//
#include <hip/hip_runtime.h>
#include <math.h>

// ---------------- constants ----------------
#define T99   99
#define CC    256
#define NHH   8
#define FEAT  400
#define NS_   32
#define LSTEP 33

typedef __attribute__((ext_vector_type(8))) short s8v;   // 8 x bf16 (as raw u16)
typedef __attribute__((ext_vector_type(4))) float f4v;   // MFMA accumulator

// non-volatile asm: data deps preserve correctness, scheduler may interleave loads
__device__ __forceinline__ void mfma_bf16(f4v& d, s8v a, s8v b) {
  asm("v_mfma_f32_16x16x32_bf16 %0, %1, %2, %0" : "+v"(d) : "v"(a), "v"(b));
}

__device__ __forceinline__ unsigned short f2bf(float f) {
  union { float f; unsigned u; } x; x.f = f;
  unsigned r = x.u + 0x7FFFu + ((x.u >> 16) & 1u);
  return (unsigned short)(r >> 16);
}
__device__ __forceinline__ float bf2f(unsigned short h) {
  union { unsigned u; float f; } x; x.u = ((unsigned)h) << 16;
  return x.f;
}
__device__ __forceinline__ float blo(unsigned u) { union { unsigned x; float f; } c; c.x = u << 16; return c.f; }
__device__ __forceinline__ float bhi(unsigned u) { union { unsigned x; float f; } c; c.x = u & 0xffff0000u; return c.f; }

__device__ __forceinline__ float pe_val(int pos, int c) {
  int i = c >> 1;
  float freq = expf((float)(2 * i) * (-0.03597789207803197f)); // -ln(10000)/256
  float ang = (float)pos * freq;
  return (c & 1) ? cosf(ang) : sinf(ang);
}

// ---------------- conv stem ----------------
__global__ __launch_bounds__(128) void k_convbase(const float* __restrict__ x,
                                                  const float* __restrict__ w,
                                                  const float* __restrict__ bias,
                                                  float* __restrict__ base) {
  int b = blockIdx.x >> 8, co = blockIdx.x & 255, t = threadIdx.x;
  if (t >= T99) return;
  int g = co >> 6;
  float acc = bias[co];
  const float* xp = x + (size_t)(b * FEAT + g * 100) * T99;
  const float* wp = w + (size_t)co * 300;
  for (int ic = 0; ic < 100; ++ic) {
    float x0 = (t > 0)  ? xp[ic * T99 + t - 1] : 0.f;
    float x1 = xp[ic * T99 + t];
    float x2 = (t < 98) ? xp[ic * T99 + t + 1] : 0.f;
    acc += wp[ic * 3] * x0 + wp[ic * 3 + 1] * x1 + wp[ic * 3 + 2] * x2;
  }
  base[(size_t)(b * CC + co) * T99 + t] = fmaxf(acc, 0.f);
}

// ---------------- weight conversion: pack {qkv,o,l1,l2} per layer into bf16 row-major blob ----------------
__global__ __launch_bounds__(256) void k_convW(const float* __restrict__ qkv, const float* __restrict__ o,
                                               const float* __restrict__ l1, const float* __restrict__ l2,
                                               int L, unsigned short* __restrict__ dst) {
  int total = L * 786432;
  for (int idx = blockIdx.x * 256 + threadIdx.x; idx < total; idx += gridDim.x * 256) {
    int l = idx / 786432, r = idx % 786432;
    float v;
    if (r < 196608)      v = qkv[(size_t)l * 196608 + r];
    else if (r < 262144) v = o[(size_t)l * 65536 + (r - 196608)];
    else if (r < 524288) v = l1[(size_t)l * 262144 + (r - 262144)];
    else                 v = l2[(size_t)l * 262144 + (r - 524288)];
    dst[idx] = f2bf(v);
  }
}

// ---------------- o_w transpose pack: wot[l][ci][co] = bf16(ow[l][co][ci]) ----------------
__global__ __launch_bounds__(256) void k_wot(const float* __restrict__ ow, int L,
                                             unsigned short* __restrict__ wot) {
  int idx = blockIdx.x * 256 + threadIdx.x;
  if (idx >= L * 65536) return;
  int l = idx >> 16, r = idx & 65535;
  int ci = r >> 8, co = r & 255;
  wot[idx] = f2bf(ow[(size_t)l * 65536 + co * 256 + ci]);
}

// ---------------- build encoder inputs ----------------
__global__ __launch_bounds__(256) void k_build_xg(const float* __restrict__ base, float* __restrict__ xg,
                                                  unsigned short* __restrict__ xgb) {
  int idx = blockIdx.x * 256 + threadIdx.x;
  int t = idx >> 10, r = idx & 1023, b4 = r >> 8, c = r & 255;
  float v = (b4 < 2) ? base[(size_t)(b4 * CC + c) * T99 + t]
                     : base[(size_t)((b4 - 2) * CC + c) * T99 + (98 - t)];
  v += pe_val(t, c);
  xg[idx] = v; xgb[idx] = f2bf(v);
}

__global__ __launch_bounds__(256) void k_build_xl(const float* __restrict__ base, float* __restrict__ xl,
                                                  unsigned short* __restrict__ xlb) {
  int idx = blockIdx.x * 256 + threadIdx.x;
  int ls = idx / 1536, r = idx % 1536, j = r >> 8, c = r & 255;
  int g = j >> 1, b = j & 1, t = ls * 3 + g;
  float v = base[(size_t)(b * CC + c) * T99 + t] + pe_val(ls, c);
  xl[idx] = v; xlb[idx] = f2bf(v);
}

// ================= GEMM (R6-proven: 32-wide ksteps, dual LDS staging) =================
// flags: 1=relu, 2=residual R, 4=write bf16 Yb, 8=skip fp32 Yf
struct GJ {
  const unsigned short* Ab;   // bf16 row-major [M][K]
  const unsigned short* W;    // bf16 row-major [N][K]
  const float* bias;
  const float* R;
  float* Yf;
  unsigned short* Yb;
  int M, N, K, flags;
};

__device__ void g_body(const GJ& j, int m0, int n0) {
  __shared__ __align__(16) unsigned short Al[64][40];
  __shared__ __align__(16) unsigned short Bl[64][40];
  int tid = threadIdx.x;
  int lane = tid & 63, w = tid >> 6, wm = w >> 1, wn = w & 1;
  int sp = tid >> 2, kc = (tid & 3) << 3;
  f4v acc[2][2];
#pragma unroll
  for (int mt = 0; mt < 2; ++mt)
#pragma unroll
    for (int nt = 0; nt < 2; ++nt) acc[mt][nt] = (f4v){0.f, 0.f, 0.f, 0.f};

  for (int k0 = 0; k0 < j.K; k0 += 32) {
    s8v av = {0, 0, 0, 0, 0, 0, 0, 0};
    int row = m0 + sp;
    if (row < j.M) av = *(const s8v*)&j.Ab[(size_t)row * j.K + k0 + kc];
    *(s8v*)&Al[sp][kc] = av;
    *(s8v*)&Bl[sp][kc] = *(const s8v*)&j.W[(size_t)(n0 + sp) * j.K + k0 + kc];
    __syncthreads();
    s8v af[2], bf[2];
#pragma unroll
    for (int mt = 0; mt < 2; ++mt)
      af[mt] = *(const s8v*)&Al[wm * 32 + mt * 16 + (lane & 15)][(lane >> 4) * 8];
#pragma unroll
    for (int nt = 0; nt < 2; ++nt)
      bf[nt] = *(const s8v*)&Bl[wn * 32 + nt * 16 + (lane & 15)][(lane >> 4) * 8];
#pragma unroll
    for (int mt = 0; mt < 2; ++mt)
#pragma unroll
      for (int nt = 0; nt < 2; ++nt) mfma_bf16(acc[mt][nt], af[mt], bf[nt]);
    __syncthreads();
  }
  asm volatile("s_nop 7\n\ts_nop 7\n\ts_nop 4");
#pragma unroll
  for (int mt = 0; mt < 2; ++mt) {
#pragma unroll
    for (int nt = 0; nt < 2; ++nt) {
      int col = n0 + wn * 32 + nt * 16 + (lane & 15);
      float bv = j.bias[col];
#pragma unroll
      for (int r = 0; r < 4; ++r) {
        int row = m0 + wm * 32 + mt * 16 + (lane >> 4) * 4 + r;
        if (row < j.M) {
          float v = acc[mt][nt][r] + bv;
          if (j.flags & 2) v += j.R[(size_t)row * j.N + col];
          if (j.flags & 1) v = fmaxf(v, 0.f);
          if (!(j.flags & 8)) j.Yf[(size_t)row * j.N + col] = v;
          if (j.flags & 4) j.Yb[(size_t)row * j.N + col] = f2bf(v);
        }
      }
    }
  }
}

__global__ __launch_bounds__(256) void k_g(GJ j) {
  if ((int)blockIdx.x * 64 >= j.M) return;
  g_body(j, blockIdx.x * 64, blockIdx.y * 64);
}

__global__ __launch_bounds__(256) void k_g2(GJ j0, GJ j1) {
  if (blockIdx.z == 0) {
    if ((int)blockIdx.x * 64 >= j0.M) return;
    g_body(j0, blockIdx.x * 64, blockIdx.y * 64);
  } else {
    if ((int)blockIdx.x * 64 >= j1.M) return;
    g_body(j1, blockIdx.x * 64, blockIdx.y * 64);
  }
}

// ========== fused attn + proj + residual + LN1 (block = one token row) ==========
__device__ void apl_body(const unsigned short* __restrict__ qkvb,
                         const unsigned short* __restrict__ Wt,   // [ci][co] bf16
                         const float* __restrict__ ob,
                         const float* __restrict__ g, const float* __restrict__ beta,
                         float* __restrict__ X, unsigned short* __restrict__ Xb,
                         int T_, int B_, int tok) {
  __shared__ float qrow[256];
  __shared__ float sc[8][100];
  __shared__ float den[8];
  __shared__ float att[256];
  __shared__ float rs[256], rq[256];
  int tid = threadIdx.x;
  int b = tok % B_;
  qrow[tid] = bf2f(qkvb[(size_t)tok * 768 + tid]);
  __syncthreads();
  // scores for all (h,k)
  for (int e = tid; e < 8 * T_; e += 256) {
    int h = e / T_, k = e % T_;
    const unsigned short* kp = qkvb + (size_t)(k * B_ + b) * 768 + 256 + h * 32;
    float d = 0.f;
#pragma unroll
    for (int i = 0; i < 32; ++i) d += qrow[h * 32 + i] * bf2f(kp[i]);
    sc[h][k] = d * 0.176776695296636881f;
  }
  __syncthreads();
  // per-head softmax (32-lane groups; halves of a wave64, lockstep)
  int h = tid >> 5, lane = tid & 31;
  float m = -1e30f;
  for (int k = lane; k < T_; k += 32) m = fmaxf(m, sc[h][k]);
#pragma unroll
  for (int msk = 16; msk >= 1; msk >>= 1) m = fmaxf(m, __shfl_xor(m, msk, 32));
  float sum = 0.f;
  for (int k = lane; k < T_; k += 32) {
    float p = expf(sc[h][k] - m);
    sc[h][k] = p; sum += p;
  }
#pragma unroll
  for (int msk = 16; msk >= 1; msk >>= 1) sum += __shfl_xor(sum, msk, 32);
  if (lane == 0) den[h] = sum;
  // PV: thread (h,d) == tid spans all 256 channels -> coalesced 512B V loads per k
  float o = 0.f;
  for (int k = 0; k < T_; ++k)
    o += sc[h][k] * bf2f(qkvb[(size_t)(k * B_ + b) * 768 + 512 + tid]);
  o /= den[h];
  att[tid] = o;
  __syncthreads();
  // proj matvec (W^T coalesced) + bias
  float acc = ob[tid];
#pragma unroll 8
  for (int ci = 0; ci < 256; ++ci) acc += att[ci] * bf2f(Wt[(size_t)ci * 256 + tid]);
  // residual + LN
  float v = acc + X[(size_t)tok * 256 + tid];
  rs[tid] = v; rq[tid] = v * v; __syncthreads();
  for (int oo = 128; oo > 0; oo >>= 1) { if (tid < oo) { rs[tid] += rs[tid + oo]; rq[tid] += rq[tid + oo]; } __syncthreads(); }
  float mu = rs[0] * (1.f / 256.f);
  float var = rq[0] * (1.f / 256.f) - mu * mu;
  float r = (v - mu) * rsqrtf(var + 1e-5f) * g[tid] + beta[tid];
  X[(size_t)tok * 256 + tid] = r;
  Xb[(size_t)tok * 256 + tid] = f2bf(r);
}

__global__ __launch_bounds__(256) void k_apl(const unsigned short* qkvb, const unsigned short* Wt,
                                             const float* ob, const float* g, const float* beta,
                                             float* X, unsigned short* Xb, int T_, int B_, int M) {
  if ((int)blockIdx.x >= M) return;
  apl_body(qkvb, Wt, ob, g, beta, X, Xb, T_, B_, blockIdx.x);
}

__global__ __launch_bounds__(256) void k_apl2(const unsigned short* q0, const unsigned short* Wt0,
                                              const float* ob0, const float* g0, const float* be0,
                                              float* X0, unsigned short* Xb0, int T0, int B0, int M0,
                                              const unsigned short* q1, const unsigned short* Wt1,
                                              const float* ob1, const float* g1, const float* be1,
                                              float* X1, unsigned short* Xb1, int T1, int B1, int M1) {
  int tok = blockIdx.x;
  if (blockIdx.z == 0) {
    if (tok >= M0) return;
    apl_body(q0, Wt0, ob0, g0, be0, X0, Xb0, T0, B0, tok);
  } else {
    if (tok >= M1) return;
    apl_body(q1, Wt1, ob1, g1, be1, X1, Xb1, T1, B1, tok);
  }
}

// ---------------- layer norm (fp32 out + optional bf16 mirror) ----------------
__device__ __forceinline__ void ln_body(const float* __restrict__ X, const float* __restrict__ g,
                                        const float* __restrict__ bb, float* __restrict__ Y,
                                        unsigned short* __restrict__ Yb, int tok) {
  __shared__ float rs[256], rq[256];
  int c = threadIdx.x;
  float v = X[(size_t)tok * 256 + c];
  rs[c] = v; rq[c] = v * v; __syncthreads();
  for (int o = 128; o > 0; o >>= 1) { if (c < o) { rs[c] += rs[c + o]; rq[c] += rq[c + o]; } __syncthreads(); }
  float mu = rs[0] * (1.f / 256.f);
  float var = rq[0] * (1.f / 256.f) - mu * mu;
  float r = (v - mu) * rsqrtf(var + 1e-5f) * g[c] + bb[c];
  Y[(size_t)tok * 256 + c] = r;
  if (Yb) Yb[(size_t)tok * 256 + c] = f2bf(r);
}

__global__ __launch_bounds__(256) void k_ln(const float* __restrict__ X, const float* __restrict__ g,
                                            const float* __restrict__ bb, float* __restrict__ Y,
                                            unsigned short* __restrict__ Yb) {
  ln_body(X, g, bb, Y, Yb, blockIdx.x);
}

__global__ __launch_bounds__(256) void k_ln2(const float* __restrict__ X0, const float* __restrict__ g0,
                                             const float* __restrict__ bb0, float* __restrict__ Y0,
                                             unsigned short* __restrict__ Yb0, int n0,
                                             const float* __restrict__ X1, const float* __restrict__ g1,
                                             const float* __restrict__ bb1, float* __restrict__ Y1,
                                             unsigned short* __restrict__ Yb1, int n1) {
  int tok = blockIdx.x;
  if (blockIdx.z == 0) { if (tok < n0) ln_body(X0, g0, bb0, Y0, Yb0, tok); }
  else                 { if (tok < n1) ln_body(X1, g1, bb1, Y1, Yb1, tok); }
}

// ---------------- combine: base2 fp32 [b][c][t] + b2t bf16 [b][t][c] ----------------
__global__ __launch_bounds__(256) void k_combine(const float* __restrict__ encl, const float* __restrict__ encg,
                                                 float* __restrict__ base2, unsigned short* __restrict__ b2t) {
  int idx = blockIdx.x * 256 + threadIdx.x;
  int t = idx % T99, c = (idx / T99) & 255, b = idx / (CC * T99);
  int ls = t / 3, g = t % 3;
  float v = encl[(size_t)(ls * 6 + g * 2 + b) * 256 + c]
          + encg[(size_t)(t * 4 + b) * 256 + c]
          + encg[(size_t)((98 - t) * 4 + 2 + b) * 256 + c];
  base2[idx] = v;
  b2t[((size_t)(b * T99) + t) * 256 + c] = f2bf(v);
}

// ---------------- fused s-branch ----------------
__global__ __launch_bounds__(256) void k_sfuse(const float* __restrict__ base2, const float* __restrict__ s1w,
                                               const float* __restrict__ s1b, const float* __restrict__ s2w,
                                               const float* __restrict__ s2b, float* __restrict__ out) {
  __shared__ float rs[256];
  int b = blockIdx.x / T99, t = blockIdx.x % T99, co = threadIdx.x;
  int g = co >> 6;
  float acc = s1b[co];
  const float* xp = base2 + (size_t)(b * CC + g * 64) * T99;
  const float* wp = s1w + (size_t)co * 192;
  for (int ic = 0; ic < 64; ++ic) {
    float x0 = (t > 0)  ? xp[ic * T99 + t - 1] : 0.f;
    float x1 = xp[ic * T99 + t];
    float x2 = (t < 98) ? xp[ic * T99 + t + 1] : 0.f;
    acc += wp[ic * 3] * x0 + wp[ic * 3 + 1] * x1 + wp[ic * 3 + 2] * x2;
  }
  rs[co] = fmaxf(acc, 0.f) * s2w[co];
  __syncthreads();
  for (int o = 128; o > 0; o >>= 1) { if (co < o) rs[co] += rs[co + o]; __syncthreads(); }
  if (co == 0) out[blockIdx.x] = 1.f / (1.f + expf(-(rs[0] + s2b[0])));
}

// ---------------- w3 pack: w3tb[n][co][ci] bf16 = c3w[co][ci][n] ----------------
__global__ __launch_bounds__(256) void k_w3tb(const float* __restrict__ c3w, unsigned short* __restrict__ w3tb) {
  int idx = blockIdx.x * 256 + threadIdx.x;
  int ci = idx & 255, co = (idx >> 8) & 255, n = idx >> 16;
  w3tb[idx] = f2bf(c3w[((size_t)(co << 8) + ci) * 32 + n]);
}

// ---------------- Gb via MFMA: 64 batched GEMMs (99t x 64co x 256ci) ----------------
__global__ __launch_bounds__(256) void k_Gm(const unsigned short* __restrict__ b2t,
                                            const unsigned short* __restrict__ w3tb,
                                            unsigned short* __restrict__ Gb) {
  __shared__ __align__(16) unsigned short Al[64][40];
  __shared__ __align__(16) unsigned short Bl[64][40];
  int nb = blockIdx.z, n = nb >> 1, b = nb & 1;
  int m0 = blockIdx.x * 64, n0 = blockIdx.y * 64;
  int tid = threadIdx.x;
  if (blockIdx.x == 0 && blockIdx.y == 0 && nb == 0)
    ((unsigned int*)(Gb + (size_t)NS_ * T99 * 512))[tid] = 0u;
  const unsigned short* A = b2t + (size_t)b * T99 * 256;
  const unsigned short* W = w3tb + (size_t)n * 65536;
  int lane = tid & 63, w = tid >> 6, wm = w >> 1, wn = w & 1;
  int sp = tid >> 2, kc = (tid & 3) << 3;
  f4v acc[2][2];
#pragma unroll
  for (int mt = 0; mt < 2; ++mt)
#pragma unroll
    for (int nt = 0; nt < 2; ++nt) acc[mt][nt] = (f4v){0.f, 0.f, 0.f, 0.f};
#pragma unroll
  for (int k0 = 0; k0 < 256; k0 += 32) {
    s8v av = {0, 0, 0, 0, 0, 0, 0, 0};
    int row = m0 + sp;
    if (row < T99) av = *(const s8v*)&A[(size_t)row * 256 + k0 + kc];
    *(s8v*)&Al[sp][kc] = av;
    *(s8v*)&Bl[sp][kc] = *(const s8v*)&W[(size_t)(n0 + sp) * 256 + k0 + kc];
    __syncthreads();
    s8v af[2], bf[2];
#pragma unroll
    for (int mt = 0; mt < 2; ++mt)
      af[mt] = *(const s8v*)&Al[wm * 32 + mt * 16 + (lane & 15)][(lane >> 4) * 8];
#pragma unroll
    for (int nt = 0; nt < 2; ++nt)
      bf[nt] = *(const s8v*)&Bl[wn * 32 + nt * 16 + (lane & 15)][(lane >> 4) * 8];
#pragma unroll
    for (int mt = 0; mt < 2; ++mt)
#pragma unroll
      for (int nt = 0; nt < 2; ++nt) mfma_bf16(acc[mt][nt], af[mt], bf[nt]);
    __syncthreads();
  }
  asm volatile("s_nop 7\n\ts_nop 7\n\ts_nop 4");
#pragma unroll
  for (int mt = 0; mt < 2; ++mt) {
#pragma unroll
    for (int nt = 0; nt < 2; ++nt) {
      int co = n0 + wn * 32 + nt * 16 + (lane & 15);
#pragma unroll
      for (int r = 0; r < 4; ++r) {
        int t = m0 + wm * 32 + mt * 16 + (lane >> 4) * 4 + r;
        if (t < T99)
          Gb[((size_t)(n * T99 + t) * 256 + co) * 2 + b] = f2bf(acc[mt][nt][r]);
      }
    }
  }
}

// ---------------- p_pre: split-k 256-thread ----------------
__global__ __launch_bounds__(256) void k_ppre(const unsigned short* __restrict__ Gb,
                                              const float* __restrict__ c3b,
                                              unsigned int* __restrict__ pinb32) {
  __shared__ float w0s[96], w1s[96];
  __shared__ int   ofs[96];
  __shared__ float part[128][4];
  int e = blockIdx.x % T99, s = blockIdx.x / T99;
  int tid = threadIdx.x;
  if (s >= e) {
    if (tid < 128) {
      float z0 = fmaxf(c3b[2 * tid], 0.f), z1 = fmaxf(c3b[2 * tid + 1], 0.f);
      unsigned int zz = ((unsigned)f2bf(z1) << 16) | (unsigned)f2bf(z0);
      pinb32[((size_t)s * T99 + e) * 128 + tid] = zz;
      pinb32[((size_t)(T99 + s) * T99 + e) * 128 + tid] = zz;
    }
    return;
  }
  if (tid < 96) {
    double center = (double)(e - s + 1);
    double S = ((double)s - 0.5 * center) + ((2.0 * center - 1.0) / 95.0) * (double)tid;
    double dn = trunc(S);
    double dec = S - dn;
    int di = (int)dn;
    double uc = ceil(S);
    int ui = (int)uc;
    int n = tid / 3;
    float w0 = 0.f, w1 = 0.f;
    int r0 = 0;
    if (dn >= 0.0 && dn <= 98.0) {
      r0 = di;
      w0 = (float)((1.0 - dec) / 3.0);
      if (uc >= 0.0 && uc <= 98.0) {
        if (ui == di) w0 += (float)(dec / 3.0);
        else          w1  = (float)(dec / 3.0);
      }
    }
    w0s[tid] = w0; w1s[tid] = w1;
    ofs[tid] = (n * T99 + r0) * 1024;
  }
  __syncthreads();
  int ch = tid & 127, half = tid >> 7;
  float a00 = 0.f, a01 = 0.f, a10 = 0.f, a11 = 0.f;
  const char* basep = (const char*)Gb + ch * 8;
  int k0 = half * 48;
#pragma unroll 8
  for (int k = k0; k < k0 + 48; ++k) {
    float w0 = w0s[k], w1 = w1s[k];
    const uint2* p = (const uint2*)(basep + ofs[k]);
    uint2 u0 = p[0];
    uint2 u1 = p[128];
    a00 += w0 * blo(u0.x) + w1 * blo(u1.x);
    a01 += w0 * bhi(u0.x) + w1 * bhi(u1.x);
    a10 += w0 * blo(u0.y) + w1 * blo(u1.y);
    a11 += w0 * bhi(u0.y) + w1 * bhi(u1.y);
  }
  if (half) { part[ch][0] = a00; part[ch][1] = a01; part[ch][2] = a10; part[ch][3] = a11; }
  __syncthreads();
  if (tid < 128) {
    a00 += part[ch][0]; a01 += part[ch][1]; a10 += part[ch][2]; a11 += part[ch][3];
    float b0 = c3b[2 * tid], b1 = c3b[2 * tid + 1];
    unsigned int zb0 = ((unsigned)f2bf(fmaxf(a10 + b1, 0.f)) << 16) | (unsigned)f2bf(fmaxf(a00 + b0, 0.f));
    unsigned int zb1 = ((unsigned)f2bf(fmaxf(a11 + b1, 0.f)) << 16) | (unsigned)f2bf(fmaxf(a01 + b0, 0.f));
    pinb32[((size_t)s * T99 + e) * 128 + tid] = zb0;
    pinb32[((size_t)(T99 + s) * T99 + e) * 128 + tid] = zb1;
  }
}

// ---------------- weight pack for conv3x3 ----------------
__global__ __launch_bounds__(256) void k_wb2(const float* __restrict__ pw, unsigned short* __restrict__ wbf) {
  int idx = blockIdx.x * 256 + threadIdx.x;
  if (idx >= 73728) return;
  int lane = idx & 63;
  int cog  = (idx >> 6) & 15;
  int kst  = (idx >> 10) & 7;
  int tap  = idx >> 13;
  int co = cog * 16 + (lane & 15);
  int k  = kst * 32 + (lane >> 4) * 8;
  s8v v;
#pragma unroll
  for (int j = 0; j < 8; ++j)
    v[j] = (short)f2bf(pw[((size_t)co * 256 + k + j) * 9 + tap]);
  *(s8v*)&wbf[(size_t)idx * 8] = v;
}

// ---------------- const-vector for conv const-region ----------------
__global__ __launch_bounds__(256) void k_cvec(const float* __restrict__ pw, const float* __restrict__ cin,
                                              const float* __restrict__ bias, int reluCin,
                                              float* __restrict__ coutF, unsigned short* __restrict__ coutB) {
  __shared__ float rs[256];
  int co = blockIdx.x, ci = threadIdx.x;
  float c = cin[ci];
  if (reluCin) c = fmaxf(c, 0.f);
  const float* wp = pw + ((size_t)co * 256 + ci) * 9;
  float wsum = 0.f;
#pragma unroll
  for (int t = 0; t < 9; ++t) wsum += wp[t];
  rs[ci] = wsum * c;
  __syncthreads();
  for (int o = 128; o > 0; o >>= 1) { if (ci < o) rs[ci] += rs[ci + o]; __syncthreads(); }
  if (ci == 0) {
    float r = fmaxf(bias[co] + rs[0], 0.f);
    coutF[co] = r;
    coutB[co] = f2bf(r);
  }
}

// ---------------- 3x3 conv: halo-LDS, sw-pipelined MFMA, const-region skip ----------------
__device__ __forceinline__ int aoff(int s) {
  int tap = s >> 3, kst = s & 7;
  return ((tap / 3) * 10 + (tap % 3)) * 264 + kst * 32;
}
__device__ __forceinline__ void ldb4(const unsigned short* __restrict__ B0, int s, s8v* dst) {
#pragma unroll
  for (int nt = 0; nt < 4; ++nt) dst[nt] = *(const s8v*)(B0 + (size_t)s * 8192 + nt * 512);
}

__global__ __launch_bounds__(256) void k_conv3x3(const unsigned short* __restrict__ in,
                                                 const unsigned short* __restrict__ wbf,
                                                 const float* __restrict__ bias,
                                                 const unsigned short* __restrict__ cvecB,
                                                 int D, int lo, int hi,
                                                 unsigned short* __restrict__ out) {
  __shared__ __align__(16) unsigned short Ah[100 * 264];
  int b = blockIdx.z;
  int co0 = blockIdx.y * 128;
  int ti = blockIdx.x / 13, tj = blockIdx.x % 13;
  int i0 = ti * 8, j0 = tj * 8;
  int tid = threadIdx.x;

  if (i0 - 1 >= lo && i0 + 8 <= hi && j0 - 1 >= lo && j0 + 8 <= hi && i0 - 1 >= j0 + 8 + D) {
    const unsigned int* cv = (const unsigned int*)(cvecB + co0);
    unsigned int* ob = (unsigned int*)out;
#pragma unroll
    for (int r = 0; r < 16; ++r) {
      int idx = r * 256 + tid;
      int sp = idx >> 6, cp = idx & 63;
      int gi = i0 + (sp >> 3), gj = j0 + (sp & 7);
      ob[((size_t)(b * T99 + gi) * T99 + gj) * 128 + (co0 >> 1) + cp] = cv[cp];
    }
    return;
  }

#pragma unroll
  for (int it = 0; it < 13; ++it) {
    int chunk = it * 256 + tid;
    if (chunk < 3200) {
      int row = chunk >> 5;
      int cc = (chunk & 31) * 8;
      int gi = i0 + row / 10 - 1, gj = j0 + row % 10 - 1;
      s8v val = {0, 0, 0, 0, 0, 0, 0, 0};
      if (gi >= 0 && gi < T99 && gj >= 0 && gj < T99)
        val = *(const s8v*)&in[((size_t)(b * T99 + gi) * T99 + gj) * 256 + cc];
      *(s8v*)&Ah[row * 264 + cc] = val;
    }
  }
  __syncthreads();

  int lane = tid & 63, w = tid >> 6, wm = w >> 1, wn = w & 1;
  int l15 = lane & 15, lk = lane >> 4;
  int spL0 = wm * 32 + l15, spL1 = spL0 + 16;
  int hr0 = (spL0 >> 3) * 10 + (spL0 & 7);
  int hr1 = (spL1 >> 3) * 10 + (spL1 & 7);
  const unsigned short* A0 = &Ah[hr0 * 264 + lk * 8];
  const unsigned short* A1 = &Ah[hr1 * 264 + lk * 8];
  int cogbase = blockIdx.y * 8 + wn * 4;
  const unsigned short* B0 = wbf + (size_t)cogbase * 512 + (size_t)lane * 8;

  f4v acc[2][4];
#pragma unroll
  for (int mt = 0; mt < 2; ++mt)
#pragma unroll
    for (int nt = 0; nt < 4; ++nt) acc[mt][nt] = (f4v){0.f, 0.f, 0.f, 0.f};

  s8v a0c, a1c, a0n, a1n;
  s8v bq[3][4];
  a0c = *(const s8v*)(A0 + aoff(0));
  a1c = *(const s8v*)(A1 + aoff(0));
  a0n = a0c; a1n = a1c;
  ldb4(B0, 0, bq[0]);
  ldb4(B0, 1, bq[1]);
#pragma unroll
  for (int s = 0; s < 72; ++s) {
    if (s + 2 < 72) ldb4(B0, s + 2, bq[(s + 2) % 3]);
    if (s + 1 < 72) {
      a0n = *(const s8v*)(A0 + aoff(s + 1));
      a1n = *(const s8v*)(A1 + aoff(s + 1));
    }
#pragma unroll
    for (int nt = 0; nt < 4; ++nt) {
      mfma_bf16(acc[0][nt], a0c, bq[s % 3][nt]);
      mfma_bf16(acc[1][nt], a1c, bq[s % 3][nt]);
    }
    a0c = a0n; a1c = a1n;
  }

  asm volatile("s_nop 7\n\ts_nop 7\n\ts_nop 4");
#pragma unroll
  for (int mt = 0; mt < 2; ++mt) {
#pragma unroll
    for (int nt = 0; nt < 4; ++nt) {
      int co = co0 + wn * 64 + nt * 16 + l15;
      float bv = bias[co];
#pragma unroll
      for (int r = 0; r < 4; ++r) {
        int sp = wm * 32 + mt * 16 + lk * 4 + r;
        int gi = i0 + (sp >> 3), gj = j0 + (sp & 7);
        if (gi < T99 && gj < T99) {
          float v = fmaxf(acc[mt][nt][r] + bv, 0.f);
          out[((size_t)(b * T99 + gi) * T99 + gj) * 256 + co] = f2bf(v);
        }
      }
    }
  }
}

// ---------------- p3: both channels per row ----------------
__global__ __launch_bounds__(256) void k_p3(const unsigned short* __restrict__ p2o,
                                            const float* __restrict__ w, const float* __restrict__ bias,
                                            float* __restrict__ cm) {
  int idx = blockIdx.x * 256 + threadIdx.x;
  if (idx >= 2 * T99 * T99) return;
  int j = idx % T99, i = (idx / T99) % T99, b = idx / (T99 * T99);
  float a0 = bias[0], a1 = bias[1];
  const unsigned short* row = p2o + ((size_t)(b * T99 + i) * T99 + j) * 256;
  for (int c8 = 0; c8 < 256; c8 += 8) {
    s8v v = *(const s8v*)&row[c8];
#pragma unroll
    for (int q = 0; q < 8; ++q) {
      float x = bf2f((unsigned short)v[q]);
      a0 += w[c8 + q] * x;
      a1 += w[256 + c8 + q] * x;
    }
  }
  size_t base = (size_t)b * 2 * T99 * T99 + (size_t)i * T99 + j;
  cm[base] = 1.f / (1.f + expf(-a0));
  cm[base + T99 * T99] = 1.f / (1.f + expf(-a1));
}

// ---------------- host ----------------
struct EncW {
  const float *qkvw, *qkvb, *ow, *ob, *l1w, *l1b, *l2w, *l2b, *n1g, *n1b, *n2g, *n2b, *nfg, *nfb;
};
struct EncBufs {
  float* x; unsigned short* xb;
  float* yb;
  unsigned short *qkvb, *hb;
  int M;
};

static GJ jqkv(const EncW& W, const unsigned short* Wb, int l, const EncBufs& B) {
  GJ j = {}; j.Ab = B.xb; j.W = Wb + (size_t)l * 786432;
  j.bias = W.qkvb + (size_t)l * 768; j.Yb = B.qkvb; j.flags = 4 | 8;
  j.M = B.M; j.N = 768; j.K = 256; return j;
}
static GJ jffn1(const EncW& W, const unsigned short* Wb, int l, const EncBufs& B) {
  GJ j = {}; j.Ab = B.xb; j.W = Wb + (size_t)l * 786432 + 262144;
  j.bias = W.l1b + (size_t)l * 1024; j.Yb = B.hb; j.flags = 1 | 4 | 8;
  j.M = B.M; j.N = 1024; j.K = 256; return j;
}
static GJ jffn2(const EncW& W, const unsigned short* Wb, int l, const EncBufs& B) {
  GJ j = {}; j.Ab = B.hb; j.W = Wb + (size_t)l * 786432 + 524288;
  j.bias = W.l2b + (size_t)l * 256; j.R = B.x; j.Yf = B.yb; j.flags = 2;
  j.M = B.M; j.N = 256; j.K = 1024; return j;
}

extern "C" void kernel_launch(void* const* d_in, const int* in_sizes, int n_in,
                              void* d_out, int out_size, void* d_ws, size_t ws_size,
                              hipStream_t stream) {
  (void)in_sizes; (void)n_in; (void)out_size; (void)ws_size;
  const float* x    = (const float*)d_in[0];
  const float* cbw  = (const float*)d_in[1];
  const float* cbb  = (const float*)d_in[2];
  EncW tg = {(const float*)d_in[3],  (const float*)d_in[4],  (const float*)d_in[5],  (const float*)d_in[6],
             (const float*)d_in[7],  (const float*)d_in[8],  (const float*)d_in[9],  (const float*)d_in[10],
             (const float*)d_in[11], (const float*)d_in[12], (const float*)d_in[13], (const float*)d_in[14],
             (const float*)d_in[15], (const float*)d_in[16]};
  EncW tl = {(const float*)d_in[17], (const float*)d_in[18], (const float*)d_in[19], (const float*)d_in[20],
             (const float*)d_in[21], (const float*)d_in[22], (const float*)d_in[23], (const float*)d_in[24],
             (const float*)d_in[25], (const float*)d_in[26], (const float*)d_in[27], (const float*)d_in[28],
             (const float*)d_in[29], (const float*)d_in[30]};
  const float* s1w = (const float*)d_in[31];
  const float* s1b = (const float*)d_in[32];
  const float* s2w = (const float*)d_in[33];
  const float* s2b = (const float*)d_in[34];
  const float* c3w = (const float*)d_in[35];
  const float* c3b = (const float*)d_in[36];
  const float* p1w = (const float*)d_in[37];
  const float* p1b = (const float*)d_in[38];
  const float* p2w = (const float*)d_in[39];
  const float* p2b = (const float*)d_in[40];
  const float* p3w = (const float*)d_in[41];
  const float* p3b = (const float*)d_in[42];

  float* outp = (float*)d_out; // [cm 39204][start1 198]

  char* wp = (char*)d_ws;
  auto alloc = [&](size_t bytes) -> void* {
    void* p = (void*)wp;
    wp += (bytes + 255) & ~(size_t)255;
    return p;
  };
  float* base  = (float*)alloc(sizeof(float) * 2 * CC * T99);
  const int ML = 198, MG = 396;
  EncBufs BG, BL;
  BG.M = MG; BL.M = ML;
  BG.x  = (float*)alloc(sizeof(float) * MG * 256);
  BL.x  = (float*)alloc(sizeof(float) * ML * 256);
  BG.xb = (unsigned short*)alloc(sizeof(short) * MG * 256);
  BL.xb = (unsigned short*)alloc(sizeof(short) * ML * 256);
  BG.yb = (float*)alloc(sizeof(float) * MG * 256);
  BL.yb = (float*)alloc(sizeof(float) * ML * 256);
  BG.qkvb = (unsigned short*)alloc(sizeof(short) * MG * 768);
  BL.qkvb = (unsigned short*)alloc(sizeof(short) * ML * 768);
  BG.hb = (unsigned short*)alloc(sizeof(short) * MG * 1024);
  BL.hb = (unsigned short*)alloc(sizeof(short) * ML * 1024);
  float* encg  = (float*)alloc(sizeof(float) * MG * 256);
  float* encl  = (float*)alloc(sizeof(float) * ML * 256);
  float* base2 = (float*)alloc(sizeof(float) * 2 * CC * T99);
  unsigned short* b2t = (unsigned short*)alloc(sizeof(short) * 2 * T99 * 256);
  unsigned short* w3tb = (unsigned short*)alloc(sizeof(short) * 32 * 256 * 256);
  unsigned short* Gb = (unsigned short*)alloc(sizeof(short) * (2 * NS_ * T99 * 256 + 512));
  unsigned short* pinb = (unsigned short*)alloc(sizeof(short) * 2 * T99 * T99 * 256);
  unsigned short* p1o  = (unsigned short*)alloc(sizeof(short) * 2 * T99 * T99 * 256);
  unsigned short* p2o  = (unsigned short*)alloc(sizeof(short) * 2 * T99 * T99 * 256);
  unsigned short* wb2a = (unsigned short*)alloc(sizeof(short) * 9 * 256 * 256);
  unsigned short* wb2b = (unsigned short*)alloc(sizeof(short) * 9 * 256 * 256);
  unsigned short* wtgb = (unsigned short*)alloc(sizeof(short) * 6 * 786432);
  unsigned short* wtlb = (unsigned short*)alloc(sizeof(short) * 3 * 786432);
  unsigned short* wotg = (unsigned short*)alloc(sizeof(short) * 6 * 65536);
  unsigned short* wotl = (unsigned short*)alloc(sizeof(short) * 3 * 65536);
  float* c1F = (float*)alloc(sizeof(float) * 256);
  unsigned short* c1B = (unsigned short*)alloc(sizeof(short) * 256);
  float* c2F = (float*)alloc(sizeof(float) * 256);
  unsigned short* c2B = (unsigned short*)alloc(sizeof(short) * 256);

  // 0. preamble
  k_convW<<<dim3(4096), dim3(256), 0, stream>>>(tg.qkvw, tg.ow, tg.l1w, tg.l2w, 6, wtgb);
  k_convW<<<dim3(2048), dim3(256), 0, stream>>>(tl.qkvw, tl.ow, tl.l1w, tl.l2w, 3, wtlb);
  k_wot<<<dim3(1536), dim3(256), 0, stream>>>(tg.ow, 6, wotg);
  k_wot<<<dim3(768), dim3(256), 0, stream>>>(tl.ow, 3, wotl);
  k_w3tb<<<dim3(8192), dim3(256), 0, stream>>>(c3w, w3tb);
  k_wb2<<<dim3(288), dim3(256), 0, stream>>>(p1w, wb2a);
  k_wb2<<<dim3(288), dim3(256), 0, stream>>>(p2w, wb2b);
  k_cvec<<<dim3(256), dim3(256), 0, stream>>>(p1w, c3b, p1b, 1, c1F, c1B);
  k_cvec<<<dim3(256), dim3(256), 0, stream>>>(p2w, c1F, p2b, 0, c2F, c2B);
  // 1. conv stem + encoder inputs
  k_convbase<<<dim3(512), dim3(128), 0, stream>>>(x, cbw, cbb, base);
  k_build_xl<<<dim3(198), dim3(256), 0, stream>>>(base, BL.x, BL.xb);
  k_build_xg<<<dim3(396), dim3(256), 0, stream>>>(base, BG.x, BG.xb);

  // 2. layers 0..2 merged (local || global)
  const int mgG = 7;
  for (int l = 0; l < 3; ++l) {
    k_g2<<<dim3(mgG, 12, 2), dim3(256), 0, stream>>>(jqkv(tl, wtlb, l, BL), jqkv(tg, wtgb, l, BG));
    k_apl2<<<dim3(MG, 1, 2), dim3(256), 0, stream>>>(
        BL.qkvb, wotl + (size_t)l * 65536, tl.ob + l * 256, tl.n1g + l * 256, tl.n1b + l * 256,
        BL.x, BL.xb, LSTEP, 6, ML,
        BG.qkvb, wotg + (size_t)l * 65536, tg.ob + l * 256, tg.n1g + l * 256, tg.n1b + l * 256,
        BG.x, BG.xb, T99, 4, MG);
    k_g2<<<dim3(mgG, 16, 2), dim3(256), 0, stream>>>(jffn1(tl, wtlb, l, BL), jffn1(tg, wtgb, l, BG));
    k_g2<<<dim3(mgG, 4, 2), dim3(256), 0, stream>>>(jffn2(tl, wtlb, l, BL), jffn2(tg, wtgb, l, BG));
    k_ln2<<<dim3(MG, 1, 2), dim3(256), 0, stream>>>(BL.yb, tl.n2g + l * 256, tl.n2b + l * 256, BL.x, BL.xb, ML,
                                                    BG.yb, tg.n2g + l * 256, tg.n2b + l * 256, BG.x, BG.xb, MG);
  }
  // 3. global layers 3..5
  for (int l = 3; l < 6; ++l) {
    k_g<<<dim3(mgG, 12), dim3(256), 0, stream>>>(jqkv(tg, wtgb, l, BG));
    k_apl<<<dim3(MG), dim3(256), 0, stream>>>(BG.qkvb, wotg + (size_t)l * 65536, tg.ob + l * 256,
                                              tg.n1g + l * 256, tg.n1b + l * 256, BG.x, BG.xb, T99, 4, MG);
    k_g<<<dim3(mgG, 16), dim3(256), 0, stream>>>(jffn1(tg, wtgb, l, BG));
    k_g<<<dim3(mgG, 4), dim3(256), 0, stream>>>(jffn2(tg, wtgb, l, BG));
    k_ln<<<dim3(MG), dim3(256), 0, stream>>>(BG.yb, tg.n2g + l * 256, tg.n2b + l * 256, BG.x, BG.xb);
  }
  // 4. final LNs
  k_ln2<<<dim3(MG, 1, 2), dim3(256), 0, stream>>>(BL.x, tl.nfg, tl.nfb, encl, nullptr, ML,
                                                  BG.x, tg.nfg, tg.nfb, encg, nullptr, MG);
  // 5. combine + s-branch
  k_combine<<<dim3(198), dim3(256), 0, stream>>>(encl, encg, base2, b2t);
  k_sfuse<<<dim3(198), dim3(256), 0, stream>>>(base2, s1w, s1b, s2w, s2b, outp + 2 * 2 * T99 * T99);
  // 6. bm + conv3d
  k_Gm<<<dim3(2, 4, 64), dim3(256), 0, stream>>>(b2t, w3tb, Gb);
  k_ppre<<<dim3(T99 * T99), dim3(256), 0, stream>>>(Gb, c3b, (unsigned int*)pinb);
  // 7. p-branch
  k_conv3x3<<<dim3(169, 2, 2), dim3(256), 0, stream>>>(pinb, wb2a, p1b, c1B, 0, 0, 98, p1o);
  k_conv3x3<<<dim3(169, 2, 2), dim3(256), 0, stream>>>(p1o, wb2b, p2b, c2B, 2, 1, 97, p2o);
  k_p3<<<dim3(77), dim3(256), 0, stream>>>(p2o, p3w, p3b, outp);
}

// Round 13
// 607.701 us; speedup vs baseline: 1.8470x; 1.0306x over previous
//
#include <hip/hip_runtime.h>
#include <math.h>

// ---------------- constants ----------------
#define T99   99
#define CC    256
#define NHH   8
#define FEAT  400
#define NS_   32
#define LSTEP 33

typedef __attribute__((ext_vector_type(8))) short s8v;   // 8 x bf16 (as raw u16)
typedef __attribute__((ext_vector_type(4))) float f4v;   // MFMA accumulator

__device__ __forceinline__ void mfma_bf16(f4v& d, s8v a, s8v b) {
  asm("v_mfma_f32_16x16x32_bf16 %0, %1, %2, %0" : "+v"(d) : "v"(a), "v"(b));
}

__device__ __forceinline__ unsigned short f2bf(float f) {
  union { float f; unsigned u; } x; x.f = f;
  unsigned r = x.u + 0x7FFFu + ((x.u >> 16) & 1u);
  return (unsigned short)(r >> 16);
}
__device__ __forceinline__ float bf2f(unsigned short h) {
  union { unsigned u; float f; } x; x.u = ((unsigned)h) << 16;
  return x.f;
}
__device__ __forceinline__ float blo(unsigned u) { union { unsigned x; float f; } c; c.x = u << 16; return c.f; }
__device__ __forceinline__ float bhi(unsigned u) { union { unsigned x; float f; } c; c.x = u & 0xffff0000u; return c.f; }

__device__ __forceinline__ float pe_val(int pos, int c) {
  int i = c >> 1;
  float freq = expf((float)(2 * i) * (-0.03597789207803197f)); // -ln(10000)/256
  float ang = (float)pos * freq;
  return (c & 1) ? cosf(ang) : sinf(ang);
}

// ---------------- conv stem ----------------
__global__ __launch_bounds__(128) void k_convbase(const float* __restrict__ x,
                                                  const float* __restrict__ w,
                                                  const float* __restrict__ bias,
                                                  float* __restrict__ base) {
  int b = blockIdx.x >> 8, co = blockIdx.x & 255, t = threadIdx.x;
  if (t >= T99) return;
  int g = co >> 6;
  float acc = bias[co];
  const float* xp = x + (size_t)(b * FEAT + g * 100) * T99;
  const float* wp = w + (size_t)co * 300;
  for (int ic = 0; ic < 100; ++ic) {
    float x0 = (t > 0)  ? xp[ic * T99 + t - 1] : 0.f;
    float x1 = xp[ic * T99 + t];
    float x2 = (t < 98) ? xp[ic * T99 + t + 1] : 0.f;
    acc += wp[ic * 3] * x0 + wp[ic * 3 + 1] * x1 + wp[ic * 3 + 2] * x2;
  }
  base[(size_t)(b * CC + co) * T99 + t] = fmaxf(acc, 0.f);
}

// ---------------- unified weight pack (all bf16 transforms in one kernel) ----------------
struct PackP {
  const float *gq, *go, *g1, *g2;   // global enc
  const float *lq, *lo, *l1, *l2;   // local enc
  const float *c3w, *p1w, *p2w;
  unsigned short *wtg, *wtl, *wog, *wol, *w3, *wba, *wbb;
};
#define S0 4718592   // wtg  (convW L=6)
#define S1 2359296   // wtl  (convW L=3)
#define S2 393216    // wog  (wot L=6)
#define S3 196608    // wol  (wot L=3)
#define S4 2097152   // w3   (w3tb)
#define S5 589824    // wba  (wb2 elements)
#define S6 589824    // wbb
#define STOT (S0+S1+S2+S3+S4+S5+S6)

__device__ __forceinline__ float convW_val(const float* qkv, const float* o, const float* l1,
                                           const float* l2, int idx) {
  int l = idx / 786432, r = idx % 786432;
  if (r < 196608)      return qkv[(size_t)l * 196608 + r];
  else if (r < 262144) return o[(size_t)l * 65536 + (r - 196608)];
  else if (r < 524288) return l1[(size_t)l * 262144 + (r - 262144)];
  else                 return l2[(size_t)l * 262144 + (r - 524288)];
}
__device__ __forceinline__ float wb2_val(const float* pw, int idx) {
  int v8 = idx >> 3, j = idx & 7;
  int lane = v8 & 63, cog = (v8 >> 6) & 15, kst = (v8 >> 10) & 7, tap = v8 >> 13;
  int co = cog * 16 + (lane & 15);
  int k  = kst * 32 + (lane >> 4) * 8;
  return pw[((size_t)co * 256 + k + j) * 9 + tap];
}

__global__ __launch_bounds__(256) void k_pack(PackP P) {
  for (int idx = blockIdx.x * 256 + threadIdx.x; idx < STOT; idx += gridDim.x * 256) {
    int r = idx;
    if (r < S0) { P.wtg[r] = f2bf(convW_val(P.gq, P.go, P.g1, P.g2, r)); continue; }
    r -= S0;
    if (r < S1) { P.wtl[r] = f2bf(convW_val(P.lq, P.lo, P.l1, P.l2, r)); continue; }
    r -= S1;
    if (r < S2) { int l = r >> 16, q = r & 65535; int ci = q >> 8, co = q & 255;
                  P.wog[r] = f2bf(P.go[(size_t)l * 65536 + co * 256 + ci]); continue; }
    r -= S2;
    if (r < S3) { int l = r >> 16, q = r & 65535; int ci = q >> 8, co = q & 255;
                  P.wol[r] = f2bf(P.lo[(size_t)l * 65536 + co * 256 + ci]); continue; }
    r -= S3;
    if (r < S4) { int ci = r & 255, co = (r >> 8) & 255, n = r >> 16;
                  P.w3[r] = f2bf(P.c3w[((size_t)(co << 8) + ci) * 32 + n]); continue; }
    r -= S4;
    if (r < S5) { P.wba[r] = f2bf(wb2_val(P.p1w, r)); continue; }
    r -= S5;
    P.wbb[r] = f2bf(wb2_val(P.p2w, r));
  }
}

// ---------------- build encoder inputs (dual) ----------------
__global__ __launch_bounds__(256) void k_build2(const float* __restrict__ base,
                                                float* __restrict__ xl, unsigned short* __restrict__ xlb,
                                                float* __restrict__ xg, unsigned short* __restrict__ xgb) {
  int tid = threadIdx.x;
  if (blockIdx.z == 0) {
    if (blockIdx.x >= 198) return;
    int idx = blockIdx.x * 256 + tid;
    int ls = idx / 1536, r = idx % 1536, j = r >> 8, c = r & 255;
    int g = j >> 1, b = j & 1, t = ls * 3 + g;
    float v = base[(size_t)(b * CC + c) * T99 + t] + pe_val(ls, c);
    xl[idx] = v; xlb[idx] = f2bf(v);
  } else {
    int idx = blockIdx.x * 256 + tid;
    int t = idx >> 10, r = idx & 1023, b4 = r >> 8, c = r & 255;
    float v = (b4 < 2) ? base[(size_t)(b4 * CC + c) * T99 + t]
                       : base[(size_t)((b4 - 2) * CC + c) * T99 + (98 - t)];
    v += pe_val(t, c);
    xg[idx] = v; xgb[idx] = f2bf(v);
  }
}

// ================= GEMM (R6-proven: 32-wide ksteps, dual LDS staging) =================
struct GJ {
  const unsigned short* Ab;
  const unsigned short* W;
  const float* bias;
  const float* R;
  float* Yf;
  unsigned short* Yb;
  int M, N, K, flags;
};

__device__ void g_body(const GJ& j, int m0, int n0) {
  __shared__ __align__(16) unsigned short Al[64][40];
  __shared__ __align__(16) unsigned short Bl[64][40];
  int tid = threadIdx.x;
  int lane = tid & 63, w = tid >> 6, wm = w >> 1, wn = w & 1;
  int sp = tid >> 2, kc = (tid & 3) << 3;
  f4v acc[2][2];
#pragma unroll
  for (int mt = 0; mt < 2; ++mt)
#pragma unroll
    for (int nt = 0; nt < 2; ++nt) acc[mt][nt] = (f4v){0.f, 0.f, 0.f, 0.f};

  for (int k0 = 0; k0 < j.K; k0 += 32) {
    s8v av = {0, 0, 0, 0, 0, 0, 0, 0};
    int row = m0 + sp;
    if (row < j.M) av = *(const s8v*)&j.Ab[(size_t)row * j.K + k0 + kc];
    *(s8v*)&Al[sp][kc] = av;
    *(s8v*)&Bl[sp][kc] = *(const s8v*)&j.W[(size_t)(n0 + sp) * j.K + k0 + kc];
    __syncthreads();
    s8v af[2], bf[2];
#pragma unroll
    for (int mt = 0; mt < 2; ++mt)
      af[mt] = *(const s8v*)&Al[wm * 32 + mt * 16 + (lane & 15)][(lane >> 4) * 8];
#pragma unroll
    for (int nt = 0; nt < 2; ++nt)
      bf[nt] = *(const s8v*)&Bl[wn * 32 + nt * 16 + (lane & 15)][(lane >> 4) * 8];
#pragma unroll
    for (int mt = 0; mt < 2; ++mt)
#pragma unroll
      for (int nt = 0; nt < 2; ++nt) mfma_bf16(acc[mt][nt], af[mt], bf[nt]);
    __syncthreads();
  }
  asm volatile("s_nop 7\n\ts_nop 7\n\ts_nop 4");
#pragma unroll
  for (int mt = 0; mt < 2; ++mt) {
#pragma unroll
    for (int nt = 0; nt < 2; ++nt) {
      int col = n0 + wn * 32 + nt * 16 + (lane & 15);
      float bv = j.bias[col];
#pragma unroll
      for (int r = 0; r < 4; ++r) {
        int row = m0 + wm * 32 + mt * 16 + (lane >> 4) * 4 + r;
        if (row < j.M) {
          float v = acc[mt][nt][r] + bv;
          if (j.flags & 2) v += j.R[(size_t)row * j.N + col];
          if (j.flags & 1) v = fmaxf(v, 0.f);
          if (!(j.flags & 8)) j.Yf[(size_t)row * j.N + col] = v;
          if (j.flags & 4) j.Yb[(size_t)row * j.N + col] = f2bf(v);
        }
      }
    }
  }
}

__global__ __launch_bounds__(256) void k_g(GJ j) {
  if ((int)blockIdx.x * 64 >= j.M) return;
  g_body(j, blockIdx.x * 64, blockIdx.y * 64);
}

__global__ __launch_bounds__(256) void k_g2(GJ j0, GJ j1) {
  if (blockIdx.z == 0) {
    if ((int)blockIdx.x * 64 >= j0.M) return;
    g_body(j0, blockIdx.x * 64, blockIdx.y * 64);
  } else {
    if ((int)blockIdx.x * 64 >= j1.M) return;
    g_body(j1, blockIdx.x * 64, blockIdx.y * 64);
  }
}

// ========== fused attn + proj + residual + LN1 (block = one token row) ==========
__device__ void apl_body(const unsigned short* __restrict__ qkvb,
                         const unsigned short* __restrict__ Wt,
                         const float* __restrict__ ob,
                         const float* __restrict__ g, const float* __restrict__ beta,
                         float* __restrict__ X, unsigned short* __restrict__ Xb,
                         int T_, int B_, int tok) {
  __shared__ float qrow[256];
  __shared__ float sc[8][100];
  __shared__ float den[8];
  __shared__ float att[256];
  __shared__ float rs[256], rq[256];
  int tid = threadIdx.x;
  int b = tok % B_;
  qrow[tid] = bf2f(qkvb[(size_t)tok * 768 + tid]);
  __syncthreads();
  for (int e = tid; e < 8 * T_; e += 256) {
    int h = e / T_, k = e % T_;
    const unsigned short* kp = qkvb + (size_t)(k * B_ + b) * 768 + 256 + h * 32;
    float d = 0.f;
#pragma unroll
    for (int i = 0; i < 32; ++i) d += qrow[h * 32 + i] * bf2f(kp[i]);
    sc[h][k] = d * 0.176776695296636881f;
  }
  __syncthreads();
  int h = tid >> 5, lane = tid & 31;
  float m = -1e30f;
  for (int k = lane; k < T_; k += 32) m = fmaxf(m, sc[h][k]);
#pragma unroll
  for (int msk = 16; msk >= 1; msk >>= 1) m = fmaxf(m, __shfl_xor(m, msk, 32));
  float sum = 0.f;
  for (int k = lane; k < T_; k += 32) {
    float p = expf(sc[h][k] - m);
    sc[h][k] = p; sum += p;
  }
#pragma unroll
  for (int msk = 16; msk >= 1; msk >>= 1) sum += __shfl_xor(sum, msk, 32);
  if (lane == 0) den[h] = sum;
  float o = 0.f;
  for (int k = 0; k < T_; ++k)
    o += sc[h][k] * bf2f(qkvb[(size_t)(k * B_ + b) * 768 + 512 + tid]);
  o /= den[h];
  att[tid] = o;
  __syncthreads();
  float acc = ob[tid];
#pragma unroll 8
  for (int ci = 0; ci < 256; ++ci) acc += att[ci] * bf2f(Wt[(size_t)ci * 256 + tid]);
  float v = acc + X[(size_t)tok * 256 + tid];
  rs[tid] = v; rq[tid] = v * v; __syncthreads();
  for (int oo = 128; oo > 0; oo >>= 1) { if (tid < oo) { rs[tid] += rs[tid + oo]; rq[tid] += rq[tid + oo]; } __syncthreads(); }
  float mu = rs[0] * (1.f / 256.f);
  float var = rq[0] * (1.f / 256.f) - mu * mu;
  float r = (v - mu) * rsqrtf(var + 1e-5f) * g[tid] + beta[tid];
  X[(size_t)tok * 256 + tid] = r;
  Xb[(size_t)tok * 256 + tid] = f2bf(r);
}

__global__ __launch_bounds__(256) void k_apl(const unsigned short* qkvb, const unsigned short* Wt,
                                             const float* ob, const float* g, const float* beta,
                                             float* X, unsigned short* Xb, int T_, int B_, int M) {
  if ((int)blockIdx.x >= M) return;
  apl_body(qkvb, Wt, ob, g, beta, X, Xb, T_, B_, blockIdx.x);
}

__global__ __launch_bounds__(256) void k_apl2(const unsigned short* q0, const unsigned short* Wt0,
                                              const float* ob0, const float* g0, const float* be0,
                                              float* X0, unsigned short* Xb0, int T0, int B0, int M0,
                                              const unsigned short* q1, const unsigned short* Wt1,
                                              const float* ob1, const float* g1, const float* be1,
                                              float* X1, unsigned short* Xb1, int T1, int B1, int M1) {
  int tok = blockIdx.x;
  if (blockIdx.z == 0) {
    if (tok >= M0) return;
    apl_body(q0, Wt0, ob0, g0, be0, X0, Xb0, T0, B0, tok);
  } else {
    if (tok >= M1) return;
    apl_body(q1, Wt1, ob1, g1, be1, X1, Xb1, T1, B1, tok);
  }
}

// ---------------- layer norm (fp32 out + optional bf16 mirror) ----------------
__device__ __forceinline__ void ln_body(const float* __restrict__ X, const float* __restrict__ g,
                                        const float* __restrict__ bb, float* __restrict__ Y,
                                        unsigned short* __restrict__ Yb, int tok) {
  __shared__ float rs[256], rq[256];
  int c = threadIdx.x;
  float v = X[(size_t)tok * 256 + c];
  rs[c] = v; rq[c] = v * v; __syncthreads();
  for (int o = 128; o > 0; o >>= 1) { if (c < o) { rs[c] += rs[c + o]; rq[c] += rq[c + o]; } __syncthreads(); }
  float mu = rs[0] * (1.f / 256.f);
  float var = rq[0] * (1.f / 256.f) - mu * mu;
  float r = (v - mu) * rsqrtf(var + 1e-5f) * g[c] + bb[c];
  Y[(size_t)tok * 256 + c] = r;
  if (Yb) Yb[(size_t)tok * 256 + c] = f2bf(r);
}

__global__ __launch_bounds__(256) void k_ln(const float* __restrict__ X, const float* __restrict__ g,
                                            const float* __restrict__ bb, float* __restrict__ Y,
                                            unsigned short* __restrict__ Yb) {
  ln_body(X, g, bb, Y, Yb, blockIdx.x);
}

__global__ __launch_bounds__(256) void k_ln2(const float* __restrict__ X0, const float* __restrict__ g0,
                                             const float* __restrict__ bb0, float* __restrict__ Y0,
                                             unsigned short* __restrict__ Yb0, int n0,
                                             const float* __restrict__ X1, const float* __restrict__ g1,
                                             const float* __restrict__ bb1, float* __restrict__ Y1,
                                             unsigned short* __restrict__ Yb1, int n1) {
  int tok = blockIdx.x;
  if (blockIdx.z == 0) { if (tok < n0) ln_body(X0, g0, bb0, Y0, Yb0, tok); }
  else                 { if (tok < n1) ln_body(X1, g1, bb1, Y1, Yb1, tok); }
}

// ---------------- combine2: final LNs (3 rows, zero duplication) + combine + b2t ----------------
__device__ __forceinline__ float ln3(float v, float* rs, float* rq) {
  int c = threadIdx.x;
  rs[c] = v; rq[c] = v * v; __syncthreads();
  for (int o = 128; o > 0; o >>= 1) { if (c < o) { rs[c] += rs[c + o]; rq[c] += rq[c + o]; } __syncthreads(); }
  float mu = rs[0] * (1.f / 256.f);
  float var = rq[0] * (1.f / 256.f) - mu * mu;
  float r = (v - mu) * rsqrtf(var + 1e-5f);
  __syncthreads();
  return r;
}

__global__ __launch_bounds__(256) void k_combine2(const float* __restrict__ XL, const float* __restrict__ XG,
                                                  const float* __restrict__ nfgL, const float* __restrict__ nfbL,
                                                  const float* __restrict__ nfgG, const float* __restrict__ nfbG,
                                                  float* __restrict__ base2, unsigned short* __restrict__ b2t) {
  __shared__ float rs[256], rq[256];
  int t = blockIdx.x % T99, b = blockIdx.x / T99, c = threadIdx.x;
  int ls = t / 3, g = t % 3;
  int tokL = ls * 6 + g * 2 + b;
  int tok1 = t * 4 + b;
  int tok2 = (98 - t) * 4 + 2 + b;
  float vL = ln3(XL[(size_t)tokL * 256 + c], rs, rq) * nfgL[c] + nfbL[c];
  float v1 = ln3(XG[(size_t)tok1 * 256 + c], rs, rq) * nfgG[c] + nfbG[c];
  float v2 = ln3(XG[(size_t)tok2 * 256 + c], rs, rq) * nfgG[c] + nfbG[c];
  float v = vL + v1 + v2;
  base2[((size_t)(b * CC) + c) * T99 + t] = v;
  b2t[((size_t)(b * T99) + t) * 256 + c] = f2bf(v);
}

// ---------------- merged Gm + sfuse ----------------
__device__ void gm_body(const unsigned short* __restrict__ b2t, const unsigned short* __restrict__ w3tb,
                        unsigned short* __restrict__ Gb, int mi, int ni, int nb, bool padzero) {
  __shared__ __align__(16) unsigned short Al[64][40];
  __shared__ __align__(16) unsigned short Bl[64][40];
  int n = nb >> 1, b = nb & 1;
  int m0 = mi * 64, n0 = ni * 64;
  int tid = threadIdx.x;
  if (padzero)
    ((unsigned int*)(Gb + (size_t)NS_ * T99 * 512))[tid] = 0u;
  const unsigned short* A = b2t + (size_t)b * T99 * 256;
  const unsigned short* W = w3tb + (size_t)n * 65536;
  int lane = tid & 63, w = tid >> 6, wm = w >> 1, wn = w & 1;
  int sp = tid >> 2, kc = (tid & 3) << 3;
  f4v acc[2][2];
#pragma unroll
  for (int mt = 0; mt < 2; ++mt)
#pragma unroll
    for (int nt = 0; nt < 2; ++nt) acc[mt][nt] = (f4v){0.f, 0.f, 0.f, 0.f};
#pragma unroll
  for (int k0 = 0; k0 < 256; k0 += 32) {
    s8v av = {0, 0, 0, 0, 0, 0, 0, 0};
    int row = m0 + sp;
    if (row < T99) av = *(const s8v*)&A[(size_t)row * 256 + k0 + kc];
    *(s8v*)&Al[sp][kc] = av;
    *(s8v*)&Bl[sp][kc] = *(const s8v*)&W[(size_t)(n0 + sp) * 256 + k0 + kc];
    __syncthreads();
    s8v af[2], bf[2];
#pragma unroll
    for (int mt = 0; mt < 2; ++mt)
      af[mt] = *(const s8v*)&Al[wm * 32 + mt * 16 + (lane & 15)][(lane >> 4) * 8];
#pragma unroll
    for (int nt = 0; nt < 2; ++nt)
      bf[nt] = *(const s8v*)&Bl[wn * 32 + nt * 16 + (lane & 15)][(lane >> 4) * 8];
#pragma unroll
    for (int mt = 0; mt < 2; ++mt)
#pragma unroll
      for (int nt = 0; nt < 2; ++nt) mfma_bf16(acc[mt][nt], af[mt], bf[nt]);
    __syncthreads();
  }
  asm volatile("s_nop 7\n\ts_nop 7\n\ts_nop 4");
#pragma unroll
  for (int mt = 0; mt < 2; ++mt) {
#pragma unroll
    for (int nt = 0; nt < 2; ++nt) {
      int co = n0 + wn * 32 + nt * 16 + (lane & 15);
#pragma unroll
      for (int r = 0; r < 4; ++r) {
        int t = m0 + wm * 32 + mt * 16 + (lane >> 4) * 4 + r;
        if (t < T99)
          Gb[((size_t)(n * T99 + t) * 256 + co) * 2 + b] = f2bf(acc[mt][nt][r]);
      }
    }
  }
}

__device__ void sfuse_body(const float* __restrict__ base2, const float* __restrict__ s1w,
                           const float* __restrict__ s1b, const float* __restrict__ s2w,
                           const float* __restrict__ s2b, float* __restrict__ out, int bid) {
  __shared__ float rs[256];
  int b = bid / T99, t = bid % T99, co = threadIdx.x;
  int g = co >> 6;
  float acc = s1b[co];
  const float* xp = base2 + (size_t)(b * CC + g * 64) * T99;
  const float* wp = s1w + (size_t)co * 192;
  for (int ic = 0; ic < 64; ++ic) {
    float x0 = (t > 0)  ? xp[ic * T99 + t - 1] : 0.f;
    float x1 = xp[ic * T99 + t];
    float x2 = (t < 98) ? xp[ic * T99 + t + 1] : 0.f;
    acc += wp[ic * 3] * x0 + wp[ic * 3 + 1] * x1 + wp[ic * 3 + 2] * x2;
  }
  rs[co] = fmaxf(acc, 0.f) * s2w[co];
  __syncthreads();
  for (int o = 128; o > 0; o >>= 1) { if (co < o) rs[co] += rs[co + o]; __syncthreads(); }
  if (co == 0) out[bid] = 1.f / (1.f + expf(-(rs[0] + s2b[0])));
}

__global__ __launch_bounds__(256) void k_gmsf(const unsigned short* b2t, const unsigned short* w3tb,
                                              unsigned short* Gb,
                                              const float* base2, const float* s1w, const float* s1b,
                                              const float* s2w, const float* s2b, float* sout) {
  int bid = blockIdx.x;
  if (bid < 512) {
    int mi = bid & 1, ni = (bid >> 1) & 3, nb = bid >> 3;
    gm_body(b2t, w3tb, Gb, mi, ni, nb, bid == 0);
  } else {
    sfuse_body(base2, s1w, s1b, s2w, s2b, sout, bid - 512);
  }
}

// ---------------- p_pre: split-k 256-thread ----------------
__global__ __launch_bounds__(256) void k_ppre(const unsigned short* __restrict__ Gb,
                                              const float* __restrict__ c3b,
                                              unsigned int* __restrict__ pinb32) {
  __shared__ float w0s[96], w1s[96];
  __shared__ int   ofs[96];
  __shared__ float part[128][4];
  int e = blockIdx.x % T99, s = blockIdx.x / T99;
  int tid = threadIdx.x;
  if (s >= e) {
    if (tid < 128) {
      float z0 = fmaxf(c3b[2 * tid], 0.f), z1 = fmaxf(c3b[2 * tid + 1], 0.f);
      unsigned int zz = ((unsigned)f2bf(z1) << 16) | (unsigned)f2bf(z0);
      pinb32[((size_t)s * T99 + e) * 128 + tid] = zz;
      pinb32[((size_t)(T99 + s) * T99 + e) * 128 + tid] = zz;
    }
    return;
  }
  if (tid < 96) {
    double center = (double)(e - s + 1);
    double S = ((double)s - 0.5 * center) + ((2.0 * center - 1.0) / 95.0) * (double)tid;
    double dn = trunc(S);
    double dec = S - dn;
    int di = (int)dn;
    double uc = ceil(S);
    int ui = (int)uc;
    int n = tid / 3;
    float w0 = 0.f, w1 = 0.f;
    int r0 = 0;
    if (dn >= 0.0 && dn <= 98.0) {
      r0 = di;
      w0 = (float)((1.0 - dec) / 3.0);
      if (uc >= 0.0 && uc <= 98.0) {
        if (ui == di) w0 += (float)(dec / 3.0);
        else          w1  = (float)(dec / 3.0);
      }
    }
    w0s[tid] = w0; w1s[tid] = w1;
    ofs[tid] = (n * T99 + r0) * 1024;
  }
  __syncthreads();
  int ch = tid & 127, half = tid >> 7;
  float a00 = 0.f, a01 = 0.f, a10 = 0.f, a11 = 0.f;
  const char* basep = (const char*)Gb + ch * 8;
  int k0 = half * 48;
#pragma unroll 8
  for (int k = k0; k < k0 + 48; ++k) {
    float w0 = w0s[k], w1 = w1s[k];
    const uint2* p = (const uint2*)(basep + ofs[k]);
    uint2 u0 = p[0];
    uint2 u1 = p[128];
    a00 += w0 * blo(u0.x) + w1 * blo(u1.x);
    a01 += w0 * bhi(u0.x) + w1 * bhi(u1.x);
    a10 += w0 * blo(u0.y) + w1 * blo(u1.y);
    a11 += w0 * bhi(u0.y) + w1 * bhi(u1.y);
  }
  if (half) { part[ch][0] = a00; part[ch][1] = a01; part[ch][2] = a10; part[ch][3] = a11; }
  __syncthreads();
  if (tid < 128) {
    a00 += part[ch][0]; a01 += part[ch][1]; a10 += part[ch][2]; a11 += part[ch][3];
    float b0 = c3b[2 * tid], b1 = c3b[2 * tid + 1];
    unsigned int zb0 = ((unsigned)f2bf(fmaxf(a10 + b1, 0.f)) << 16) | (unsigned)f2bf(fmaxf(a00 + b0, 0.f));
    unsigned int zb1 = ((unsigned)f2bf(fmaxf(a11 + b1, 0.f)) << 16) | (unsigned)f2bf(fmaxf(a01 + b0, 0.f));
    pinb32[((size_t)s * T99 + e) * 128 + tid] = zb0;
    pinb32[((size_t)(T99 + s) * T99 + e) * 128 + tid] = zb1;
  }
}

// ---------------- const-vector for conv const-region ----------------
__global__ __launch_bounds__(256) void k_cvec(const float* __restrict__ pw, const float* __restrict__ cin,
                                              const float* __restrict__ bias, int reluCin,
                                              float* __restrict__ coutF, unsigned short* __restrict__ coutB) {
  __shared__ float rs[256];
  int co = blockIdx.x, ci = threadIdx.x;
  float c = cin[ci];
  if (reluCin) c = fmaxf(c, 0.f);
  const float* wp = pw + ((size_t)co * 256 + ci) * 9;
  float wsum = 0.f;
#pragma unroll
  for (int t = 0; t < 9; ++t) wsum += wp[t];
  rs[ci] = wsum * c;
  __syncthreads();
  for (int o = 128; o > 0; o >>= 1) { if (ci < o) rs[ci] += rs[ci + o]; __syncthreads(); }
  if (ci == 0) {
    float r = fmaxf(bias[co] + rs[0], 0.f);
    coutF[co] = r;
    coutB[co] = f2bf(r);
  }
}

// ---------------- 3x3 conv: halo-LDS, sw-pipelined MFMA, const-region skip ----------------
__device__ __forceinline__ int aoff(int s) {
  int tap = s >> 3, kst = s & 7;
  return ((tap / 3) * 10 + (tap % 3)) * 264 + kst * 32;
}
__device__ __forceinline__ void ldb4(const unsigned short* __restrict__ B0, int s, s8v* dst) {
#pragma unroll
  for (int nt = 0; nt < 4; ++nt) dst[nt] = *(const s8v*)(B0 + (size_t)s * 8192 + nt * 512);
}

__global__ __launch_bounds__(256) void k_conv3x3(const unsigned short* __restrict__ in,
                                                 const unsigned short* __restrict__ wbf,
                                                 const float* __restrict__ bias,
                                                 const unsigned short* __restrict__ cvecB,
                                                 int D, int lo, int hi,
                                                 unsigned short* __restrict__ out) {
  __shared__ __align__(16) unsigned short Ah[100 * 264];
  int b = blockIdx.z;
  int co0 = blockIdx.y * 128;
  int ti = blockIdx.x / 13, tj = blockIdx.x % 13;
  int i0 = ti * 8, j0 = tj * 8;
  int tid = threadIdx.x;

  if (i0 - 1 >= lo && i0 + 8 <= hi && j0 - 1 >= lo && j0 + 8 <= hi && i0 - 1 >= j0 + 8 + D) {
    const unsigned int* cv = (const unsigned int*)(cvecB + co0);
    unsigned int* ob = (unsigned int*)out;
#pragma unroll
    for (int r = 0; r < 16; ++r) {
      int idx = r * 256 + tid;
      int sp = idx >> 6, cp = idx & 63;
      int gi = i0 + (sp >> 3), gj = j0 + (sp & 7);
      ob[((size_t)(b * T99 + gi) * T99 + gj) * 128 + (co0 >> 1) + cp] = cv[cp];
    }
    return;
  }

#pragma unroll
  for (int it = 0; it < 13; ++it) {
    int chunk = it * 256 + tid;
    if (chunk < 3200) {
      int row = chunk >> 5;
      int cc = (chunk & 31) * 8;
      int gi = i0 + row / 10 - 1, gj = j0 + row % 10 - 1;
      s8v val = {0, 0, 0, 0, 0, 0, 0, 0};
      if (gi >= 0 && gi < T99 && gj >= 0 && gj < T99)
        val = *(const s8v*)&in[((size_t)(b * T99 + gi) * T99 + gj) * 256 + cc];
      *(s8v*)&Ah[row * 264 + cc] = val;
    }
  }
  __syncthreads();

  int lane = tid & 63, w = tid >> 6, wm = w >> 1, wn = w & 1;
  int l15 = lane & 15, lk = lane >> 4;
  int spL0 = wm * 32 + l15, spL1 = spL0 + 16;
  int hr0 = (spL0 >> 3) * 10 + (spL0 & 7);
  int hr1 = (spL1 >> 3) * 10 + (spL1 & 7);
  const unsigned short* A0 = &Ah[hr0 * 264 + lk * 8];
  const unsigned short* A1 = &Ah[hr1 * 264 + lk * 8];
  int cogbase = blockIdx.y * 8 + wn * 4;
  const unsigned short* B0 = wbf + (size_t)cogbase * 512 + (size_t)lane * 8;

  f4v acc[2][4];
#pragma unroll
  for (int mt = 0; mt < 2; ++mt)
#pragma unroll
    for (int nt = 0; nt < 4; ++nt) acc[mt][nt] = (f4v){0.f, 0.f, 0.f, 0.f};

  s8v a0c, a1c, a0n, a1n;
  s8v bq[3][4];
  a0c = *(const s8v*)(A0 + aoff(0));
  a1c = *(const s8v*)(A1 + aoff(0));
  a0n = a0c; a1n = a1c;
  ldb4(B0, 0, bq[0]);
  ldb4(B0, 1, bq[1]);
#pragma unroll
  for (int s = 0; s < 72; ++s) {
    if (s + 2 < 72) ldb4(B0, s + 2, bq[(s + 2) % 3]);
    if (s + 1 < 72) {
      a0n = *(const s8v*)(A0 + aoff(s + 1));
      a1n = *(const s8v*)(A1 + aoff(s + 1));
    }
#pragma unroll
    for (int nt = 0; nt < 4; ++nt) {
      mfma_bf16(acc[0][nt], a0c, bq[s % 3][nt]);
      mfma_bf16(acc[1][nt], a1c, bq[s % 3][nt]);
    }
    a0c = a0n; a1c = a1n;
  }

  asm volatile("s_nop 7\n\ts_nop 7\n\ts_nop 4");
#pragma unroll
  for (int mt = 0; mt < 2; ++mt) {
#pragma unroll
    for (int nt = 0; nt < 4; ++nt) {
      int co = co0 + wn * 64 + nt * 16 + l15;
      float bv = bias[co];
#pragma unroll
      for (int r = 0; r < 4; ++r) {
        int sp = wm * 32 + mt * 16 + lk * 4 + r;
        int gi = i0 + (sp >> 3), gj = j0 + (sp & 7);
        if (gi < T99 && gj < T99) {
          float v = fmaxf(acc[mt][nt][r] + bv, 0.f);
          out[((size_t)(b * T99 + gi) * T99 + gj) * 256 + co] = f2bf(v);
        }
      }
    }
  }
}

// ---------------- p3: both channels per row ----------------
__global__ __launch_bounds__(256) void k_p3(const unsigned short* __restrict__ p2o,
                                            const float* __restrict__ w, const float* __restrict__ bias,
                                            float* __restrict__ cm) {
  int idx = blockIdx.x * 256 + threadIdx.x;
  if (idx >= 2 * T99 * T99) return;
  int j = idx % T99, i = (idx / T99) % T99, b = idx / (T99 * T99);
  float a0 = bias[0], a1 = bias[1];
  const unsigned short* row = p2o + ((size_t)(b * T99 + i) * T99 + j) * 256;
  for (int c8 = 0; c8 < 256; c8 += 8) {
    s8v v = *(const s8v*)&row[c8];
#pragma unroll
    for (int q = 0; q < 8; ++q) {
      float x = bf2f((unsigned short)v[q]);
      a0 += w[c8 + q] * x;
      a1 += w[256 + c8 + q] * x;
    }
  }
  size_t base = (size_t)b * 2 * T99 * T99 + (size_t)i * T99 + j;
  cm[base] = 1.f / (1.f + expf(-a0));
  cm[base + T99 * T99] = 1.f / (1.f + expf(-a1));
}

// ---------------- host ----------------
struct EncW {
  const float *qkvw, *qkvb, *ow, *ob, *l1w, *l1b, *l2w, *l2b, *n1g, *n1b, *n2g, *n2b, *nfg, *nfb;
};
struct EncBufs {
  float* x; unsigned short* xb;
  float* yb;
  unsigned short *qkvb, *hb;
  int M;
};

static GJ jqkv(const EncW& W, const unsigned short* Wb, int l, const EncBufs& B) {
  GJ j = {}; j.Ab = B.xb; j.W = Wb + (size_t)l * 786432;
  j.bias = W.qkvb + (size_t)l * 768; j.Yb = B.qkvb; j.flags = 4 | 8;
  j.M = B.M; j.N = 768; j.K = 256; return j;
}
static GJ jffn1(const EncW& W, const unsigned short* Wb, int l, const EncBufs& B) {
  GJ j = {}; j.Ab = B.xb; j.W = Wb + (size_t)l * 786432 + 262144;
  j.bias = W.l1b + (size_t)l * 1024; j.Yb = B.hb; j.flags = 1 | 4 | 8;
  j.M = B.M; j.N = 1024; j.K = 256; return j;
}
static GJ jffn2(const EncW& W, const unsigned short* Wb, int l, const EncBufs& B) {
  GJ j = {}; j.Ab = B.hb; j.W = Wb + (size_t)l * 786432 + 524288;
  j.bias = W.l2b + (size_t)l * 256; j.R = B.x; j.Yf = B.yb; j.flags = 2;
  j.M = B.M; j.N = 256; j.K = 1024; return j;
}

extern "C" void kernel_launch(void* const* d_in, const int* in_sizes, int n_in,
                              void* d_out, int out_size, void* d_ws, size_t ws_size,
                              hipStream_t stream) {
  (void)in_sizes; (void)n_in; (void)out_size; (void)ws_size;
  const float* x    = (const float*)d_in[0];
  const float* cbw  = (const float*)d_in[1];
  const float* cbb  = (const float*)d_in[2];
  EncW tg = {(const float*)d_in[3],  (const float*)d_in[4],  (const float*)d_in[5],  (const float*)d_in[6],
             (const float*)d_in[7],  (const float*)d_in[8],  (const float*)d_in[9],  (const float*)d_in[10],
             (const float*)d_in[11], (const float*)d_in[12], (const float*)d_in[13], (const float*)d_in[14],
             (const float*)d_in[15], (const float*)d_in[16]};
  EncW tl = {(const float*)d_in[17], (const float*)d_in[18], (const float*)d_in[19], (const float*)d_in[20],
             (const float*)d_in[21], (const float*)d_in[22], (const float*)d_in[23], (const float*)d_in[24],
             (const float*)d_in[25], (const float*)d_in[26], (const float*)d_in[27], (const float*)d_in[28],
             (const float*)d_in[29], (const float*)d_in[30]};
  const float* s1w = (const float*)d_in[31];
  const float* s1b = (const float*)d_in[32];
  const float* s2w = (const float*)d_in[33];
  const float* s2b = (const float*)d_in[34];
  const float* c3w = (const float*)d_in[35];
  const float* c3b = (const float*)d_in[36];
  const float* p1w = (const float*)d_in[37];
  const float* p1b = (const float*)d_in[38];
  const float* p2w = (const float*)d_in[39];
  const float* p2b = (const float*)d_in[40];
  const float* p3w = (const float*)d_in[41];
  const float* p3b = (const float*)d_in[42];

  float* outp = (float*)d_out; // [cm 39204][start1 198]

  char* wp = (char*)d_ws;
  auto alloc = [&](size_t bytes) -> void* {
    void* p = (void*)wp;
    wp += (bytes + 255) & ~(size_t)255;
    return p;
  };
  float* base  = (float*)alloc(sizeof(float) * 2 * CC * T99);
  const int ML = 198, MG = 396;
  EncBufs BG, BL;
  BG.M = MG; BL.M = ML;
  BG.x  = (float*)alloc(sizeof(float) * MG * 256);
  BL.x  = (float*)alloc(sizeof(float) * ML * 256);
  BG.xb = (unsigned short*)alloc(sizeof(short) * MG * 256);
  BL.xb = (unsigned short*)alloc(sizeof(short) * ML * 256);
  BG.yb = (float*)alloc(sizeof(float) * MG * 256);
  BL.yb = (float*)alloc(sizeof(float) * ML * 256);
  BG.qkvb = (unsigned short*)alloc(sizeof(short) * MG * 768);
  BL.qkvb = (unsigned short*)alloc(sizeof(short) * ML * 768);
  BG.hb = (unsigned short*)alloc(sizeof(short) * MG * 1024);
  BL.hb = (unsigned short*)alloc(sizeof(short) * ML * 1024);
  float* base2 = (float*)alloc(sizeof(float) * 2 * CC * T99);
  unsigned short* b2t = (unsigned short*)alloc(sizeof(short) * 2 * T99 * 256);
  unsigned short* w3tb = (unsigned short*)alloc(sizeof(short) * 32 * 256 * 256);
  unsigned short* Gb = (unsigned short*)alloc(sizeof(short) * (2 * NS_ * T99 * 256 + 512));
  unsigned short* pinb = (unsigned short*)alloc(sizeof(short) * 2 * T99 * T99 * 256);
  unsigned short* p1o  = (unsigned short*)alloc(sizeof(short) * 2 * T99 * T99 * 256);
  unsigned short* p2o  = (unsigned short*)alloc(sizeof(short) * 2 * T99 * T99 * 256);
  unsigned short* wb2a = (unsigned short*)alloc(sizeof(short) * 9 * 256 * 256);
  unsigned short* wb2b = (unsigned short*)alloc(sizeof(short) * 9 * 256 * 256);
  unsigned short* wtgb = (unsigned short*)alloc(sizeof(short) * 6 * 786432);
  unsigned short* wtlb = (unsigned short*)alloc(sizeof(short) * 3 * 786432);
  unsigned short* wotg = (unsigned short*)alloc(sizeof(short) * 6 * 65536);
  unsigned short* wotl = (unsigned short*)alloc(sizeof(short) * 3 * 65536);
  float* c1F = (float*)alloc(sizeof(float) * 256);
  unsigned short* c1B = (unsigned short*)alloc(sizeof(short) * 256);
  float* c2F = (float*)alloc(sizeof(float) * 256);
  unsigned short* c2B = (unsigned short*)alloc(sizeof(short) * 256);

  // 0. preamble: one pack kernel + 2 cvec (dependent chain)
  PackP PK = {tg.qkvw, tg.ow, tg.l1w, tg.l2w, tl.qkvw, tl.ow, tl.l1w, tl.l2w,
              c3w, p1w, p2w, wtgb, wtlb, wotg, wotl, w3tb, wb2a, wb2b};
  k_pack<<<dim3(8192), dim3(256), 0, stream>>>(PK);
  k_cvec<<<dim3(256), dim3(256), 0, stream>>>(p1w, c3b, p1b, 1, c1F, c1B);
  k_cvec<<<dim3(256), dim3(256), 0, stream>>>(p2w, c1F, p2b, 0, c2F, c2B);
  // 1. conv stem + encoder inputs
  k_convbase<<<dim3(512), dim3(128), 0, stream>>>(x, cbw, cbb, base);
  k_build2<<<dim3(396, 1, 2), dim3(256), 0, stream>>>(base, BL.x, BL.xb, BG.x, BG.xb);

  // 2. layers 0..2 merged (local || global)
  const int mgG = 7;
  for (int l = 0; l < 3; ++l) {
    k_g2<<<dim3(mgG, 12, 2), dim3(256), 0, stream>>>(jqkv(tl, wtlb, l, BL), jqkv(tg, wtgb, l, BG));
    k_apl2<<<dim3(MG, 1, 2), dim3(256), 0, stream>>>(
        BL.qkvb, wotl + (size_t)l * 65536, tl.ob + l * 256, tl.n1g + l * 256, tl.n1b + l * 256,
        BL.x, BL.xb, LSTEP, 6, ML,
        BG.qkvb, wotg + (size_t)l * 65536, tg.ob + l * 256, tg.n1g + l * 256, tg.n1b + l * 256,
        BG.x, BG.xb, T99, 4, MG);
    k_g2<<<dim3(mgG, 16, 2), dim3(256), 0, stream>>>(jffn1(tl, wtlb, l, BL), jffn1(tg, wtgb, l, BG));
    k_g2<<<dim3(mgG, 4, 2), dim3(256), 0, stream>>>(jffn2(tl, wtlb, l, BL), jffn2(tg, wtgb, l, BG));
    k_ln2<<<dim3(MG, 1, 2), dim3(256), 0, stream>>>(BL.yb, tl.n2g + l * 256, tl.n2b + l * 256, BL.x, BL.xb, ML,
                                                    BG.yb, tg.n2g + l * 256, tg.n2b + l * 256, BG.x, BG.xb, MG);
  }
  // 3. global layers 3..5
  for (int l = 3; l < 6; ++l) {
    k_g<<<dim3(mgG, 12), dim3(256), 0, stream>>>(jqkv(tg, wtgb, l, BG));
    k_apl<<<dim3(MG), dim3(256), 0, stream>>>(BG.qkvb, wotg + (size_t)l * 65536, tg.ob + l * 256,
                                              tg.n1g + l * 256, tg.n1b + l * 256, BG.x, BG.xb, T99, 4, MG);
    k_g<<<dim3(mgG, 16), dim3(256), 0, stream>>>(jffn1(tg, wtgb, l, BG));
    k_g<<<dim3(mgG, 4), dim3(256), 0, stream>>>(jffn2(tg, wtgb, l, BG));
    k_ln<<<dim3(MG), dim3(256), 0, stream>>>(BG.yb, tg.n2g + l * 256, tg.n2b + l * 256, BG.x, BG.xb);
  }
  // 4. final LNs + combine + b2t (fused, zero duplication)
  k_combine2<<<dim3(198), dim3(256), 0, stream>>>(BL.x, BG.x, tl.nfg, tl.nfb, tg.nfg, tg.nfb, base2, b2t);
  // 5. Gm + sfuse merged
  k_gmsf<<<dim3(710), dim3(256), 0, stream>>>(b2t, w3tb, Gb, base2, s1w, s1b, s2w, s2b,
                                              outp + 2 * 2 * T99 * T99);
  // 6. ppre + p-branch
  k_ppre<<<dim3(T99 * T99), dim3(256), 0, stream>>>(Gb, c3b, (unsigned int*)pinb);
  k_conv3x3<<<dim3(169, 2, 2), dim3(256), 0, stream>>>(pinb, wb2a, p1b, c1B, 0, 0, 98, p1o);
  k_conv3x3<<<dim3(169, 2, 2), dim3(256), 0, stream>>>(p1o, wb2b, p2b, c2B, 2, 1, 97, p2o);
  k_p3<<<dim3(77), dim3(256), 0, stream>>>(p2o, p3w, p3b, outp);
}